// Round 1
// baseline (1652.568 us; speedup 1.0000x reference)
//
#include <hip/hip_runtime.h>
#include <math.h>

#define NB 1024
// conv1
#define C1 16
#define H1 4
#define W1 153
#define WX 216
#define K1 64
// conv2
#define C2 32
#define H2 4
#define W2 155
#define W2IN 186
// pool2
#define PW2 38
// conv3
#define C3 32
#define H3 2
#define W3 38
#define H3IN 9
#define W3IN 41

// workspace float offsets
#define OFF_OUT1   0
#define OFF_OUT2   10027008
#define OFF_POOL2  30343168
#define OFF_OUT3   32833536
#define OFF_FEATS  35323904
#define OFF_Q      35618816
#define OFF_PART1  35913728
#define OFF_PART2  35913984
#define OFF_PART3  35914496
#define OFF_STATS1 35915008
#define OFF_STATS2 35915040
#define OFF_STATS3 35915104
#define OFF_WTRIG  35915168

__device__ __forceinline__ float eluf(float x){ return x > 0.f ? x : expm1f(x); }

// ---------------- conv1: (1024,1,4,216) * (16,1,1,64) -> (1024,16,4,153)
__global__ __launch_bounds__(256) void k_conv1(const float* __restrict__ x,
                                               const float* __restrict__ w1,
                                               float* __restrict__ out1){
  __shared__ float xrow[WX];
  __shared__ float wl[C1*K1];
  int n = blockIdx.x >> 2, h = blockIdx.x & 3;
  int tid = threadIdx.x;
  if (tid < WX) xrow[tid] = x[(n*H1 + h)*WX + tid];
  for (int i = tid; i < C1*K1; i += 256) wl[i] = w1[i];
  __syncthreads();
  for (int idx = tid; idx < C1*W1; idx += 256){
    int co = idx / W1, w = idx - co*W1;
    float s = 0.f;
    #pragma unroll
    for (int k = 0; k < K1; ++k) s += xrow[w+k] * wl[co*K1 + k];
    out1[((size_t)(n*C1 + co)*H1 + h)*W1 + w] = s;
  }
}

// ---------------- generic BN stats: layout (N, C, len) contiguous per (n,c)
__global__ __launch_bounds__(256) void k_stats_partial(const float* __restrict__ in,
                                                       float* __restrict__ part,
                                                       int C, int len){
  int c = blockIdx.x >> 3, sl = blockIdx.x & 7;
  float s = 0.f, sq = 0.f;
  for (int n = sl*128; n < sl*128 + 128; ++n){
    const float* base = in + (size_t)(n*C + c)*len;
    for (int i = threadIdx.x; i < len; i += 256){ float v = base[i]; s += v; sq += v*v; }
  }
  __shared__ float rs[256], rq[256];
  rs[threadIdx.x] = s; rq[threadIdx.x] = sq; __syncthreads();
  for (int st = 128; st > 0; st >>= 1){
    if (threadIdx.x < st){ rs[threadIdx.x] += rs[threadIdx.x+st]; rq[threadIdx.x] += rq[threadIdx.x+st]; }
    __syncthreads();
  }
  if (threadIdx.x == 0){ part[blockIdx.x*2] = rs[0]; part[blockIdx.x*2+1] = rq[0]; }
}

__global__ void k_stats_final(const float* __restrict__ part, float* __restrict__ stats,
                              int C, float inv_count){
  int c = threadIdx.x;
  if (c >= C) return;
  float s = 0.f, sq = 0.f;
  for (int sl = 0; sl < 8; ++sl){ s += part[(c*8+sl)*2]; sq += part[(c*8+sl)*2+1]; }
  float mean = s * inv_count;
  float var  = sq * inv_count - mean*mean;
  stats[c*2]   = mean;
  stats[c*2+1] = rsqrtf(var + 1e-5f);
}

// ---------------- BN+ELU in place on out1
__global__ void k_bnelu1(float* __restrict__ a, const float* __restrict__ stats){
  const int total = NB*C1*H1*W1;
  for (int idx = blockIdx.x*256 + threadIdx.x; idx < total; idx += gridDim.x*256){
    int c = (idx / (H1*W1)) % C1;
    float v = (a[idx] - stats[c*2]) * stats[c*2+1];
    a[idx] = v > 0.f ? v : expm1f(v);
  }
}

// ---------------- conv2: padded (1024,16,5,186) * (32,16,2,32) -> (1024,32,4,155)
__global__ __launch_bounds__(256) void k_conv2(const float* __restrict__ act1,
                                               const float* __restrict__ w2,
                                               float* __restrict__ out2){
  __shared__ float sin_[2*16*W2IN + 64];  // pad: discarded-tail reads stay in bounds
  int n = blockIdx.x >> 2, h = blockIdx.x & 3;
  int tid = threadIdx.x;
  for (int i = tid; i < 2*16*W2IN; i += 256){
    int r = i / (16*W2IN); int rem = i - r*(16*W2IN);
    int ci = rem / W2IN;   int wp  = rem - ci*W2IN;
    int hr = h + r; int wsrc = wp - 16;
    float v = 0.f;
    if (hr < 4 && (unsigned)wsrc < (unsigned)W1)
      v = act1[((size_t)(n*C1 + ci)*H1 + hr)*W1 + wsrc];
    sin_[i] = v;
  }
  for (int i = tid; i < 64; i += 256) sin_[2*16*W2IN + i] = 0.f;
  __syncthreads();
  int wq = tid & 63, cobase = (tid >> 6) * 8;
  float acc[8][3] = {};
  for (int ci = 0; ci < 16; ++ci){
    #pragma unroll
    for (int r = 0; r < 2; ++r){
      const float* wbase = w2 + ((size_t)(cobase*16 + ci)*2 + r)*32;  // co stride = 1024 floats
      const float* sbase = sin_ + (r*16 + ci)*W2IN + wq;
      #pragma unroll
      for (int k4 = 0; k4 < 8; ++k4){
        float4 wv[8];
        #pragma unroll
        for (int i = 0; i < 8; ++i) wv[i] = *(const float4*)(wbase + i*1024 + k4*4);
        #pragma unroll
        for (int kk = 0; kk < 4; ++kk){
          int k = k4*4 + kk;
          float x0 = sbase[k], x1 = sbase[64+k], x2 = sbase[128+k];
          #pragma unroll
          for (int i = 0; i < 8; ++i){
            float wk = ((const float*)&wv[i])[kk];
            acc[i][0] += wk*x0; acc[i][1] += wk*x1; acc[i][2] += wk*x2;
          }
        }
      }
    }
  }
  #pragma unroll
  for (int m = 0; m < 3; ++m){
    int w = wq + 64*m;
    if (w < W2){
      #pragma unroll
      for (int i = 0; i < 8; ++i)
        out2[((size_t)(n*C2 + cobase + i)*H2 + h)*W2 + w] = acc[i][m];
    }
  }
}

// ---------------- pool(2,4)+BN+ELU on out2 -> pooled2 (1024,32,2,38)
__global__ void k_bnelupool2(const float* __restrict__ out2, const float* __restrict__ stats,
                             float* __restrict__ pool){
  const int total = NB*C2*2*PW2;
  for (int idx = blockIdx.x*256 + threadIdx.x; idx < total; idx += gridDim.x*256){
    int pw = idx % PW2; int t = idx / PW2;
    int ph = t & 1; t >>= 1;
    int c = t & 31; int n = t >> 5;
    const float* base = out2 + ((size_t)(n*C2 + c)*H2 + 2*ph)*W2 + 4*pw;
    float mx = base[0];
    #pragma unroll
    for (int dh = 0; dh < 2; ++dh)
      #pragma unroll
      for (int dw = 0; dw < 4; ++dw) mx = fmaxf(mx, base[dh*W2 + dw]);
    float v = (mx - stats[c*2]) * stats[c*2+1];
    pool[idx] = v > 0.f ? v : expm1f(v);
  }
}

// ---------------- conv3: padded (1024,32,9,41) * (32,32,8,4) -> (1024,32,2,38)
__global__ __launch_bounds__(256) void k_conv3(const float* __restrict__ pool,
                                               const float* __restrict__ w3,
                                               float* __restrict__ out3){
  __shared__ float spad[C3*H3IN*W3IN + 40];  // 11808 + pad for discarded-tail reads
  int n = blockIdx.x, tid = threadIdx.x;
  for (int i = tid; i < C3*H3IN*W3IN; i += 256){
    int ci = i / (H3IN*W3IN); int rem = i - ci*(H3IN*W3IN);
    int rp = rem / W3IN; int wp = rem - rp*W3IN;
    int hs = rp - 4, ws = wp - 2;
    float v = 0.f;
    if ((unsigned)hs < 2u && (unsigned)ws < (unsigned)W3)
      v = pool[((size_t)(n*C3 + ci)*2 + hs)*PW2 + ws];
    spad[i] = v;
  }
  for (int i = tid; i < 40; i += 256) spad[C3*H3IN*W3IN + i] = 0.f;
  __syncthreads();
  int wq = tid & 31, cobase = (tid >> 5) * 4;
  float acc[4][2][2] = {};
  for (int ci = 0; ci < 32; ++ci){
    #pragma unroll
    for (int r = 0; r < 8; ++r){
      float4 wv[4];
      #pragma unroll
      for (int i = 0; i < 4; ++i)
        wv[i] = *(const float4*)(w3 + (((size_t)(cobase+i)*32 + ci)*8 + r)*4);
      const float* s0 = spad + (ci*H3IN + r)*W3IN + wq;
      const float* s1 = s0 + W3IN;
      #pragma unroll
      for (int kk = 0; kk < 4; ++kk){
        float x00 = s0[kk], x01 = s0[32+kk];
        float x10 = s1[kk], x11 = s1[32+kk];
        #pragma unroll
        for (int i = 0; i < 4; ++i){
          float wk = ((const float*)&wv[i])[kk];
          acc[i][0][0] += wk*x00; acc[i][0][1] += wk*x01;
          acc[i][1][0] += wk*x10; acc[i][1][1] += wk*x11;
        }
      }
    }
  }
  #pragma unroll
  for (int m = 0; m < 2; ++m){
    int w = wq + 32*m;
    if (w < W3){
      #pragma unroll
      for (int i = 0; i < 4; ++i)
        #pragma unroll
        for (int hh = 0; hh < 2; ++hh)
          out3[((size_t)(n*C3 + cobase + i)*H3 + hh)*W3 + w] = acc[i][hh][m];
    }
  }
}

// ---------------- pool(2,4)+BN+ELU on out3 -> feats (1024,32,9)
__global__ void k_bnelupool3(const float* __restrict__ out3, const float* __restrict__ stats,
                             float* __restrict__ feats){
  int idx = blockIdx.x*256 + threadIdx.x;  // total 294912 exactly
  int pw = idx % 9; int t = idx / 9;
  int c = t & 31; int n = t >> 5;
  const float* base = out3 + ((size_t)(n*C3 + c)*H3)*W3 + 4*pw;
  float mx = base[0];
  #pragma unroll
  for (int dh = 0; dh < 2; ++dh)
    #pragma unroll
    for (int dw = 0; dw < 4; ++dw) mx = fmaxf(mx, base[dh*W3 + dw]);
  float v = (mx - stats[c*2]) * stats[c*2+1];
  feats[idx] = v > 0.f ? v : expm1f(v);
}

// ---------------- precompute cos/sin of layer weights
__global__ void k_wtrig(const float* __restrict__ qw, float* __restrict__ wtrig){
  int i = threadIdx.x;
  if (i < 36){
    float s, c; sincosf(qw[i]*0.5f, &s, &c);
    wtrig[i*2] = c; wtrig[i*2+1] = s;
  }
}

// ---------------- quantum layer: one wave per sample, 512 amps = 64 lanes x 8 regs
// state index s: bits[8:3]=lane, bits[2:0]=register. wire i <-> bit (8-i).
__global__ __launch_bounds__(256) void k_quantum(const float* __restrict__ feats,
                                                 const float* __restrict__ wtrig,
                                                 float* __restrict__ qout){
  int wid = threadIdx.x >> 6, lane = threadIdx.x & 63;
  int sample = blockIdx.x*4 + wid;
  const float* ang = feats + (size_t)sample*9;
  float cc[9], ssn[9];
  #pragma unroll
  for (int i = 0; i < 9; ++i){ sincosf(ang[i]*0.5f, &ssn[i], &cc[i]); }
  float P = 1.f;
  #pragma unroll
  for (int i = 0; i < 6; ++i) P *= (lane & (32>>i)) ? ssn[i] : cc[i];
  float v[8];
  #pragma unroll
  for (int r = 0; r < 8; ++r)
    v[r] = P * ((r&4)?ssn[6]:cc[6]) * ((r&2)?ssn[7]:cc[7]) * ((r&1)?ssn[8]:cc[8]);

  for (int j = 0; j < 4; ++j){
    // CNOT(i, i+1) for i=0..4: ctrl lane bit (5-i), tgt lane bit (4-i)
    #pragma unroll
    for (int i = 0; i < 5; ++i){
      int cm = 32>>i, tm = 16>>i;
      bool flip = (lane & cm) != 0;
      #pragma unroll
      for (int r = 0; r < 8; ++r){
        float w = __shfl_xor(v[r], tm);
        v[r] = flip ? w : v[r];
      }
    }
    // CNOT(5,6): ctrl lane bit0, tgt reg bit2
    { bool flip = (lane & 1) != 0;
      #pragma unroll
      for (int r = 0; r < 4; ++r){ float a = v[r], b = v[r+4]; v[r] = flip?b:a; v[r+4] = flip?a:b; } }
    // CNOT(6,7): ctrl reg bit2, tgt reg bit1
    { float t = v[4]; v[4] = v[6]; v[6] = t; t = v[5]; v[5] = v[7]; v[7] = t; }
    // CNOT(7,8): ctrl reg bit1, tgt reg bit0
    { float t = v[2]; v[2] = v[3]; v[3] = t; t = v[6]; v[6] = v[7]; v[7] = t; }
    // CNOT(8,0): ctrl reg bit0, tgt lane bit5
    #pragma unroll
    for (int r = 1; r < 8; r += 2) v[r] = __shfl_xor(v[r], 32);

    // RY wires 0..5 (lane bits)
    #pragma unroll
    for (int i = 0; i < 6; ++i){
      float c = wtrig[(j*9+i)*2], s = wtrig[(j*9+i)*2+1];
      int m = 32>>i;
      float sg = (lane & m) ? s : -s;
      #pragma unroll
      for (int r = 0; r < 8; ++r){
        float w = __shfl_xor(v[r], m);
        v[r] = c*v[r] + sg*w;
      }
    }
    // RY wire 6 (reg bit2)
    { float c = wtrig[(j*9+6)*2], s = wtrig[(j*9+6)*2+1];
      #pragma unroll
      for (int r = 0; r < 4; ++r){ float a = v[r], b = v[r+4]; v[r] = c*a - s*b; v[r+4] = s*a + c*b; } }
    // RY wire 7 (reg bit1): pairs (0,2),(1,3),(4,6),(5,7)
    { float c = wtrig[(j*9+7)*2], s = wtrig[(j*9+7)*2+1]; float a, b;
      a=v[0]; b=v[2]; v[0]=c*a-s*b; v[2]=s*a+c*b;
      a=v[1]; b=v[3]; v[1]=c*a-s*b; v[3]=s*a+c*b;
      a=v[4]; b=v[6]; v[4]=c*a-s*b; v[6]=s*a+c*b;
      a=v[5]; b=v[7]; v[5]=c*a-s*b; v[7]=s*a+c*b; }
    // RY wire 8 (reg bit0): pairs (0,1),(2,3),(4,5),(6,7)
    { float c = wtrig[(j*9+8)*2], s = wtrig[(j*9+8)*2+1]; float a, b;
      a=v[0]; b=v[1]; v[0]=c*a-s*b; v[1]=s*a+c*b;
      a=v[2]; b=v[3]; v[2]=c*a-s*b; v[3]=s*a+c*b;
      a=v[4]; b=v[5]; v[4]=c*a-s*b; v[5]=s*a+c*b;
      a=v[6]; b=v[7]; v[6]=c*a-s*b; v[7]=s*a+c*b; }
  }

  // measure <Z_i>
  float q2[8];
  #pragma unroll
  for (int r = 0; r < 8; ++r) q2[r] = v[r]*v[r];
  float psum = 0.f;
  #pragma unroll
  for (int r = 0; r < 8; ++r) psum += q2[r];
  float z[9];
  #pragma unroll
  for (int i = 0; i < 6; ++i) z[i] = (lane & (32>>i)) ? -psum : psum;
  z[6] = (q2[0]+q2[1]+q2[2]+q2[3]) - (q2[4]+q2[5]+q2[6]+q2[7]);
  z[7] = (q2[0]+q2[1]+q2[4]+q2[5]) - (q2[2]+q2[3]+q2[6]+q2[7]);
  z[8] = (q2[0]+q2[2]+q2[4]+q2[6]) - (q2[1]+q2[3]+q2[5]+q2[7]);
  #pragma unroll
  for (int m = 1; m < 64; m <<= 1){
    #pragma unroll
    for (int i = 0; i < 9; ++i) z[i] += __shfl_xor(z[i], m);
  }
  if (lane == 0){
    #pragma unroll
    for (int i = 0; i < 9; ++i) qout[(size_t)sample*9 + i] = z[i];
  }
}

// ---------------- fc: (1024,288) @ (5,288)^T + b
__global__ void k_fc(const float* __restrict__ q, const float* __restrict__ fw,
                     const float* __restrict__ fb, float* __restrict__ out){
  int idx = blockIdx.x*256 + threadIdx.x;
  if (idx >= NB*5) return;
  int b = idx / 5, o = idx - b*5;
  const float* qr = q + (size_t)b*288;
  const float* wr = fw + (size_t)o*288;
  float s = 0.f;
  for (int j = 0; j < 288; ++j) s += qr[j]*wr[j];
  out[idx] = s + fb[o];
}

extern "C" void kernel_launch(void* const* d_in, const int* in_sizes, int n_in,
                              void* d_out, int out_size, void* d_ws, size_t ws_size,
                              hipStream_t stream){
  const float* x  = (const float*)d_in[0];
  const float* w1 = (const float*)d_in[1];
  const float* w2 = (const float*)d_in[2];
  const float* w3 = (const float*)d_in[3];
  const float* qw = (const float*)d_in[4];
  const float* fw = (const float*)d_in[5];
  const float* fb = (const float*)d_in[6];
  float* out = (float*)d_out;
  float* W = (float*)d_ws;

  float* out1   = W + OFF_OUT1;
  float* out2   = W + OFF_OUT2;
  float* pool2  = W + OFF_POOL2;
  float* out3   = W + OFF_OUT3;
  float* feats  = W + OFF_FEATS;
  float* qo     = W + OFF_Q;
  float* part1  = W + OFF_PART1;
  float* part2  = W + OFF_PART2;
  float* part3  = W + OFF_PART3;
  float* stats1 = W + OFF_STATS1;
  float* stats2 = W + OFF_STATS2;
  float* stats3 = W + OFF_STATS3;
  float* wtrig  = W + OFF_WTRIG;

  k_conv1<<<NB*H1, 256, 0, stream>>>(x, w1, out1);
  k_stats_partial<<<C1*8, 256, 0, stream>>>(out1, part1, C1, H1*W1);
  k_stats_final<<<1, 64, 0, stream>>>(part1, stats1, C1, 1.f/(NB*H1*W1));
  k_bnelu1<<<4096, 256, 0, stream>>>(out1, stats1);
  k_conv2<<<NB*H2, 256, 0, stream>>>(out1, w2, out2);
  k_stats_partial<<<C2*8, 256, 0, stream>>>(out2, part2, C2, H2*W2);
  k_stats_final<<<1, 64, 0, stream>>>(part2, stats2, C2, 1.f/((float)NB*H2*W2));
  k_bnelupool2<<<2048, 256, 0, stream>>>(out2, stats2, pool2);
  k_conv3<<<NB, 256, 0, stream>>>(pool2, w3, out3);
  k_stats_partial<<<C3*8, 256, 0, stream>>>(out3, part3, C3, H3*W3);
  k_stats_final<<<1, 64, 0, stream>>>(part3, stats3, C3, 1.f/((float)NB*H3*W3));
  k_bnelupool3<<<1152, 256, 0, stream>>>(out3, stats3, feats);
  k_wtrig<<<1, 64, 0, stream>>>(qw, wtrig);
  k_quantum<<<8192, 256, 0, stream>>>(feats, wtrig, qo);
  k_fc<<<20, 256, 0, stream>>>(qo, fw, fb, out);
}

// Round 2
// 560.100 us; speedup vs baseline: 2.9505x; 2.9505x over previous
//
#include <hip/hip_runtime.h>
#include <math.h>

#define NB 1024
#define C1 16
#define H1 4
#define W1 153
#define WX 216
#define K1 64
#define C2 32
#define H2 4
#define W2 155
#define W192 192
#define PW2 38
#define C3 32
#define W3 38

typedef short short4v __attribute__((ext_vector_type(4)));
typedef short short8 __attribute__((ext_vector_type(8)));
typedef float f32x16 __attribute__((ext_vector_type(16)));

// ---- workspace float offsets
#define OFF_OUT1     0          // 10,027,008
#define OFF_ACT1H    10027008   // 6,291,456 f32 slots (12,582,912 ushort)
#define OFF_ACT1L    16318464
#define OFF_W2PH     22609920   // 16384 slots each
#define OFF_W2PL     22626304
#define OFF_W3PH     22642688
#define OFF_W3PL     22659072
#define OFF_POOL2RAW 22675456   // 2,490,368
#define OFF_ACT2H    25165824   // 2,359,296 slots (4,718,592 ushort)
#define OFF_ACT2L    27525120
#define OFF_FEATSRAW 29884416   // 294,912
#define OFF_FEATS    30179328
#define OFF_Q        30474240
#define OFF_PART1    30769152   // 256
#define OFF_PART2    30769408   // 65,536
#define OFF_PART3    30834944   // 32,768
#define OFF_STATS1   30867712
#define OFF_STATS2   30867744
#define OFF_STATS3   30867808
#define OFF_WTRIG    30867872

__device__ __forceinline__ float eluf(float x){ return x > 0.f ? x : expm1f(x); }

__device__ __forceinline__ ushort bf16h(float x){
  unsigned u = __float_as_uint(x);
  unsigned r = u + 0x7fffu + ((u >> 16) & 1u);
  return (ushort)(r >> 16);
}
__device__ __forceinline__ float bf16f(ushort h){ return __uint_as_float(((unsigned)h) << 16); }

__device__ __forceinline__ short8 cat8(short4v a, short4v b){
  return __builtin_shufflevector(a, b, 0,1,2,3,4,5,6,7);
}

// ---------------- conv1: (1024,1,4,216) * (16,1,1,64) -> out1 (1024,16,4,153)
__global__ __launch_bounds__(256) void k_conv1(const float* __restrict__ x,
                                               const float* __restrict__ w1,
                                               float* __restrict__ out1){
  __shared__ float xrow[WX];
  __shared__ float wl[C1*K1];
  int n = blockIdx.x >> 2, h = blockIdx.x & 3;
  int tid = threadIdx.x;
  if (tid < WX) xrow[tid] = x[(n*H1 + h)*WX + tid];
  for (int i = tid; i < C1*K1; i += 256) wl[i] = w1[i];
  __syncthreads();
  for (int idx = tid; idx < C1*W1; idx += 256){
    int co = idx / W1, w = idx - co*W1;
    float s = 0.f;
    #pragma unroll
    for (int k = 0; k < K1; ++k) s += xrow[w+k] * wl[co*K1 + k];
    out1[((size_t)(n*C1 + co)*H1 + h)*W1 + w] = s;
  }
}

// ---------------- BN stats partial for conv1 (layout (N,C,len))
__global__ __launch_bounds__(256) void k_stats_partial(const float* __restrict__ in,
                                                       float* __restrict__ part,
                                                       int C, int len){
  int c = blockIdx.x >> 3, sl = blockIdx.x & 7;
  float s = 0.f, sq = 0.f;
  for (int n = sl*128; n < sl*128 + 128; ++n){
    const float* base = in + (size_t)(n*C + c)*len;
    for (int i = threadIdx.x; i < len; i += 256){ float v = base[i]; s += v; sq += v*v; }
  }
  __shared__ float rs[256], rq[256];
  rs[threadIdx.x] = s; rq[threadIdx.x] = sq; __syncthreads();
  for (int st = 128; st > 0; st >>= 1){
    if (threadIdx.x < st){ rs[threadIdx.x] += rs[threadIdx.x+st]; rq[threadIdx.x] += rq[threadIdx.x+st]; }
    __syncthreads();
  }
  if (threadIdx.x == 0){ part[blockIdx.x*2] = rs[0]; part[blockIdx.x*2+1] = rq[0]; }
}

__global__ void k_stats_final(const float* __restrict__ part, float* __restrict__ stats,
                              int C, float inv_count){
  int c = threadIdx.x;
  if (c >= C) return;
  float s = 0.f, sq = 0.f;
  for (int sl = 0; sl < 8; ++sl){ s += part[(c*8+sl)*2]; sq += part[(c*8+sl)*2+1]; }
  float mean = s * inv_count;
  float var  = sq * inv_count - mean*mean;
  stats[c*2]   = mean;
  stats[c*2+1] = rsqrtf(var + 1e-5f);
}

// generic partial reduce: part[nblk][32][2] -> stats[32][2]
__global__ void k_statsN_final(const float* __restrict__ part, float* __restrict__ stats,
                               int nblk, float inv_count){
  __shared__ float ls[8][32][2];
  int co = threadIdx.x & 31, sl = threadIdx.x >> 5;
  float s = 0.f, q = 0.f;
  for (int b = sl; b < nblk; b += 8){
    s += part[(b*32+co)*2];
    q += part[(b*32+co)*2+1];
  }
  ls[sl][co][0] = s; ls[sl][co][1] = q;
  __syncthreads();
  if (threadIdx.x < 32){
    float S=0.f, Q=0.f;
    for (int i=0;i<8;++i){ S += ls[i][threadIdx.x][0]; Q += ls[i][threadIdx.x][1]; }
    float mean = S*inv_count;
    float var  = Q*inv_count - mean*mean;
    stats[threadIdx.x*2]   = mean;
    stats[threadIdx.x*2+1] = rsqrtf(var + 1e-5f);
  }
}

// ---------------- bnelu1: out1 -> act1 bf16 hi/lo, layout [n][h][w192][ci16], ci-subblock XOR-swizzled
__global__ __launch_bounds__(256) void k_bnelu1(const float* __restrict__ out1,
                                                const float* __restrict__ stats,
                                                ushort* __restrict__ a1h, ushort* __restrict__ a1l){
  int b = blockIdx.x;
  int wc = b % 12; int t = b / 12; int h = t & 3; int n = t >> 2;
  int tid = threadIdx.x;
  int ci = tid & 15, wlcl = tid >> 4;
  int w = wc*16 + wlcl;
  int ws = w - 16;
  float v = 0.f;
  if ((unsigned)ws < (unsigned)W1){
    float xx = out1[((size_t)(n*C1 + ci)*H1 + h)*W1 + ws];
    float bn = (xx - stats[ci*2]) * stats[ci*2+1];
    v = eluf(bn);
  }
  int ciS = ci ^ (((w >> 2) & 3) << 2);
  size_t o = ((size_t)(n*4 + h)*W192 + w)*16 + ciS;
  ushort hs = bf16h(v);
  float hf = bf16f(hs);
  ushort lsu = bf16h(v - hf);
  a1h[o] = hs; a1l[o] = lsu;
}

// ---------------- weight convert+permute: w2 -> [rk64][co32][ci16], w3 -> [rk32][co32][ci32]
__global__ void k_cvtw(const float* __restrict__ w2, const float* __restrict__ w3,
                       ushort* __restrict__ w2ph, ushort* __restrict__ w2pl,
                       ushort* __restrict__ w3ph, ushort* __restrict__ w3pl){
  int idx = blockIdx.x*256 + threadIdx.x;   // 65536 total
  if (idx < 32768){
    int ci = idx & 15; int co = (idx >> 4) & 31; int rk = idx >> 9;
    int r = rk >> 5, kw = rk & 31;
    float v = w2[((size_t)(co*16 + ci)*2 + r)*32 + kw];
    ushort hs = bf16h(v); float hf = bf16f(hs);
    w2ph[idx] = hs; w2pl[idx] = bf16h(v - hf);
  } else {
    int j = idx - 32768;
    int ci = j & 31; int co = (j >> 5) & 31; int rk = j >> 10;
    int r = rk >> 2, kw = rk & 3;
    float v = w3[((size_t)(co*32 + ci)*8 + r)*4 + kw];
    ushort hs = bf16h(v); float hf = bf16f(hs);
    w3ph[j] = hs; w3pl[j] = bf16h(v - hf);
  }
}

// ---------------- fused conv2 (MFMA 3-term bf16) + stats partial + maxpool(2,4)
// block = one n; wave = one h. M=32co (one 32x32 frag), N=160 pos (5 frags), K=16ci per (r,kw) step.
__global__ __launch_bounds__(256, 2) void k_conv2f(const ushort* __restrict__ a1h,
                                                   const ushort* __restrict__ a1l,
                                                   const ushort* __restrict__ w2ph,
                                                   const ushort* __restrict__ w2pl,
                                                   float* __restrict__ pool2raw,
                                                   float* __restrict__ part2){
  __shared__ ushort s_hi[4*W192*16];
  __shared__ ushort s_lo[4*W192*16];
  __shared__ float poolL[4][32][40];
  __shared__ float statL[4][32][2];
  int n = blockIdx.x;
  int tid = threadIdx.x;
  { // stage (pre-swizzled in global): 12288 ushorts per array = 1536 float4
    const float4* gh = (const float4*)(a1h + (size_t)n*12288);
    const float4* gl = (const float4*)(a1l + (size_t)n*12288);
    float4* dh = (float4*)s_hi;
    float4* dl = (float4*)s_lo;
    #pragma unroll
    for (int i = 0; i < 6; ++i){ dh[tid + 256*i] = gh[tid + 256*i]; dl[tid + 256*i] = gl[tid + 256*i]; }
  }
  __syncthreads();
  int wave = tid >> 6, lane = tid & 63;
  int h = wave;
  int l5 = lane >> 5, l31 = lane & 31;

  f32x16 acc[5];
  #pragma unroll
  for (int p = 0; p < 5; ++p)
    #pragma unroll
    for (int e = 0; e < 16; ++e) acc[p][e] = 0.f;

  int rmax = (h == 3) ? 1 : 2;
  for (int r = 0; r < rmax; ++r){
    int rb = (h + r) * (W192*16);
    for (int kw = 0; kw < 32; ++kw){
      int widx = (((r << 5) + kw)*32 + l31)*16 + l5*4;
      short8 Ah = cat8(*(const short4v*)(w2ph + widx), *(const short4v*)(w2ph + widx + 8));
      short8 Al = cat8(*(const short4v*)(w2pl + widx), *(const short4v*)(w2pl + widx + 8));
      short8 Bh[5], Bl[5];
      #pragma unroll
      for (int p = 0; p < 5; ++p){
        int pos = p*32 + l31 + kw;
        int sw = ((pos >> 2) & 3) << 2;
        int off0 = rb + pos*16 + ((l5*4) ^ sw);
        int off1 = rb + pos*16 + ((l5*4 + 8) ^ sw);
        Bh[p] = cat8(*(const short4v*)(s_hi + off0), *(const short4v*)(s_hi + off1));
        Bl[p] = cat8(*(const short4v*)(s_lo + off0), *(const short4v*)(s_lo + off1));
      }
      #pragma unroll
      for (int p = 0; p < 5; ++p) acc[p] = __builtin_amdgcn_mfma_f32_32x32x16_bf16(Ah, Bh[p], acc[p], 0, 0, 0);
      #pragma unroll
      for (int p = 0; p < 5; ++p) acc[p] = __builtin_amdgcn_mfma_f32_32x32x16_bf16(Ah, Bl[p], acc[p], 0, 0, 0);
      #pragma unroll
      for (int p = 0; p < 5; ++p) acc[p] = __builtin_amdgcn_mfma_f32_32x32x16_bf16(Al, Bh[p], acc[p], 0, 0, 0);
    }
  }

  // ---- stats partial (mask w>=155) : C/D map col=lane&31, row=(e&3)+8*(e>>2)+4*l5
  {
    float sreg[16], qreg[16];
    #pragma unroll
    for (int e = 0; e < 16; ++e){ sreg[e] = 0.f; qreg[e] = 0.f; }
    #pragma unroll
    for (int p = 0; p < 5; ++p){
      bool pv = (p < 4) || (l31 < 27);
      #pragma unroll
      for (int e = 0; e < 16; ++e){
        float v = pv ? acc[p][e] : 0.f;
        sreg[e] += v; qreg[e] += v*v;
      }
    }
    #pragma unroll
    for (int m = 1; m < 32; m <<= 1){
      #pragma unroll
      for (int e = 0; e < 16; ++e){
        sreg[e] += __shfl_xor(sreg[e], m);
        qreg[e] += __shfl_xor(qreg[e], m);
      }
    }
    if (l31 == 0){
      #pragma unroll
      for (int e = 0; e < 16; ++e){
        int co = (e & 3) + ((e >> 2) << 3) + (l5 << 2);
        statL[h][co][0] = sreg[e];
        statL[h][co][1] = qreg[e];
      }
    }
  }
  // ---- per-wave pooled max over w quads
  #pragma unroll
  for (int p = 0; p < 5; ++p){
    #pragma unroll
    for (int e = 0; e < 16; ++e){
      float v = acc[p][e];
      float v1 = fmaxf(v, __shfl_xor(v, 1));
      float v2 = fmaxf(v1, __shfl_xor(v1, 2));
      int pw = p*8 + (l31 >> 2);
      if ((l31 & 3) == 0 && pw < PW2){
        int co = (e & 3) + ((e >> 2) << 3) + (l5 << 2);
        poolL[h][co][pw] = v2;
      }
    }
  }
  __syncthreads();
  // cross-h pool + write (pre-BN)
  for (int i = tid; i < 2*32*PW2; i += 256){
    int pw = i % PW2; int t = i / PW2; int co = t & 31; int ph = t >> 5;
    float v = fmaxf(poolL[2*ph][co][pw], poolL[2*ph+1][co][pw]);
    pool2raw[(((size_t)n*2 + ph)*32 + co)*PW2 + pw] = v;
  }
  if (tid < 32){
    float s = 0.f, q = 0.f;
    #pragma unroll
    for (int hh = 0; hh < 4; ++hh){ s += statL[hh][tid][0]; q += statL[hh][tid][1]; }
    part2[(n*32 + tid)*2]   = s;
    part2[(n*32 + tid)*2+1] = q;
  }
}

// ---------------- bn2: pool2raw -> act2 bf16 hi/lo, layout [n][hr2][w72][ci32], swizzled
__global__ void k_bn2(const float* __restrict__ pool2raw, const float* __restrict__ stats,
                      ushort* __restrict__ a2h, ushort* __restrict__ a2l){
  int idx = blockIdx.x*256 + threadIdx.x;  // 4,718,592 exact
  int ci = idx & 31; int t = idx >> 5;
  int w = t % 72; t /= 72; int hr = t & 1; int n = t >> 1;
  float v = 0.f;
  int pw = w - 2;
  if ((unsigned)pw < (unsigned)PW2){
    float xx = pool2raw[(((size_t)n*2 + hr)*32 + ci)*PW2 + pw];
    v = eluf((xx - stats[ci*2]) * stats[ci*2+1]);
  }
  int ciS = ci ^ (((w >> 1) & 7) << 2);
  size_t o = (((size_t)n*2 + hr)*72 + w)*32 + ciS;
  ushort hs = bf16h(v); float hf = bf16f(hs);
  a2h[o] = hs; a2l[o] = bf16h(v - hf);
}

// ---------------- fused conv3 (MFMA 3-term bf16) + stats partial + maxpool(2,4)
// block = 2 n; wave = (nh, h). M=32co, N=64 pos (2 frags), K=16ci-half per (r,kw,ch) step (16 steps).
__global__ __launch_bounds__(256, 2) void k_conv3f(const ushort* __restrict__ a2h,
                                                   const ushort* __restrict__ a2l,
                                                   const ushort* __restrict__ w3ph,
                                                   const ushort* __restrict__ w3pl,
                                                   float* __restrict__ featsraw,
                                                   float* __restrict__ part3){
  __shared__ ushort s3h[9216];
  __shared__ ushort s3l[9216];
  __shared__ float poolL3[4][32][12];
  __shared__ float statL3[4][32][2];
  int nb = blockIdx.x;   // 512 blocks, 2 n each
  int tid = threadIdx.x;
  { // stage 9216 ushorts per array = 1152 float4
    const float4* gh = (const float4*)(a2h + (size_t)nb*9216);
    const float4* gl = (const float4*)(a2l + (size_t)nb*9216);
    float4* dh = (float4*)s3h;
    float4* dl = (float4*)s3l;
    for (int i = tid; i < 1152; i += 256){ dh[i] = gh[i]; dl[i] = gl[i]; }
  }
  __syncthreads();
  int wave = tid >> 6, lane = tid & 63;
  int nh = wave >> 1, h = wave & 1;
  int l5 = lane >> 5, l31 = lane & 31;

  f32x16 acc[2];
  #pragma unroll
  for (int p = 0; p < 2; ++p)
    #pragma unroll
    for (int e = 0; e < 16; ++e) acc[p][e] = 0.f;

  #pragma unroll
  for (int ri = 0; ri < 2; ++ri){
    int r = (h == 0) ? (4 + ri) : (3 + ri);
    int rbase = (nh*2 + ri)*72*32;
    #pragma unroll
    for (int kw = 0; kw < 4; ++kw){
      #pragma unroll
      for (int ch = 0; ch < 2; ++ch){
        int widx = ((r*4 + kw)*32 + l31)*32 + ch*16 + l5*4;
        short8 Ah = cat8(*(const short4v*)(w3ph + widx), *(const short4v*)(w3ph + widx + 8));
        short8 Al = cat8(*(const short4v*)(w3pl + widx), *(const short4v*)(w3pl + widx + 8));
        short8 Bh[2], Bl[2];
        #pragma unroll
        for (int p = 0; p < 2; ++p){
          int pos = p*32 + l31 + kw;
          int sw = ((pos >> 1) & 7) << 2;
          int s0 = ch*16 + l5*4;
          int off0 = rbase + pos*32 + (s0 ^ sw);
          int off1 = rbase + pos*32 + ((s0 + 8) ^ sw);
          Bh[p] = cat8(*(const short4v*)(s3h + off0), *(const short4v*)(s3h + off1));
          Bl[p] = cat8(*(const short4v*)(s3l + off0), *(const short4v*)(s3l + off1));
        }
        #pragma unroll
        for (int p = 0; p < 2; ++p) acc[p] = __builtin_amdgcn_mfma_f32_32x32x16_bf16(Ah, Bh[p], acc[p], 0, 0, 0);
        #pragma unroll
        for (int p = 0; p < 2; ++p) acc[p] = __builtin_amdgcn_mfma_f32_32x32x16_bf16(Ah, Bl[p], acc[p], 0, 0, 0);
        #pragma unroll
        for (int p = 0; p < 2; ++p) acc[p] = __builtin_amdgcn_mfma_f32_32x32x16_bf16(Al, Bh[p], acc[p], 0, 0, 0);
      }
    }
  }

  // stats partial (mask w>=38)
  {
    float sreg[16], qreg[16];
    #pragma unroll
    for (int e = 0; e < 16; ++e){ sreg[e] = 0.f; qreg[e] = 0.f; }
    #pragma unroll
    for (int p = 0; p < 2; ++p){
      bool pv = (p == 0) || (l31 < 6);
      #pragma unroll
      for (int e = 0; e < 16; ++e){
        float v = pv ? acc[p][e] : 0.f;
        sreg[e] += v; qreg[e] += v*v;
      }
    }
    #pragma unroll
    for (int m = 1; m < 32; m <<= 1){
      #pragma unroll
      for (int e = 0; e < 16; ++e){
        sreg[e] += __shfl_xor(sreg[e], m);
        qreg[e] += __shfl_xor(qreg[e], m);
      }
    }
    if (l31 == 0){
      #pragma unroll
      for (int e = 0; e < 16; ++e){
        int co = (e & 3) + ((e >> 2) << 3) + (l5 << 2);
        statL3[wave][co][0] = sreg[e];
        statL3[wave][co][1] = qreg[e];
      }
    }
  }
  // per-wave pooled max (pw<9)
  #pragma unroll
  for (int p = 0; p < 2; ++p){
    #pragma unroll
    for (int e = 0; e < 16; ++e){
      float v = acc[p][e];
      float v1 = fmaxf(v, __shfl_xor(v, 1));
      float v2 = fmaxf(v1, __shfl_xor(v1, 2));
      int pw = p*8 + (l31 >> 2);
      if ((l31 & 3) == 0 && pw < 9){
        int co = (e & 3) + ((e >> 2) << 3) + (l5 << 2);
        poolL3[wave][co][pw] = v2;
      }
    }
  }
  __syncthreads();
  for (int i = tid; i < 2*32*9; i += 256){
    int pw = i % 9; int t = i / 9; int co = t & 31; int nh2 = t >> 5;
    float v = fmaxf(poolL3[nh2*2][co][pw], poolL3[nh2*2+1][co][pw]);
    featsraw[((size_t)(nb*2 + nh2)*32 + co)*9 + pw] = v;
  }
  if (tid < 32){
    float s = 0.f, q = 0.f;
    #pragma unroll
    for (int wv = 0; wv < 4; ++wv){ s += statL3[wv][tid][0]; q += statL3[wv][tid][1]; }
    part3[(nb*32 + tid)*2]   = s;
    part3[(nb*32 + tid)*2+1] = q;
  }
}

// ---------------- feats BN+ELU
__global__ void k_featbn(const float* __restrict__ fr, const float* __restrict__ stats,
                         float* __restrict__ feats){
  int idx = blockIdx.x*256 + threadIdx.x;  // 294912 exact
  int c = (idx / 9) & 31;
  feats[idx] = eluf((fr[idx] - stats[c*2]) * stats[c*2+1]);
}

// ---------------- precompute cos/sin of layer weights
__global__ void k_wtrig(const float* __restrict__ qw, float* __restrict__ wtrig){
  int i = threadIdx.x;
  if (i < 36){
    float s, c; sincosf(qw[i]*0.5f, &s, &c);
    wtrig[i*2] = c; wtrig[i*2+1] = s;
  }
}

// ---------------- quantum layer: one wave per sample, 512 amps = 64 lanes x 8 regs
__global__ __launch_bounds__(256) void k_quantum(const float* __restrict__ feats,
                                                 const float* __restrict__ wtrig,
                                                 float* __restrict__ qout){
  int wid = threadIdx.x >> 6, lane = threadIdx.x & 63;
  int sample = blockIdx.x*4 + wid;
  const float* ang = feats + (size_t)sample*9;
  float cc[9], ssn[9];
  #pragma unroll
  for (int i = 0; i < 9; ++i){ sincosf(ang[i]*0.5f, &ssn[i], &cc[i]); }
  float P = 1.f;
  #pragma unroll
  for (int i = 0; i < 6; ++i) P *= (lane & (32>>i)) ? ssn[i] : cc[i];
  float v[8];
  #pragma unroll
  for (int r = 0; r < 8; ++r)
    v[r] = P * ((r&4)?ssn[6]:cc[6]) * ((r&2)?ssn[7]:cc[7]) * ((r&1)?ssn[8]:cc[8]);

  for (int j = 0; j < 4; ++j){
    #pragma unroll
    for (int i = 0; i < 5; ++i){
      int cm = 32>>i, tm = 16>>i;
      bool flip = (lane & cm) != 0;
      #pragma unroll
      for (int r = 0; r < 8; ++r){
        float w = __shfl_xor(v[r], tm);
        v[r] = flip ? w : v[r];
      }
    }
    { bool flip = (lane & 1) != 0;
      #pragma unroll
      for (int r = 0; r < 4; ++r){ float a = v[r], b = v[r+4]; v[r] = flip?b:a; v[r+4] = flip?a:b; } }
    { float t = v[4]; v[4] = v[6]; v[6] = t; t = v[5]; v[5] = v[7]; v[7] = t; }
    { float t = v[2]; v[2] = v[3]; v[3] = t; t = v[6]; v[6] = v[7]; v[7] = t; }
    #pragma unroll
    for (int r = 1; r < 8; r += 2) v[r] = __shfl_xor(v[r], 32);

    #pragma unroll
    for (int i = 0; i < 6; ++i){
      float c = wtrig[(j*9+i)*2], s = wtrig[(j*9+i)*2+1];
      int m = 32>>i;
      float sg = (lane & m) ? s : -s;
      #pragma unroll
      for (int r = 0; r < 8; ++r){
        float w = __shfl_xor(v[r], m);
        v[r] = c*v[r] + sg*w;
      }
    }
    { float c = wtrig[(j*9+6)*2], s = wtrig[(j*9+6)*2+1];
      #pragma unroll
      for (int r = 0; r < 4; ++r){ float a = v[r], b = v[r+4]; v[r] = c*a - s*b; v[r+4] = s*a + c*b; } }
    { float c = wtrig[(j*9+7)*2], s = wtrig[(j*9+7)*2+1]; float a, b;
      a=v[0]; b=v[2]; v[0]=c*a-s*b; v[2]=s*a+c*b;
      a=v[1]; b=v[3]; v[1]=c*a-s*b; v[3]=s*a+c*b;
      a=v[4]; b=v[6]; v[4]=c*a-s*b; v[6]=s*a+c*b;
      a=v[5]; b=v[7]; v[5]=c*a-s*b; v[7]=s*a+c*b; }
    { float c = wtrig[(j*9+8)*2], s = wtrig[(j*9+8)*2+1]; float a, b;
      a=v[0]; b=v[1]; v[0]=c*a-s*b; v[1]=s*a+c*b;
      a=v[2]; b=v[3]; v[2]=c*a-s*b; v[3]=s*a+c*b;
      a=v[4]; b=v[5]; v[4]=c*a-s*b; v[5]=s*a+c*b;
      a=v[6]; b=v[7]; v[6]=c*a-s*b; v[7]=s*a+c*b; }
  }

  float q2[8];
  #pragma unroll
  for (int r = 0; r < 8; ++r) q2[r] = v[r]*v[r];
  float psum = 0.f;
  #pragma unroll
  for (int r = 0; r < 8; ++r) psum += q2[r];
  float z[9];
  #pragma unroll
  for (int i = 0; i < 6; ++i) z[i] = (lane & (32>>i)) ? -psum : psum;
  z[6] = (q2[0]+q2[1]+q2[2]+q2[3]) - (q2[4]+q2[5]+q2[6]+q2[7]);
  z[7] = (q2[0]+q2[1]+q2[4]+q2[5]) - (q2[2]+q2[3]+q2[6]+q2[7]);
  z[8] = (q2[0]+q2[2]+q2[4]+q2[6]) - (q2[1]+q2[3]+q2[5]+q2[7]);
  #pragma unroll
  for (int m = 1; m < 64; m <<= 1){
    #pragma unroll
    for (int i = 0; i < 9; ++i) z[i] += __shfl_xor(z[i], m);
  }
  if (lane == 0){
    #pragma unroll
    for (int i = 0; i < 9; ++i) qout[(size_t)sample*9 + i] = z[i];
  }
}

// ---------------- fc: (1024,288) @ (5,288)^T + b
__global__ void k_fc(const float* __restrict__ q, const float* __restrict__ fw,
                     const float* __restrict__ fb, float* __restrict__ out){
  int idx = blockIdx.x*256 + threadIdx.x;
  if (idx >= NB*5) return;
  int b = idx / 5, o = idx - b*5;
  const float* qr = q + (size_t)b*288;
  const float* wr = fw + (size_t)o*288;
  float s = 0.f;
  for (int j = 0; j < 288; ++j) s += qr[j]*wr[j];
  out[idx] = s + fb[o];
}

extern "C" void kernel_launch(void* const* d_in, const int* in_sizes, int n_in,
                              void* d_out, int out_size, void* d_ws, size_t ws_size,
                              hipStream_t stream){
  const float* x  = (const float*)d_in[0];
  const float* w1 = (const float*)d_in[1];
  const float* w2 = (const float*)d_in[2];
  const float* w3 = (const float*)d_in[3];
  const float* qw = (const float*)d_in[4];
  const float* fw = (const float*)d_in[5];
  const float* fb = (const float*)d_in[6];
  float* out = (float*)d_out;
  float* W = (float*)d_ws;

  float*  out1   = W + OFF_OUT1;
  ushort* a1h    = (ushort*)(W + OFF_ACT1H);
  ushort* a1l    = (ushort*)(W + OFF_ACT1L);
  ushort* w2ph   = (ushort*)(W + OFF_W2PH);
  ushort* w2pl   = (ushort*)(W + OFF_W2PL);
  ushort* w3ph   = (ushort*)(W + OFF_W3PH);
  ushort* w3pl   = (ushort*)(W + OFF_W3PL);
  float*  pool2raw = W + OFF_POOL2RAW;
  ushort* a2h    = (ushort*)(W + OFF_ACT2H);
  ushort* a2l    = (ushort*)(W + OFF_ACT2L);
  float*  featsraw = W + OFF_FEATSRAW;
  float*  feats  = W + OFF_FEATS;
  float*  qo     = W + OFF_Q;
  float*  part1  = W + OFF_PART1;
  float*  part2  = W + OFF_PART2;
  float*  part3  = W + OFF_PART3;
  float*  stats1 = W + OFF_STATS1;
  float*  stats2 = W + OFF_STATS2;
  float*  stats3 = W + OFF_STATS3;
  float*  wtrig  = W + OFF_WTRIG;

  k_conv1<<<NB*H1, 256, 0, stream>>>(x, w1, out1);
  k_stats_partial<<<C1*8, 256, 0, stream>>>(out1, part1, C1, H1*W1);
  k_stats_final<<<1, 64, 0, stream>>>(part1, stats1, C1, 1.f/((float)NB*H1*W1));
  k_bnelu1<<<NB*4*12, 256, 0, stream>>>(out1, stats1, a1h, a1l);
  k_cvtw<<<256, 256, 0, stream>>>(w2, w3, w2ph, w2pl, w3ph, w3pl);
  k_conv2f<<<NB, 256, 0, stream>>>(a1h, a1l, w2ph, w2pl, pool2raw, part2);
  k_statsN_final<<<1, 256, 0, stream>>>(part2, stats2, NB, 1.f/((float)NB*H2*W2));
  k_bn2<<<18432, 256, 0, stream>>>(pool2raw, stats2, a2h, a2l);
  k_conv3f<<<NB/2, 256, 0, stream>>>(a2h, a2l, w3ph, w3pl, featsraw, part3);
  k_statsN_final<<<1, 256, 0, stream>>>(part3, stats3, NB/2, 1.f/((float)NB*2*W3));
  k_featbn<<<1152, 256, 0, stream>>>(featsraw, stats3, feats);
  k_wtrig<<<1, 64, 0, stream>>>(qw, wtrig);
  k_quantum<<<8192, 256, 0, stream>>>(feats, wtrig, qo);
  k_fc<<<20, 256, 0, stream>>>(qo, fw, fb, out);
}

// Round 3
// 507.071 us; speedup vs baseline: 3.2590x; 1.1046x over previous
//
#include <hip/hip_runtime.h>
#include <math.h>

#define NB 1024
#define C1 16
#define H1 4
#define W1 153
#define WX 216
#define K1 64
#define C2 32
#define H2 4
#define W2 155
#define W192 192
#define PW2 38
#define C3 32
#define W3 38

typedef short short4v __attribute__((ext_vector_type(4)));
typedef short short8 __attribute__((ext_vector_type(8)));
typedef float f32x16 __attribute__((ext_vector_type(16)));

// ---- workspace float offsets
#define OFF_OUT1     0
#define OFF_A1H      10027008
#define OFF_A1L      16318464
#define OFF_W2PH     22609920
#define OFF_W2PL     22626304
#define OFF_W3PH     22642688
#define OFF_W3PL     22659072
#define OFF_UH       22675456
#define OFF_UL       22806528
#define OFF_POOL2RAW 22937600
#define OFF_A2H      25427968
#define OFF_A2L      27787264
#define OFF_FEATSRAW 30146560
#define OFF_QO       30441472
#define OFF_PART1    30736384
#define OFF_PART2    30867456
#define OFF_PART3    30998528
#define OFF_STATS1   31031296
#define OFF_STATS2   31031328
#define OFF_STATS3   31031392

__device__ __forceinline__ float eluf(float x){ return x > 0.f ? x : expm1f(x); }

__device__ __forceinline__ ushort bf16h(float x){
  unsigned u = __float_as_uint(x);
  unsigned r = u + 0x7fffu + ((u >> 16) & 1u);
  return (ushort)(r >> 16);
}
__device__ __forceinline__ float bf16f(ushort h){ return __uint_as_float(((unsigned)h) << 16); }

__device__ __forceinline__ short8 cat8(short4v a, short4v b){
  return __builtin_shufflevector(a, b, 0,1,2,3,4,5,6,7);
}

// ---------------- conv1 + fused BN stats partial
// block = n. wave = h. lane covers w = lane, lane+64, lane+128. 16 co per wave.
__global__ __launch_bounds__(256) void k_conv1s(const float* __restrict__ x,
                                                const float* __restrict__ w1,
                                                float* __restrict__ out1,
                                                float* __restrict__ part1){
  __shared__ float xr[4][WX];
  __shared__ float wl[C1*K1];
  int n = blockIdx.x, tid = threadIdx.x;
  for (int i = tid; i < 4*WX; i += 256) xr[i/WX][i%WX] = x[(size_t)n*4*WX + i];
  for (int i = tid; i < C1*K1; i += 256) wl[i] = w1[i];
  __syncthreads();
  int h = tid >> 6, lane = tid & 63;
  float acc[16][3];
  #pragma unroll
  for (int c = 0; c < 16; ++c){ acc[c][0]=0.f; acc[c][1]=0.f; acc[c][2]=0.f; }
  bool v2 = (lane + 128) < W1;
  for (int k = 0; k < 64; ++k){
    float x0 = xr[h][lane + k];
    float x1 = xr[h][lane + 64 + k];
    float x2 = v2 ? xr[h][lane + 128 + k] : 0.f;
    #pragma unroll
    for (int c = 0; c < 16; ++c){
      float wk = wl[c*64 + k];
      acc[c][0] += wk*x0; acc[c][1] += wk*x1; acc[c][2] += wk*x2;
    }
  }
  float ss[16], sq[16];
  #pragma unroll
  for (int c = 0; c < 16; ++c){
    float* ob = out1 + (((size_t)(n*16 + c)*4 + h))*W1;
    ob[lane] = acc[c][0];
    ob[lane + 64] = acc[c][1];
    if (v2) ob[lane + 128] = acc[c][2];
    ss[c] = acc[c][0] + acc[c][1] + acc[c][2];
    sq[c] = acc[c][0]*acc[c][0] + acc[c][1]*acc[c][1] + acc[c][2]*acc[c][2];
  }
  #pragma unroll
  for (int m = 1; m < 64; m <<= 1){
    #pragma unroll
    for (int c = 0; c < 16; ++c){ ss[c] += __shfl_xor(ss[c], m); sq[c] += __shfl_xor(sq[c], m); }
  }
  if (lane == 0){
    #pragma unroll
    for (int c = 0; c < 16; ++c){
      part1[((size_t)(n*4 + h)*16 + c)*2]     = ss[c];
      part1[((size_t)(n*4 + h)*16 + c)*2 + 1] = sq[c];
    }
  }
}

// ---------------- generic stats finalize: part[nblk][C][2] -> stats[C][2]
__global__ void k_stats_fin(const float* __restrict__ part, float* __restrict__ stats,
                            int C, int nblk, float inv){
  __shared__ float ls[256][2];
  int c = threadIdx.x % C;
  int sl = threadIdx.x / C;
  int slices = 256 / C;
  float s = 0.f, q = 0.f;
  for (int b = sl; b < nblk; b += slices){
    s += part[((size_t)b*C + c)*2];
    q += part[((size_t)b*C + c)*2 + 1];
  }
  ls[threadIdx.x][0] = s; ls[threadIdx.x][1] = q;
  __syncthreads();
  for (int st = 128; st >= C; st >>= 1){
    if (threadIdx.x < st){ ls[threadIdx.x][0] += ls[threadIdx.x+st][0]; ls[threadIdx.x][1] += ls[threadIdx.x+st][1]; }
    __syncthreads();
  }
  if (threadIdx.x < C){
    float mean = ls[threadIdx.x][0]*inv;
    float var  = ls[threadIdx.x][1]*inv - mean*mean;
    stats[threadIdx.x*2]   = mean;
    stats[threadIdx.x*2+1] = rsqrtf(var + 1e-5f);
  }
}

// ---------------- bnelu1: out1 -> a1 bf16 hi/lo, [n][h][w192][ci16], ci swizzled, 2 ci per thread
__global__ void k_bnelu1(const float* __restrict__ out1, const float* __restrict__ stats,
                         ushort* __restrict__ a1h, ushort* __restrict__ a1l){
  int idx = blockIdx.x*256 + threadIdx.x;   // 6,291,456 exact
  int cip = idx & 7; int t = idx >> 3;
  int w = t % 192; t /= 192; int h = t & 3; int n = t >> 2;
  int ci0 = cip*2;
  int ws = w - 16;
  float v0 = 0.f, v1 = 0.f;
  if ((unsigned)ws < (unsigned)W1){
    v0 = eluf((out1[((size_t)(n*16 + ci0  )*4 + h)*W1 + ws] - stats[ci0*2])*stats[ci0*2+1]);
    v1 = eluf((out1[((size_t)(n*16 + ci0+1)*4 + h)*W1 + ws] - stats[(ci0+1)*2])*stats[(ci0+1)*2+1]);
  }
  int ciS0 = ci0 ^ (((w >> 2) & 3) << 2);
  size_t o = ((size_t)(n*4 + h)*W192 + w)*16 + ciS0;
  ushort h0 = bf16h(v0), h1 = bf16h(v1);
  ushort l0 = bf16h(v0 - bf16f(h0)), l1 = bf16h(v1 - bf16f(h1));
  *(unsigned*)(a1h + o) = (unsigned)h0 | ((unsigned)h1 << 16);
  *(unsigned*)(a1l + o) = (unsigned)l0 | ((unsigned)l1 << 16);
}

// ---------------- weight convert+permute
__global__ void k_cvtw(const float* __restrict__ w2, const float* __restrict__ w3,
                       ushort* __restrict__ w2ph, ushort* __restrict__ w2pl,
                       ushort* __restrict__ w3ph, ushort* __restrict__ w3pl){
  int idx = blockIdx.x*256 + threadIdx.x;
  if (idx < 32768){
    int ci = idx & 15; int co = (idx >> 4) & 31; int rk = idx >> 9;
    int r = rk >> 5, kw = rk & 31;
    float v = w2[((size_t)(co*16 + ci)*2 + r)*32 + kw];
    ushort hs = bf16h(v); float hf = bf16f(hs);
    w2ph[idx] = hs; w2pl[idx] = bf16h(v - hf);
  } else {
    int j = idx - 32768;
    int ci = j & 31; int co = (j >> 5) & 31; int rk = j >> 10;
    int r = rk >> 2, kw = rk & 3;
    float v = w3[((size_t)(co*32 + ci)*8 + r)*4 + kw];
    ushort hs = bf16h(v); float hf = bf16f(hs);
    w3ph[j] = hs; w3pl[j] = bf16h(v - hf);
  }
}

// ---------------- fused conv2 (MFMA 3-term bf16) + stats partial + maxpool(2,4)
// block = (n, ph). 2 waves: h = 2ph+wv. Stage rows 2ph..2ph+2 only.
__global__ __launch_bounds__(128) void k_conv2f(const ushort* __restrict__ a1h,
                                                const ushort* __restrict__ a1l,
                                                const ushort* __restrict__ w2ph,
                                                const ushort* __restrict__ w2pl,
                                                float* __restrict__ pool2raw,
                                                float* __restrict__ part2){
  __shared__ ushort s_hi[3*3072];
  __shared__ ushort s_lo[3*3072];
  __shared__ float poolL[2][32][40];
  __shared__ float statL[2][32][2];
  int b = blockIdx.x;
  int n = b >> 1, ph = b & 1;
  int tid = threadIdx.x;
  int row0 = 2*ph;
  int nrows = ph ? 2 : 3;
  {
    const float4* gh = (const float4*)(a1h + ((size_t)n*4 + row0)*3072);
    const float4* gl = (const float4*)(a1l + ((size_t)n*4 + row0)*3072);
    float4* dh = (float4*)s_hi;
    float4* dl = (float4*)s_lo;
    int cnt = nrows*384;
    for (int i = tid; i < cnt; i += 128){ dh[i] = gh[i]; dl[i] = gl[i]; }
  }
  __syncthreads();
  int wv = tid >> 6, lane = tid & 63;
  int h = 2*ph + wv;
  int l5 = lane >> 5, l31 = lane & 31;

  f32x16 acc[5];
  #pragma unroll
  for (int p = 0; p < 5; ++p)
    #pragma unroll
    for (int e = 0; e < 16; ++e) acc[p][e] = 0.f;

  int rmax = (h == 3) ? 1 : 2;
  for (int r = 0; r < rmax; ++r){
    int rb = (wv + r)*3072;
    for (int kw = 0; kw < 32; ++kw){
      int widx = (((r << 5) + kw)*32 + l31)*16 + l5*4;
      short8 Ah = cat8(*(const short4v*)(w2ph + widx), *(const short4v*)(w2ph + widx + 8));
      short8 Al = cat8(*(const short4v*)(w2pl + widx), *(const short4v*)(w2pl + widx + 8));
      short8 Bh[5], Bl[5];
      #pragma unroll
      for (int p = 0; p < 5; ++p){
        int pos = p*32 + l31 + kw;
        int sw = ((pos >> 2) & 3) << 2;
        int off0 = rb + pos*16 + ((l5*4) ^ sw);
        int off1 = rb + pos*16 + ((l5*4 + 8) ^ sw);
        Bh[p] = cat8(*(const short4v*)(s_hi + off0), *(const short4v*)(s_hi + off1));
        Bl[p] = cat8(*(const short4v*)(s_lo + off0), *(const short4v*)(s_lo + off1));
      }
      #pragma unroll
      for (int p = 0; p < 5; ++p) acc[p] = __builtin_amdgcn_mfma_f32_32x32x16_bf16(Ah, Bh[p], acc[p], 0, 0, 0);
      #pragma unroll
      for (int p = 0; p < 5; ++p) acc[p] = __builtin_amdgcn_mfma_f32_32x32x16_bf16(Ah, Bl[p], acc[p], 0, 0, 0);
      #pragma unroll
      for (int p = 0; p < 5; ++p) acc[p] = __builtin_amdgcn_mfma_f32_32x32x16_bf16(Al, Bh[p], acc[p], 0, 0, 0);
    }
  }

  // stats partial (mask pos>=155): C/D map col=l31, row=(e&3)+8*(e>>2)+4*l5
  {
    float sreg[16], qreg[16];
    #pragma unroll
    for (int e = 0; e < 16; ++e){ sreg[e] = 0.f; qreg[e] = 0.f; }
    #pragma unroll
    for (int p = 0; p < 5; ++p){
      bool pv = (p < 4) || (l31 < 27);
      #pragma unroll
      for (int e = 0; e < 16; ++e){
        float v = pv ? acc[p][e] : 0.f;
        sreg[e] += v; qreg[e] += v*v;
      }
    }
    #pragma unroll
    for (int m = 1; m < 32; m <<= 1){
      #pragma unroll
      for (int e = 0; e < 16; ++e){
        sreg[e] += __shfl_xor(sreg[e], m);
        qreg[e] += __shfl_xor(qreg[e], m);
      }
    }
    if (l31 == 0){
      #pragma unroll
      for (int e = 0; e < 16; ++e){
        int co = (e & 3) + ((e >> 2) << 3) + (l5 << 2);
        statL[wv][co][0] = sreg[e];
        statL[wv][co][1] = qreg[e];
      }
    }
  }
  // per-wave pooled max over w quads
  #pragma unroll
  for (int p = 0; p < 5; ++p){
    #pragma unroll
    for (int e = 0; e < 16; ++e){
      float v = acc[p][e];
      float v1 = fmaxf(v, __shfl_xor(v, 1));
      float v2m = fmaxf(v1, __shfl_xor(v1, 2));
      int pw = p*8 + (l31 >> 2);
      if ((l31 & 3) == 0 && pw < PW2){
        int co = (e & 3) + ((e >> 2) << 3) + (l5 << 2);
        poolL[wv][co][pw] = v2m;
      }
    }
  }
  __syncthreads();
  for (int i = tid; i < 32*PW2; i += 128){
    int pw = i % PW2; int co = i / PW2;
    float v = fmaxf(poolL[0][co][pw], poolL[1][co][pw]);
    pool2raw[(((size_t)n*2 + ph)*32 + co)*PW2 + pw] = v;
  }
  if (tid < 32){
    float s = statL[0][tid][0] + statL[1][tid][0];
    float q = statL[0][tid][1] + statL[1][tid][1];
    part2[((size_t)(n*2 + ph)*32 + tid)*2]     = s;
    part2[((size_t)(n*2 + ph)*32 + tid)*2 + 1] = q;
  }
}

// ---------------- bn2: pool2raw -> a2 bf16 hi/lo, [n][hr2][w72][ci32], swizzled
__global__ void k_bn2(const float* __restrict__ pool2raw, const float* __restrict__ stats,
                      ushort* __restrict__ a2h, ushort* __restrict__ a2l){
  int idx = blockIdx.x*256 + threadIdx.x;  // 4,718,592 exact
  int ci = idx & 31; int t = idx >> 5;
  int w = t % 72; t /= 72; int hr = t & 1; int n = t >> 1;
  float v = 0.f;
  int pw = w - 2;
  if ((unsigned)pw < (unsigned)PW2){
    float xx = pool2raw[(((size_t)n*2 + hr)*32 + ci)*PW2 + pw];
    v = eluf((xx - stats[ci*2]) * stats[ci*2+1]);
  }
  int ciS = ci ^ (((w >> 1) & 7) << 2);
  size_t o = (((size_t)n*2 + hr)*72 + w)*32 + ciS;
  ushort hs = bf16h(v); float hf = bf16f(hs);
  a2h[o] = hs; a2l[o] = bf16h(v - hf);
}

// ---------------- fused conv3 (MFMA 3-term bf16) + stats partial + maxpool(2,4)
__global__ __launch_bounds__(256, 2) void k_conv3f(const ushort* __restrict__ a2h,
                                                   const ushort* __restrict__ a2l,
                                                   const ushort* __restrict__ w3ph,
                                                   const ushort* __restrict__ w3pl,
                                                   float* __restrict__ featsraw,
                                                   float* __restrict__ part3){
  __shared__ ushort s3h[9216];
  __shared__ ushort s3l[9216];
  __shared__ float poolL3[4][32][12];
  __shared__ float statL3[4][32][2];
  int nb = blockIdx.x;
  int tid = threadIdx.x;
  {
    const float4* gh = (const float4*)(a2h + (size_t)nb*9216);
    const float4* gl = (const float4*)(a2l + (size_t)nb*9216);
    float4* dh = (float4*)s3h;
    float4* dl = (float4*)s3l;
    for (int i = tid; i < 1152; i += 256){ dh[i] = gh[i]; dl[i] = gl[i]; }
  }
  __syncthreads();
  int wave = tid >> 6, lane = tid & 63;
  int nh = wave >> 1, h = wave & 1;
  int l5 = lane >> 5, l31 = lane & 31;

  f32x16 acc[2];
  #pragma unroll
  for (int p = 0; p < 2; ++p)
    #pragma unroll
    for (int e = 0; e < 16; ++e) acc[p][e] = 0.f;

  #pragma unroll
  for (int ri = 0; ri < 2; ++ri){
    int r = (h == 0) ? (4 + ri) : (3 + ri);
    int rbase = (nh*2 + ri)*72*32;
    #pragma unroll
    for (int kw = 0; kw < 4; ++kw){
      #pragma unroll
      for (int ch = 0; ch < 2; ++ch){
        int widx = ((r*4 + kw)*32 + l31)*32 + ch*16 + l5*4;
        short8 Ah = cat8(*(const short4v*)(w3ph + widx), *(const short4v*)(w3ph + widx + 8));
        short8 Al = cat8(*(const short4v*)(w3pl + widx), *(const short4v*)(w3pl + widx + 8));
        short8 Bh[2], Bl[2];
        #pragma unroll
        for (int p = 0; p < 2; ++p){
          int pos = p*32 + l31 + kw;
          int sw = ((pos >> 1) & 7) << 2;
          int s0 = ch*16 + l5*4;
          int off0 = rbase + pos*32 + (s0 ^ sw);
          int off1 = rbase + pos*32 + ((s0 + 8) ^ sw);
          Bh[p] = cat8(*(const short4v*)(s3h + off0), *(const short4v*)(s3h + off1));
          Bl[p] = cat8(*(const short4v*)(s3l + off0), *(const short4v*)(s3l + off1));
        }
        #pragma unroll
        for (int p = 0; p < 2; ++p) acc[p] = __builtin_amdgcn_mfma_f32_32x32x16_bf16(Ah, Bh[p], acc[p], 0, 0, 0);
        #pragma unroll
        for (int p = 0; p < 2; ++p) acc[p] = __builtin_amdgcn_mfma_f32_32x32x16_bf16(Ah, Bl[p], acc[p], 0, 0, 0);
        #pragma unroll
        for (int p = 0; p < 2; ++p) acc[p] = __builtin_amdgcn_mfma_f32_32x32x16_bf16(Al, Bh[p], acc[p], 0, 0, 0);
      }
    }
  }

  {
    float sreg[16], qreg[16];
    #pragma unroll
    for (int e = 0; e < 16; ++e){ sreg[e] = 0.f; qreg[e] = 0.f; }
    #pragma unroll
    for (int p = 0; p < 2; ++p){
      bool pv = (p == 0) || (l31 < 6);
      #pragma unroll
      for (int e = 0; e < 16; ++e){
        float v = pv ? acc[p][e] : 0.f;
        sreg[e] += v; qreg[e] += v*v;
      }
    }
    #pragma unroll
    for (int m = 1; m < 32; m <<= 1){
      #pragma unroll
      for (int e = 0; e < 16; ++e){
        sreg[e] += __shfl_xor(sreg[e], m);
        qreg[e] += __shfl_xor(qreg[e], m);
      }
    }
    if (l31 == 0){
      #pragma unroll
      for (int e = 0; e < 16; ++e){
        int co = (e & 3) + ((e >> 2) << 3) + (l5 << 2);
        statL3[wave][co][0] = sreg[e];
        statL3[wave][co][1] = qreg[e];
      }
    }
  }
  #pragma unroll
  for (int p = 0; p < 2; ++p){
    #pragma unroll
    for (int e = 0; e < 16; ++e){
      float v = acc[p][e];
      float v1 = fmaxf(v, __shfl_xor(v, 1));
      float v2m = fmaxf(v1, __shfl_xor(v1, 2));
      int pw = p*8 + (l31 >> 2);
      if ((l31 & 3) == 0 && pw < 9){
        int co = (e & 3) + ((e >> 2) << 3) + (l5 << 2);
        poolL3[wave][co][pw] = v2m;
      }
    }
  }
  __syncthreads();
  for (int i = tid; i < 2*32*9; i += 256){
    int pw = i % 9; int t = i / 9; int co = t & 31; int nh2 = t >> 5;
    float v = fmaxf(poolL3[nh2*2][co][pw], poolL3[nh2*2+1][co][pw]);
    featsraw[((size_t)(nb*2 + nh2)*32 + co)*9 + pw] = v;
  }
  if (tid < 32){
    float s = 0.f, q = 0.f;
    #pragma unroll
    for (int wv = 0; wv < 4; ++wv){ s += statL3[wv][tid][0]; q += statL3[wv][tid][1]; }
    part3[((size_t)nb*32 + tid)*2]     = s;
    part3[((size_t)nb*32 + tid)*2 + 1] = q;
  }
}

// ---------------- build U (512x512) by running the fixed circuit on basis states
// wave = basis column k. state s: bits[8:3]=lane, bits[2:0]=reg.
__global__ __launch_bounds__(256) void k_buildU(const float* __restrict__ qw,
                                                ushort* __restrict__ Uh, ushort* __restrict__ Ul){
  __shared__ float wt[36][2];
  int tid = threadIdx.x;
  if (tid < 36){ float s, c; sincosf(qw[tid]*0.5f, &s, &c); wt[tid][0] = c; wt[tid][1] = s; }
  __syncthreads();
  int wid = tid >> 6, lane = tid & 63;
  int k = blockIdx.x*4 + wid;
  float v[8];
  #pragma unroll
  for (int r = 0; r < 8; ++r) v[r] = (lane*8 + r == k) ? 1.f : 0.f;

  for (int j = 0; j < 4; ++j){
    #pragma unroll
    for (int i = 0; i < 5; ++i){
      int cm = 32>>i, tm = 16>>i;
      bool flip = (lane & cm) != 0;
      #pragma unroll
      for (int r = 0; r < 8; ++r){
        float w = __shfl_xor(v[r], tm);
        v[r] = flip ? w : v[r];
      }
    }
    { bool flip = (lane & 1) != 0;
      #pragma unroll
      for (int r = 0; r < 4; ++r){ float a = v[r], bb = v[r+4]; v[r] = flip?bb:a; v[r+4] = flip?a:bb; } }
    { float t = v[4]; v[4] = v[6]; v[6] = t; t = v[5]; v[5] = v[7]; v[7] = t; }
    { float t = v[2]; v[2] = v[3]; v[3] = t; t = v[6]; v[6] = v[7]; v[7] = t; }
    #pragma unroll
    for (int r = 1; r < 8; r += 2) v[r] = __shfl_xor(v[r], 32);

    #pragma unroll
    for (int i = 0; i < 6; ++i){
      float c = wt[j*9+i][0], s = wt[j*9+i][1];
      int m = 32>>i;
      float sg = (lane & m) ? s : -s;
      #pragma unroll
      for (int r = 0; r < 8; ++r){
        float w = __shfl_xor(v[r], m);
        v[r] = c*v[r] + sg*w;
      }
    }
    { float c = wt[j*9+6][0], s = wt[j*9+6][1];
      #pragma unroll
      for (int r = 0; r < 4; ++r){ float a = v[r], bb = v[r+4]; v[r] = c*a - s*bb; v[r+4] = s*a + c*bb; } }
    { float c = wt[j*9+7][0], s = wt[j*9+7][1]; float a, bb;
      a=v[0]; bb=v[2]; v[0]=c*a-s*bb; v[2]=s*a+c*bb;
      a=v[1]; bb=v[3]; v[1]=c*a-s*bb; v[3]=s*a+c*bb;
      a=v[4]; bb=v[6]; v[4]=c*a-s*bb; v[6]=s*a+c*bb;
      a=v[5]; bb=v[7]; v[5]=c*a-s*bb; v[7]=s*a+c*bb; }
    { float c = wt[j*9+8][0], s = wt[j*9+8][1]; float a, bb;
      a=v[0]; bb=v[1]; v[0]=c*a-s*bb; v[1]=s*a+c*bb;
      a=v[2]; bb=v[3]; v[2]=c*a-s*bb; v[3]=s*a+c*bb;
      a=v[4]; bb=v[5]; v[4]=c*a-s*bb; v[5]=s*a+c*bb;
      a=v[6]; bb=v[7]; v[6]=c*a-s*bb; v[7]=s*a+c*bb; }
  }
  // store in MFMA-A layout: [kstep][mfrag][row32][k16]
  #pragma unroll
  for (int r = 0; r < 8; ++r){
    int s = lane*8 + r;
    int mf = s >> 5, r31 = s & 31;
    int addr = (((k >> 4)*16 + mf)*32 + r31)*16 + (k & 15);
    float f = v[r];
    ushort hi = bf16h(f);
    Uh[addr] = hi;
    Ul[addr] = bf16h(f - bf16f(hi));
  }
}

// ---------------- quantum GEMM: state = U @ b(sample), fused BN+ELU + <Z> epilogue
// block = 64 samples. M=512 (16 mfrags, 4/wave), K=512 (32 ksteps), N=64 (2 nfrags).
__global__ __launch_bounds__(256, 1) void k_qgemm(const float* __restrict__ featsraw,
                                                  const float* __restrict__ stats,
                                                  const ushort* __restrict__ Uh,
                                                  const ushort* __restrict__ Ul,
                                                  float* __restrict__ qo){
  __shared__ ushort BhL[32768];
  __shared__ ushort BlL[32768];
  __shared__ float angL[576];
  __shared__ float zred[4][64][9];
  int nb = blockIdx.x;
  int tid = threadIdx.x;
  for (int t = tid; t < 576; t += 256){
    float vr = featsraw[(size_t)nb*576 + t];
    int c = (t/9) & 31;
    angL[t] = 0.5f * eluf((vr - stats[c*2])*stats[c*2+1]);
  }
  __syncthreads();
  // build B: product-state amplitudes, bf16 hi/lo, swizzled [kstep][sm][k16]
  {
    int sm = tid >> 2, q = tid & 3;
    float tc[9], ts[9];
    #pragma unroll
    for (int i = 0; i < 9; ++i) sincosf(angL[sm*9 + i], &ts[i], &tc[i]);
    float Pc = ((q & 2) ? ts[0] : tc[0]) * ((q & 1) ? ts[1] : tc[1]);
    int swz = (sm >> 2) & 3;
    short4v* bh4 = (short4v*)BhL;
    short4v* bl4 = (short4v*)BlL;
    int j = 0;
    #pragma unroll
    for (int b2 = 0; b2 < 2; ++b2){ float p2 = Pc*(b2 ? ts[2] : tc[2]);
    #pragma unroll
    for (int b3 = 0; b3 < 2; ++b3){ float p3 = p2*(b3 ? ts[3] : tc[3]);
    #pragma unroll
    for (int b4 = 0; b4 < 2; ++b4){ float p4 = p3*(b4 ? ts[4] : tc[4]);
    #pragma unroll
    for (int b5 = 0; b5 < 2; ++b5){ float p5 = p4*(b5 ? ts[5] : tc[5]);
    #pragma unroll
    for (int b6 = 0; b6 < 2; ++b6){ float p6 = p5*(b6 ? ts[6] : tc[6]);
      float a0 = p6*tc[7]*tc[8];
      float a1 = p6*tc[7]*ts[8];
      float a2 = p6*ts[7]*tc[8];
      float a3 = p6*ts[7]*ts[8];
      ushort h0 = bf16h(a0), h1 = bf16h(a1), h2 = bf16h(a2), h3 = bf16h(a3);
      short4v hv; hv[0]=(short)h0; hv[1]=(short)h1; hv[2]=(short)h2; hv[3]=(short)h3;
      short4v lv; lv[0]=(short)bf16h(a0 - bf16f(h0)); lv[1]=(short)bf16h(a1 - bf16f(h1));
                  lv[2]=(short)bf16h(a2 - bf16f(h2)); lv[3]=(short)bf16h(a3 - bf16f(h3));
      int kk = q*128 + j;
      int kstep = kk >> 4;
      int g = (kk >> 2) & 3;
      int idx4 = (kstep*64 + sm)*4 + (g ^ swz);
      bh4[idx4] = hv; bl4[idx4] = lv;
      j += 4;
    }}}}}
  }
  __syncthreads();
  int wv = tid >> 6, lane = tid & 63, l5 = lane >> 5, l31 = lane & 31;
  f32x16 acc[4][2];
  #pragma unroll
  for (int jj = 0; jj < 4; ++jj)
    #pragma unroll
    for (int nf = 0; nf < 2; ++nf)
      #pragma unroll
      for (int e = 0; e < 16; ++e) acc[jj][nf][e] = 0.f;

  for (int kstep = 0; kstep < 32; ++kstep){
    short8 Bh[2], Bl[2];
    #pragma unroll
    for (int nf = 0; nf < 2; ++nf){
      int sm = nf*32 + l31;
      int base = (kstep*64 + sm)*16;
      int sz = ((sm >> 2) & 3) << 2;
      int e0 = (l5*4) ^ sz;
      int e1 = (l5*4 + 8) ^ sz;
      Bh[nf] = cat8(*(const short4v*)(BhL + base + e0), *(const short4v*)(BhL + base + e1));
      Bl[nf] = cat8(*(const short4v*)(BlL + base + e0), *(const short4v*)(BlL + base + e1));
    }
    #pragma unroll
    for (int jj = 0; jj < 4; ++jj){
      int mf = wv*4 + jj;
      const ushort* ah = Uh + ((kstep*16 + mf)*32 + l31)*16 + l5*4;
      const ushort* al = Ul + ((kstep*16 + mf)*32 + l31)*16 + l5*4;
      short8 Ah = cat8(*(const short4v*)ah, *(const short4v*)(ah + 8));
      short8 Al = cat8(*(const short4v*)al, *(const short4v*)(al + 8));
      acc[jj][0] = __builtin_amdgcn_mfma_f32_32x32x16_bf16(Ah, Bh[0], acc[jj][0], 0, 0, 0);
      acc[jj][1] = __builtin_amdgcn_mfma_f32_32x32x16_bf16(Ah, Bh[1], acc[jj][1], 0, 0, 0);
      acc[jj][0] = __builtin_amdgcn_mfma_f32_32x32x16_bf16(Ah, Bl[0], acc[jj][0], 0, 0, 0);
      acc[jj][1] = __builtin_amdgcn_mfma_f32_32x32x16_bf16(Ah, Bl[1], acc[jj][1], 0, 0, 0);
      acc[jj][0] = __builtin_amdgcn_mfma_f32_32x32x16_bf16(Al, Bh[0], acc[jj][0], 0, 0, 0);
      acc[jj][1] = __builtin_amdgcn_mfma_f32_32x32x16_bf16(Al, Bh[1], acc[jj][1], 0, 0, 0);
    }
  }
  // <Z_i> epilogue: row s = mf*32 + (e&3) + 8*(e>>2) + 4*l5; wire i <-> bit (8-i) of s
  float zz[2][9];
  #pragma unroll
  for (int nf = 0; nf < 2; ++nf)
    #pragma unroll
    for (int i = 0; i < 9; ++i) zz[nf][i] = 0.f;
  #pragma unroll
  for (int jj = 0; jj < 4; ++jj){
    int mf = wv*4 + jj;
    float sg0 = (mf & 8) ? -1.f : 1.f;
    float sg1 = (mf & 4) ? -1.f : 1.f;
    float sg2 = (mf & 2) ? -1.f : 1.f;
    float sg3 = (mf & 1) ? -1.f : 1.f;
    #pragma unroll
    for (int nf = 0; nf < 2; ++nf){
      float psum = 0.f, z4 = 0.f, z5 = 0.f, z7 = 0.f, z8 = 0.f;
      #pragma unroll
      for (int e = 0; e < 16; ++e){
        float qv = acc[jj][nf][e]*acc[jj][nf][e];
        psum += qv;
        z4 += ((e >> 3) & 1) ? -qv : qv;
        z5 += ((e >> 2) & 1) ? -qv : qv;
        z7 += ((e >> 1) & 1) ? -qv : qv;
        z8 += (e & 1) ? -qv : qv;
      }
      zz[nf][0] += sg0*psum; zz[nf][1] += sg1*psum;
      zz[nf][2] += sg2*psum; zz[nf][3] += sg3*psum;
      zz[nf][4] += z4; zz[nf][5] += z5;
      zz[nf][6] += l5 ? -psum : psum;
      zz[nf][7] += z7; zz[nf][8] += z8;
    }
  }
  #pragma unroll
  for (int nf = 0; nf < 2; ++nf)
    #pragma unroll
    for (int i = 0; i < 9; ++i) zz[nf][i] += __shfl_xor(zz[nf][i], 32);
  if (l5 == 0){
    #pragma unroll
    for (int nf = 0; nf < 2; ++nf)
      #pragma unroll
      for (int i = 0; i < 9; ++i) zred[wv][nf*32 + l31][i] = zz[nf][i];
  }
  __syncthreads();
  for (int t = tid; t < 576; t += 256){
    int sm = t / 9, i = t - sm*9;
    float s = zred[0][sm][i] + zred[1][sm][i] + zred[2][sm][i] + zred[3][sm][i];
    qo[(size_t)(nb*64 + sm)*9 + i] = s;
  }
}

// ---------------- fc: (1024,288) @ (5,288)^T + b
__global__ void k_fc(const float* __restrict__ q, const float* __restrict__ fw,
                     const float* __restrict__ fb, float* __restrict__ out){
  int idx = blockIdx.x*256 + threadIdx.x;
  if (idx >= NB*5) return;
  int b = idx / 5, o = idx - b*5;
  const float* qr = q + (size_t)b*288;
  const float* wr = fw + (size_t)o*288;
  float s = 0.f;
  for (int j = 0; j < 288; ++j) s += qr[j]*wr[j];
  out[idx] = s + fb[o];
}

extern "C" void kernel_launch(void* const* d_in, const int* in_sizes, int n_in,
                              void* d_out, int out_size, void* d_ws, size_t ws_size,
                              hipStream_t stream){
  const float* x  = (const float*)d_in[0];
  const float* w1 = (const float*)d_in[1];
  const float* w2 = (const float*)d_in[2];
  const float* w3 = (const float*)d_in[3];
  const float* qw = (const float*)d_in[4];
  const float* fw = (const float*)d_in[5];
  const float* fb = (const float*)d_in[6];
  float* out = (float*)d_out;
  float* W = (float*)d_ws;

  float*  out1   = W + OFF_OUT1;
  ushort* a1h    = (ushort*)(W + OFF_A1H);
  ushort* a1l    = (ushort*)(W + OFF_A1L);
  ushort* w2ph   = (ushort*)(W + OFF_W2PH);
  ushort* w2pl   = (ushort*)(W + OFF_W2PL);
  ushort* w3ph   = (ushort*)(W + OFF_W3PH);
  ushort* w3pl   = (ushort*)(W + OFF_W3PL);
  ushort* uH     = (ushort*)(W + OFF_UH);
  ushort* uL     = (ushort*)(W + OFF_UL);
  float*  pool2raw = W + OFF_POOL2RAW;
  ushort* a2h    = (ushort*)(W + OFF_A2H);
  ushort* a2l    = (ushort*)(W + OFF_A2L);
  float*  featsraw = W + OFF_FEATSRAW;
  float*  qo     = W + OFF_QO;
  float*  part1  = W + OFF_PART1;
  float*  part2  = W + OFF_PART2;
  float*  part3  = W + OFF_PART3;
  float*  stats1 = W + OFF_STATS1;
  float*  stats2 = W + OFF_STATS2;
  float*  stats3 = W + OFF_STATS3;

  k_conv1s<<<NB, 256, 0, stream>>>(x, w1, out1, part1);
  k_stats_fin<<<1, 256, 0, stream>>>(part1, stats1, 16, NB*4, 1.f/((float)NB*H1*W1));
  k_bnelu1<<<24576, 256, 0, stream>>>(out1, stats1, a1h, a1l);
  k_cvtw<<<256, 256, 0, stream>>>(w2, w3, w2ph, w2pl, w3ph, w3pl);
  k_buildU<<<128, 256, 0, stream>>>(qw, uH, uL);
  k_conv2f<<<NB*2, 128, 0, stream>>>(a1h, a1l, w2ph, w2pl, pool2raw, part2);
  k_stats_fin<<<1, 256, 0, stream>>>(part2, stats2, 32, NB*2, 1.f/((float)NB*H2*W2));
  k_bn2<<<18432, 256, 0, stream>>>(pool2raw, stats2, a2h, a2l);
  k_conv3f<<<NB/2, 256, 0, stream>>>(a2h, a2l, w3ph, w3pl, featsraw, part3);
  k_stats_fin<<<1, 256, 0, stream>>>(part3, stats3, 32, NB/2, 1.f/((float)NB*2*W3));
  k_qgemm<<<NB/2, 256, 0, stream>>>(featsraw, stats3, uH, uL, qo);
  k_fc<<<20, 256, 0, stream>>>(qo, fw, fb, out);
}

// Round 4
// 376.460 us; speedup vs baseline: 4.3898x; 1.3469x over previous
//
#include <hip/hip_runtime.h>
#include <math.h>

#define NB 1024
#define C1 16
#define H1 4
#define W1 153
#define WX 216
#define K1 64
#define C2 32
#define H2 4
#define W2 155
#define W192 192
#define PW2 38
#define C3 32
#define W3 38

typedef short short4v __attribute__((ext_vector_type(4)));
typedef short short8 __attribute__((ext_vector_type(8)));
typedef float f32x16 __attribute__((ext_vector_type(16)));

// ---- workspace float offsets
#define OFF_OUT1     0
#define OFF_A1H      10027008
#define OFF_A1L      16318464
#define OFF_W2PH     22609920
#define OFF_W2PL     22626304
#define OFF_W3PH     22642688
#define OFF_W3PL     22659072
#define OFF_UH       22675456
#define OFF_UL       22806528
#define OFF_POOL2RAW 22937600
#define OFF_A2H      25427968
#define OFF_A2L      27787264
#define OFF_FEATSRAW 30146560
#define OFF_QO       30441472
#define OFF_PART1    30736384
#define OFF_PART2    30867456
#define OFF_PART3    30998528
#define OFF_STATS1   31031296
#define OFF_STATS2   31031328
#define OFF_STATS3   31031392

__device__ __forceinline__ float eluf(float x){ return x > 0.f ? x : expm1f(x); }

__device__ __forceinline__ ushort bf16h(float x){
  unsigned u = __float_as_uint(x);
  unsigned r = u + 0x7fffu + ((u >> 16) & 1u);
  return (ushort)(r >> 16);
}
__device__ __forceinline__ float bf16f(ushort h){ return __uint_as_float(((unsigned)h) << 16); }

__device__ __forceinline__ short8 cat8(short4v a, short4v b){
  return __builtin_shufflevector(a, b, 0,1,2,3,4,5,6,7);
}

// ---------------- conv1 + fused BN stats partial
__global__ __launch_bounds__(256) void k_conv1s(const float* __restrict__ x,
                                                const float* __restrict__ w1,
                                                float* __restrict__ out1,
                                                float* __restrict__ part1){
  __shared__ float xr[4][WX];
  __shared__ float wl[C1*K1];
  int n = blockIdx.x, tid = threadIdx.x;
  for (int i = tid; i < 4*WX; i += 256) xr[i/WX][i%WX] = x[(size_t)n*4*WX + i];
  for (int i = tid; i < C1*K1; i += 256) wl[i] = w1[i];
  __syncthreads();
  int h = tid >> 6, lane = tid & 63;
  float acc[16][3];
  #pragma unroll
  for (int c = 0; c < 16; ++c){ acc[c][0]=0.f; acc[c][1]=0.f; acc[c][2]=0.f; }
  bool v2 = (lane + 128) < W1;
  for (int k = 0; k < 64; ++k){
    float x0 = xr[h][lane + k];
    float x1 = xr[h][lane + 64 + k];
    float x2 = v2 ? xr[h][lane + 128 + k] : 0.f;
    #pragma unroll
    for (int c = 0; c < 16; ++c){
      float wk = wl[c*64 + k];
      acc[c][0] += wk*x0; acc[c][1] += wk*x1; acc[c][2] += wk*x2;
    }
  }
  float ss[16], sq[16];
  #pragma unroll
  for (int c = 0; c < 16; ++c){
    float* ob = out1 + (((size_t)(n*16 + c)*4 + h))*W1;
    ob[lane] = acc[c][0];
    ob[lane + 64] = acc[c][1];
    if (v2) ob[lane + 128] = acc[c][2];
    ss[c] = acc[c][0] + acc[c][1] + acc[c][2];
    sq[c] = acc[c][0]*acc[c][0] + acc[c][1]*acc[c][1] + acc[c][2]*acc[c][2];
  }
  #pragma unroll
  for (int m = 1; m < 64; m <<= 1){
    #pragma unroll
    for (int c = 0; c < 16; ++c){ ss[c] += __shfl_xor(ss[c], m); sq[c] += __shfl_xor(sq[c], m); }
  }
  if (lane == 0){
    #pragma unroll
    for (int c = 0; c < 16; ++c){
      part1[((size_t)(n*4 + h)*16 + c)*2]     = ss[c];
      part1[((size_t)(n*4 + h)*16 + c)*2 + 1] = sq[c];
    }
  }
}

// ---------------- parallel stats finalize: grid = C blocks
__global__ __launch_bounds__(256) void k_stats_finP(const float* __restrict__ part,
                                                    float* __restrict__ stats,
                                                    int C, int nblk, float inv){
  __shared__ float rs[256], rq[256];
  int c = blockIdx.x;
  float s = 0.f, q = 0.f;
  for (int b = threadIdx.x; b < nblk; b += 256){
    s += part[((size_t)b*C + c)*2];
    q += part[((size_t)b*C + c)*2 + 1];
  }
  rs[threadIdx.x] = s; rq[threadIdx.x] = q; __syncthreads();
  for (int st = 128; st > 0; st >>= 1){
    if (threadIdx.x < st){ rs[threadIdx.x] += rs[threadIdx.x+st]; rq[threadIdx.x] += rq[threadIdx.x+st]; }
    __syncthreads();
  }
  if (threadIdx.x == 0){
    float mean = rs[0]*inv;
    float var  = rq[0]*inv - mean*mean;
    stats[c*2]   = mean;
    stats[c*2+1] = rsqrtf(var + 1e-5f);
  }
}

// ---------------- bnelu1: LDS-staged coalesced. block=(n,h)
__global__ __launch_bounds__(256) void k_bnelu1(const float* __restrict__ out1,
                                                const float* __restrict__ stats,
                                                ushort* __restrict__ a1h, ushort* __restrict__ a1l){
  __shared__ float xf[2448];   // 16ci x 153w
  __shared__ float st[32];
  int b = blockIdx.x;          // = n*4 + h
  int n = b >> 2, h = b & 3;
  int tid = threadIdx.x;
  if (tid < 32) st[tid] = stats[tid];
  for (int i = tid; i < 2448; i += 256){
    int ci = i / 153, w = i - ci*153;
    xf[i] = out1[((size_t)(n*16 + ci)*4 + h)*W1 + w];
  }
  __syncthreads();
  for (int i = tid; i < 3072; i += 256){
    int w = i >> 4, ci = i & 15;
    float v = 0.f;
    int ws = w - 16;
    if ((unsigned)ws < (unsigned)W1){
      float xx = xf[ci*153 + ws];
      v = eluf((xx - st[ci*2])*st[ci*2+1]);
    }
    int ciS = ci ^ (((w >> 2) & 3) << 2);
    size_t o = (size_t)b*3072 + w*16 + ciS;
    ushort hs = bf16h(v);
    a1h[o] = hs;
    a1l[o] = bf16h(v - bf16f(hs));
  }
}

// ---------------- weight convert+permute
__global__ void k_cvtw(const float* __restrict__ w2, const float* __restrict__ w3,
                       ushort* __restrict__ w2ph, ushort* __restrict__ w2pl,
                       ushort* __restrict__ w3ph, ushort* __restrict__ w3pl){
  int idx = blockIdx.x*256 + threadIdx.x;
  if (idx < 32768){
    int ci = idx & 15; int co = (idx >> 4) & 31; int rk = idx >> 9;
    int r = rk >> 5, kw = rk & 31;
    float v = w2[((size_t)(co*16 + ci)*2 + r)*32 + kw];
    ushort hs = bf16h(v); float hf = bf16f(hs);
    w2ph[idx] = hs; w2pl[idx] = bf16h(v - hf);
  } else {
    int j = idx - 32768;
    int ci = j & 31; int co = (j >> 5) & 31; int rk = j >> 10;
    int r = rk >> 2, kw = rk & 3;
    float v = w3[((size_t)(co*32 + ci)*8 + r)*4 + kw];
    ushort hs = bf16h(v); float hf = bf16f(hs);
    w3ph[j] = hs; w3pl[j] = bf16h(v - hf);
  }
}

// ---------------- fused conv2 (MFMA 3-term bf16) + stats partial + maxpool(2,4)
// block = (n, ph). 2 waves. poolL aliased into staging LDS after a barrier.
__global__ __launch_bounds__(128) void k_conv2f(const ushort* __restrict__ a1h,
                                                const ushort* __restrict__ a1l,
                                                const ushort* __restrict__ w2ph,
                                                const ushort* __restrict__ w2pl,
                                                float* __restrict__ pool2raw,
                                                float* __restrict__ part2){
  __shared__ __align__(16) ushort s_hi[3*3072];
  __shared__ __align__(16) ushort s_lo[3*3072];
  __shared__ float statL[2][32][2];
  float* poolF = (float*)s_hi;   // [2][32][40] overlay, used after barrier
  int b = blockIdx.x;
  int n = b >> 1, ph = b & 1;
  int tid = threadIdx.x;
  int row0 = 2*ph;
  int nrows = ph ? 2 : 3;
  {
    const float4* gh = (const float4*)(a1h + ((size_t)n*4 + row0)*3072);
    const float4* gl = (const float4*)(a1l + ((size_t)n*4 + row0)*3072);
    float4* dh = (float4*)s_hi;
    float4* dl = (float4*)s_lo;
    int cnt = nrows*384;
    for (int i = tid; i < cnt; i += 128){ dh[i] = gh[i]; dl[i] = gl[i]; }
  }
  __syncthreads();
  int wv = tid >> 6, lane = tid & 63;
  int h = 2*ph + wv;
  int l5 = lane >> 5, l31 = lane & 31;

  f32x16 acc[5];
  #pragma unroll
  for (int p = 0; p < 5; ++p)
    #pragma unroll
    for (int e = 0; e < 16; ++e) acc[p][e] = 0.f;

  int rmax = (h == 3) ? 1 : 2;
  for (int r = 0; r < rmax; ++r){
    int rb = (wv + r)*3072;
    for (int kw = 0; kw < 32; ++kw){
      int widx = (((r << 5) + kw)*32 + l31)*16 + l5*4;
      short8 Ah = cat8(*(const short4v*)(w2ph + widx), *(const short4v*)(w2ph + widx + 8));
      short8 Al = cat8(*(const short4v*)(w2pl + widx), *(const short4v*)(w2pl + widx + 8));
      short8 Bh[5], Bl[5];
      #pragma unroll
      for (int p = 0; p < 5; ++p){
        int pos = p*32 + l31 + kw;
        int sw = ((pos >> 2) & 3) << 2;
        int off0 = rb + pos*16 + ((l5*4) ^ sw);
        int off1 = rb + pos*16 + ((l5*4 + 8) ^ sw);
        Bh[p] = cat8(*(const short4v*)(s_hi + off0), *(const short4v*)(s_hi + off1));
        Bl[p] = cat8(*(const short4v*)(s_lo + off0), *(const short4v*)(s_lo + off1));
      }
      #pragma unroll
      for (int p = 0; p < 5; ++p) acc[p] = __builtin_amdgcn_mfma_f32_32x32x16_bf16(Ah, Bh[p], acc[p], 0, 0, 0);
      #pragma unroll
      for (int p = 0; p < 5; ++p) acc[p] = __builtin_amdgcn_mfma_f32_32x32x16_bf16(Ah, Bl[p], acc[p], 0, 0, 0);
      #pragma unroll
      for (int p = 0; p < 5; ++p) acc[p] = __builtin_amdgcn_mfma_f32_32x32x16_bf16(Al, Bh[p], acc[p], 0, 0, 0);
    }
  }
  __syncthreads();   // staging reads complete; poolF overlay now safe

  // stats partial (mask pos>=155): C/D map col=l31, row=(e&3)+8*(e>>2)+4*l5
  {
    float sreg[16], qreg[16];
    #pragma unroll
    for (int e = 0; e < 16; ++e){ sreg[e] = 0.f; qreg[e] = 0.f; }
    #pragma unroll
    for (int p = 0; p < 5; ++p){
      bool pv = (p < 4) || (l31 < 27);
      #pragma unroll
      for (int e = 0; e < 16; ++e){
        float v = pv ? acc[p][e] : 0.f;
        sreg[e] += v; qreg[e] += v*v;
      }
    }
    #pragma unroll
    for (int m = 1; m < 32; m <<= 1){
      #pragma unroll
      for (int e = 0; e < 16; ++e){
        sreg[e] += __shfl_xor(sreg[e], m);
        qreg[e] += __shfl_xor(qreg[e], m);
      }
    }
    if (l31 == 0){
      #pragma unroll
      for (int e = 0; e < 16; ++e){
        int co = (e & 3) + ((e >> 2) << 3) + (l5 << 2);
        statL[wv][co][0] = sreg[e];
        statL[wv][co][1] = qreg[e];
      }
    }
  }
  // per-wave pooled max over w quads -> poolF overlay
  #pragma unroll
  for (int p = 0; p < 5; ++p){
    #pragma unroll
    for (int e = 0; e < 16; ++e){
      float v = acc[p][e];
      float v1 = fmaxf(v, __shfl_xor(v, 1));
      float v2m = fmaxf(v1, __shfl_xor(v1, 2));
      int pw = p*8 + (l31 >> 2);
      if ((l31 & 3) == 0 && pw < PW2){
        int co = (e & 3) + ((e >> 2) << 3) + (l5 << 2);
        poolF[(wv*32 + co)*40 + pw] = v2m;
      }
    }
  }
  __syncthreads();
  for (int i = tid; i < 32*PW2; i += 128){
    int pw = i % PW2; int co = i / PW2;
    float v = fmaxf(poolF[co*40 + pw], poolF[(32 + co)*40 + pw]);
    pool2raw[(((size_t)n*2 + ph)*32 + co)*PW2 + pw] = v;
  }
  if (tid < 32){
    float s = statL[0][tid][0] + statL[1][tid][0];
    float q = statL[0][tid][1] + statL[1][tid][1];
    part2[((size_t)(n*2 + ph)*32 + tid)*2]     = s;
    part2[((size_t)(n*2 + ph)*32 + tid)*2 + 1] = q;
  }
}

// ---------------- bn2: LDS-staged coalesced. block=(n,hr)
__global__ __launch_bounds__(256) void k_bn2(const float* __restrict__ pool2raw,
                                             const float* __restrict__ stats,
                                             ushort* __restrict__ a2h, ushort* __restrict__ a2l){
  __shared__ float xf[1216];   // 32ci x 38pw
  __shared__ float st[64];
  int b = blockIdx.x;          // = n*2 + hr, 2048
  int tid = threadIdx.x;
  if (tid < 64) st[tid] = stats[tid];
  for (int i = tid; i < 1216; i += 256) xf[i] = pool2raw[(size_t)b*1216 + i];
  __syncthreads();
  for (int i = tid; i < 2304; i += 256){
    int w = i >> 5, ci = i & 31;
    float v = 0.f;
    int pw = w - 2;
    if ((unsigned)pw < (unsigned)PW2)
      v = eluf((xf[ci*38 + pw] - st[ci*2])*st[ci*2+1]);
    int ciS = ci ^ (((w >> 1) & 7) << 2);
    size_t o = (size_t)b*2304 + w*32 + ciS;
    ushort hs = bf16h(v);
    a2h[o] = hs; a2l[o] = bf16h(v - bf16f(hs));
  }
}

// ---------------- fused conv3 (MFMA 3-term bf16) + stats partial + maxpool(2,4)
__global__ __launch_bounds__(256, 2) void k_conv3f(const ushort* __restrict__ a2h,
                                                   const ushort* __restrict__ a2l,
                                                   const ushort* __restrict__ w3ph,
                                                   const ushort* __restrict__ w3pl,
                                                   float* __restrict__ featsraw,
                                                   float* __restrict__ part3){
  __shared__ __align__(16) ushort s3h[9216];
  __shared__ __align__(16) ushort s3l[9216];
  __shared__ float poolL3[4][32][12];
  __shared__ float statL3[4][32][2];
  int nb = blockIdx.x;
  int tid = threadIdx.x;
  {
    const float4* gh = (const float4*)(a2h + (size_t)nb*9216);
    const float4* gl = (const float4*)(a2l + (size_t)nb*9216);
    float4* dh = (float4*)s3h;
    float4* dl = (float4*)s3l;
    for (int i = tid; i < 1152; i += 256){ dh[i] = gh[i]; dl[i] = gl[i]; }
  }
  __syncthreads();
  int wave = tid >> 6, lane = tid & 63;
  int nh = wave >> 1, h = wave & 1;
  int l5 = lane >> 5, l31 = lane & 31;

  f32x16 acc[2];
  #pragma unroll
  for (int p = 0; p < 2; ++p)
    #pragma unroll
    for (int e = 0; e < 16; ++e) acc[p][e] = 0.f;

  #pragma unroll
  for (int ri = 0; ri < 2; ++ri){
    int r = (h == 0) ? (4 + ri) : (3 + ri);
    int rbase = (nh*2 + ri)*72*32;
    #pragma unroll
    for (int kw = 0; kw < 4; ++kw){
      #pragma unroll
      for (int ch = 0; ch < 2; ++ch){
        int widx = ((r*4 + kw)*32 + l31)*32 + ch*16 + l5*4;
        short8 Ah = cat8(*(const short4v*)(w3ph + widx), *(const short4v*)(w3ph + widx + 8));
        short8 Al = cat8(*(const short4v*)(w3pl + widx), *(const short4v*)(w3pl + widx + 8));
        short8 Bh[2], Bl[2];
        #pragma unroll
        for (int p = 0; p < 2; ++p){
          int pos = p*32 + l31 + kw;
          int sw = ((pos >> 1) & 7) << 2;
          int s0 = ch*16 + l5*4;
          int off0 = rbase + pos*32 + (s0 ^ sw);
          int off1 = rbase + pos*32 + ((s0 + 8) ^ sw);
          Bh[p] = cat8(*(const short4v*)(s3h + off0), *(const short4v*)(s3h + off1));
          Bl[p] = cat8(*(const short4v*)(s3l + off0), *(const short4v*)(s3l + off1));
        }
        #pragma unroll
        for (int p = 0; p < 2; ++p) acc[p] = __builtin_amdgcn_mfma_f32_32x32x16_bf16(Ah, Bh[p], acc[p], 0, 0, 0);
        #pragma unroll
        for (int p = 0; p < 2; ++p) acc[p] = __builtin_amdgcn_mfma_f32_32x32x16_bf16(Ah, Bl[p], acc[p], 0, 0, 0);
        #pragma unroll
        for (int p = 0; p < 2; ++p) acc[p] = __builtin_amdgcn_mfma_f32_32x32x16_bf16(Al, Bh[p], acc[p], 0, 0, 0);
      }
    }
  }

  {
    float sreg[16], qreg[16];
    #pragma unroll
    for (int e = 0; e < 16; ++e){ sreg[e] = 0.f; qreg[e] = 0.f; }
    #pragma unroll
    for (int p = 0; p < 2; ++p){
      bool pv = (p == 0) || (l31 < 6);
      #pragma unroll
      for (int e = 0; e < 16; ++e){
        float v = pv ? acc[p][e] : 0.f;
        sreg[e] += v; qreg[e] += v*v;
      }
    }
    #pragma unroll
    for (int m = 1; m < 32; m <<= 1){
      #pragma unroll
      for (int e = 0; e < 16; ++e){
        sreg[e] += __shfl_xor(sreg[e], m);
        qreg[e] += __shfl_xor(qreg[e], m);
      }
    }
    if (l31 == 0){
      #pragma unroll
      for (int e = 0; e < 16; ++e){
        int co = (e & 3) + ((e >> 2) << 3) + (l5 << 2);
        statL3[wave][co][0] = sreg[e];
        statL3[wave][co][1] = qreg[e];
      }
    }
  }
  #pragma unroll
  for (int p = 0; p < 2; ++p){
    #pragma unroll
    for (int e = 0; e < 16; ++e){
      float v = acc[p][e];
      float v1 = fmaxf(v, __shfl_xor(v, 1));
      float v2m = fmaxf(v1, __shfl_xor(v1, 2));
      int pw = p*8 + (l31 >> 2);
      if ((l31 & 3) == 0 && pw < 9){
        int co = (e & 3) + ((e >> 2) << 3) + (l5 << 2);
        poolL3[wave][co][pw] = v2m;
      }
    }
  }
  __syncthreads();
  for (int i = tid; i < 2*32*9; i += 256){
    int pw = i % 9; int t = i / 9; int co = t & 31; int nh2 = t >> 5;
    float v = fmaxf(poolL3[nh2*2][co][pw], poolL3[nh2*2+1][co][pw]);
    featsraw[((size_t)(nb*2 + nh2)*32 + co)*9 + pw] = v;
  }
  if (tid < 32){
    float s = 0.f, q = 0.f;
    #pragma unroll
    for (int wv = 0; wv < 4; ++wv){ s += statL3[wv][tid][0]; q += statL3[wv][tid][1]; }
    part3[((size_t)nb*32 + tid)*2]     = s;
    part3[((size_t)nb*32 + tid)*2 + 1] = q;
  }
}

// ---------------- build U (512x512) by running the fixed circuit on basis states
__global__ __launch_bounds__(256) void k_buildU(const float* __restrict__ qw,
                                                ushort* __restrict__ Uh, ushort* __restrict__ Ul){
  __shared__ float wt[36][2];
  int tid = threadIdx.x;
  if (tid < 36){ float s, c; sincosf(qw[tid]*0.5f, &s, &c); wt[tid][0] = c; wt[tid][1] = s; }
  __syncthreads();
  int wid = tid >> 6, lane = tid & 63;
  int k = blockIdx.x*4 + wid;
  float v[8];
  #pragma unroll
  for (int r = 0; r < 8; ++r) v[r] = (lane*8 + r == k) ? 1.f : 0.f;

  for (int j = 0; j < 4; ++j){
    #pragma unroll
    for (int i = 0; i < 5; ++i){
      int cm = 32>>i, tm = 16>>i;
      bool flip = (lane & cm) != 0;
      #pragma unroll
      for (int r = 0; r < 8; ++r){
        float w = __shfl_xor(v[r], tm);
        v[r] = flip ? w : v[r];
      }
    }
    { bool flip = (lane & 1) != 0;
      #pragma unroll
      for (int r = 0; r < 4; ++r){ float a = v[r], bb = v[r+4]; v[r] = flip?bb:a; v[r+4] = flip?a:bb; } }
    { float t = v[4]; v[4] = v[6]; v[6] = t; t = v[5]; v[5] = v[7]; v[7] = t; }
    { float t = v[2]; v[2] = v[3]; v[3] = t; t = v[6]; v[6] = v[7]; v[7] = t; }
    #pragma unroll
    for (int r = 1; r < 8; r += 2) v[r] = __shfl_xor(v[r], 32);

    #pragma unroll
    for (int i = 0; i < 6; ++i){
      float c = wt[j*9+i][0], s = wt[j*9+i][1];
      int m = 32>>i;
      float sg = (lane & m) ? s : -s;
      #pragma unroll
      for (int r = 0; r < 8; ++r){
        float w = __shfl_xor(v[r], m);
        v[r] = c*v[r] + sg*w;
      }
    }
    { float c = wt[j*9+6][0], s = wt[j*9+6][1];
      #pragma unroll
      for (int r = 0; r < 4; ++r){ float a = v[r], bb = v[r+4]; v[r] = c*a - s*bb; v[r+4] = s*a + c*bb; } }
    { float c = wt[j*9+7][0], s = wt[j*9+7][1]; float a, bb;
      a=v[0]; bb=v[2]; v[0]=c*a-s*bb; v[2]=s*a+c*bb;
      a=v[1]; bb=v[3]; v[1]=c*a-s*bb; v[3]=s*a+c*bb;
      a=v[4]; bb=v[6]; v[4]=c*a-s*bb; v[6]=s*a+c*bb;
      a=v[5]; bb=v[7]; v[5]=c*a-s*bb; v[7]=s*a+c*bb; }
    { float c = wt[j*9+8][0], s = wt[j*9+8][1]; float a, bb;
      a=v[0]; bb=v[1]; v[0]=c*a-s*bb; v[1]=s*a+c*bb;
      a=v[2]; bb=v[3]; v[2]=c*a-s*bb; v[3]=s*a+c*bb;
      a=v[4]; bb=v[5]; v[4]=c*a-s*bb; v[5]=s*a+c*bb;
      a=v[6]; bb=v[7]; v[6]=c*a-s*bb; v[7]=s*a+c*bb; }
  }
  #pragma unroll
  for (int r = 0; r < 8; ++r){
    int s = lane*8 + r;
    int mf = s >> 5, r31 = s & 31;
    int addr = (((k >> 4)*16 + mf)*32 + r31)*16 + (k & 15);
    float f = v[r];
    ushort hi = bf16h(f);
    Uh[addr] = hi;
    Ul[addr] = bf16h(f - bf16f(hi));
  }
}

// ---------------- quantum GEMM: state = U @ b(sample), fused BN+ELU + <Z> epilogue
__global__ __launch_bounds__(256, 1) void k_qgemm(const float* __restrict__ featsraw,
                                                  const float* __restrict__ stats,
                                                  const ushort* __restrict__ Uh,
                                                  const ushort* __restrict__ Ul,
                                                  float* __restrict__ qo){
  __shared__ __align__(16) ushort BhL[32768];
  __shared__ __align__(16) ushort BlL[32768];
  __shared__ float angL[576];
  __shared__ float zred[4][64][9];
  int nb = blockIdx.x;
  int tid = threadIdx.x;
  for (int t = tid; t < 576; t += 256){
    float vr = featsraw[(size_t)nb*576 + t];
    int c = (t/9) & 31;
    angL[t] = 0.5f * eluf((vr - stats[c*2])*stats[c*2+1]);
  }
  __syncthreads();
  {
    int sm = tid >> 2, q = tid & 3;
    float tc[9], ts[9];
    #pragma unroll
    for (int i = 0; i < 9; ++i) sincosf(angL[sm*9 + i], &ts[i], &tc[i]);
    float Pc = ((q & 2) ? ts[0] : tc[0]) * ((q & 1) ? ts[1] : tc[1]);
    int swz = (sm >> 2) & 3;
    short4v* bh4 = (short4v*)BhL;
    short4v* bl4 = (short4v*)BlL;
    int j = 0;
    #pragma unroll
    for (int b2 = 0; b2 < 2; ++b2){ float p2 = Pc*(b2 ? ts[2] : tc[2]);
    #pragma unroll
    for (int b3 = 0; b3 < 2; ++b3){ float p3 = p2*(b3 ? ts[3] : tc[3]);
    #pragma unroll
    for (int b4 = 0; b4 < 2; ++b4){ float p4 = p3*(b4 ? ts[4] : tc[4]);
    #pragma unroll
    for (int b5 = 0; b5 < 2; ++b5){ float p5 = p4*(b5 ? ts[5] : tc[5]);
    #pragma unroll
    for (int b6 = 0; b6 < 2; ++b6){ float p6 = p5*(b6 ? ts[6] : tc[6]);
      float a0 = p6*tc[7]*tc[8];
      float a1 = p6*tc[7]*ts[8];
      float a2 = p6*ts[7]*tc[8];
      float a3 = p6*ts[7]*ts[8];
      ushort h0 = bf16h(a0), h1 = bf16h(a1), h2 = bf16h(a2), h3 = bf16h(a3);
      short4v hv; hv[0]=(short)h0; hv[1]=(short)h1; hv[2]=(short)h2; hv[3]=(short)h3;
      short4v lv; lv[0]=(short)bf16h(a0 - bf16f(h0)); lv[1]=(short)bf16h(a1 - bf16f(h1));
                  lv[2]=(short)bf16h(a2 - bf16f(h2)); lv[3]=(short)bf16h(a3 - bf16f(h3));
      int kk = q*128 + j;
      int kstep = kk >> 4;
      int g = (kk >> 2) & 3;
      int idx4 = (kstep*64 + sm)*4 + (g ^ swz);
      bh4[idx4] = hv; bl4[idx4] = lv;
      j += 4;
    }}}}}
  }
  __syncthreads();
  int wv = tid >> 6, lane = tid & 63, l5 = lane >> 5, l31 = lane & 31;
  f32x16 acc[4][2];
  #pragma unroll
  for (int jj = 0; jj < 4; ++jj)
    #pragma unroll
    for (int nf = 0; nf < 2; ++nf)
      #pragma unroll
      for (int e = 0; e < 16; ++e) acc[jj][nf][e] = 0.f;

  for (int kstep = 0; kstep < 32; ++kstep){
    short8 Bh[2], Bl[2];
    #pragma unroll
    for (int nf = 0; nf < 2; ++nf){
      int sm = nf*32 + l31;
      int base = (kstep*64 + sm)*16;
      int sz = ((sm >> 2) & 3) << 2;
      int e0 = (l5*4) ^ sz;
      int e1 = (l5*4 + 8) ^ sz;
      Bh[nf] = cat8(*(const short4v*)(BhL + base + e0), *(const short4v*)(BhL + base + e1));
      Bl[nf] = cat8(*(const short4v*)(BlL + base + e0), *(const short4v*)(BlL + base + e1));
    }
    #pragma unroll
    for (int jj = 0; jj < 4; ++jj){
      int mf = wv*4 + jj;
      const ushort* ah = Uh + ((kstep*16 + mf)*32 + l31)*16 + l5*4;
      const ushort* al = Ul + ((kstep*16 + mf)*32 + l31)*16 + l5*4;
      short8 Ah = cat8(*(const short4v*)ah, *(const short4v*)(ah + 8));
      short8 Al = cat8(*(const short4v*)al, *(const short4v*)(al + 8));
      acc[jj][0] = __builtin_amdgcn_mfma_f32_32x32x16_bf16(Ah, Bh[0], acc[jj][0], 0, 0, 0);
      acc[jj][1] = __builtin_amdgcn_mfma_f32_32x32x16_bf16(Ah, Bh[1], acc[jj][1], 0, 0, 0);
      acc[jj][0] = __builtin_amdgcn_mfma_f32_32x32x16_bf16(Ah, Bl[0], acc[jj][0], 0, 0, 0);
      acc[jj][1] = __builtin_amdgcn_mfma_f32_32x32x16_bf16(Ah, Bl[1], acc[jj][1], 0, 0, 0);
      acc[jj][0] = __builtin_amdgcn_mfma_f32_32x32x16_bf16(Al, Bh[0], acc[jj][0], 0, 0, 0);
      acc[jj][1] = __builtin_amdgcn_mfma_f32_32x32x16_bf16(Al, Bh[1], acc[jj][1], 0, 0, 0);
    }
  }
  float zz[2][9];
  #pragma unroll
  for (int nf = 0; nf < 2; ++nf)
    #pragma unroll
    for (int i = 0; i < 9; ++i) zz[nf][i] = 0.f;
  #pragma unroll
  for (int jj = 0; jj < 4; ++jj){
    int mf = wv*4 + jj;
    float sg0 = (mf & 8) ? -1.f : 1.f;
    float sg1 = (mf & 4) ? -1.f : 1.f;
    float sg2 = (mf & 2) ? -1.f : 1.f;
    float sg3 = (mf & 1) ? -1.f : 1.f;
    #pragma unroll
    for (int nf = 0; nf < 2; ++nf){
      float psum = 0.f, z4 = 0.f, z5 = 0.f, z7 = 0.f, z8 = 0.f;
      #pragma unroll
      for (int e = 0; e < 16; ++e){
        float qv = acc[jj][nf][e]*acc[jj][nf][e];
        psum += qv;
        z4 += ((e >> 3) & 1) ? -qv : qv;
        z5 += ((e >> 2) & 1) ? -qv : qv;
        z7 += ((e >> 1) & 1) ? -qv : qv;
        z8 += (e & 1) ? -qv : qv;
      }
      zz[nf][0] += sg0*psum; zz[nf][1] += sg1*psum;
      zz[nf][2] += sg2*psum; zz[nf][3] += sg3*psum;
      zz[nf][4] += z4; zz[nf][5] += z5;
      zz[nf][6] += l5 ? -psum : psum;
      zz[nf][7] += z7; zz[nf][8] += z8;
    }
  }
  #pragma unroll
  for (int nf = 0; nf < 2; ++nf)
    #pragma unroll
    for (int i = 0; i < 9; ++i) zz[nf][i] += __shfl_xor(zz[nf][i], 32);
  if (l5 == 0){
    #pragma unroll
    for (int nf = 0; nf < 2; ++nf)
      #pragma unroll
      for (int i = 0; i < 9; ++i) zred[wv][nf*32 + l31][i] = zz[nf][i];
  }
  __syncthreads();
  for (int t = tid; t < 576; t += 256){
    int sm = t / 9, i = t - sm*9;
    float s = zred[0][sm][i] + zred[1][sm][i] + zred[2][sm][i] + zred[3][sm][i];
    qo[(size_t)(nb*64 + sm)*9 + i] = s;
  }
}

// ---------------- fc
__global__ void k_fc(const float* __restrict__ q, const float* __restrict__ fw,
                     const float* __restrict__ fb, float* __restrict__ out){
  int idx = blockIdx.x*256 + threadIdx.x;
  if (idx >= NB*5) return;
  int b = idx / 5, o = idx - b*5;
  const float* qr = q + (size_t)b*288;
  const float* wr = fw + (size_t)o*288;
  float s = 0.f;
  for (int j = 0; j < 288; ++j) s += qr[j]*wr[j];
  out[idx] = s + fb[o];
}

extern "C" void kernel_launch(void* const* d_in, const int* in_sizes, int n_in,
                              void* d_out, int out_size, void* d_ws, size_t ws_size,
                              hipStream_t stream){
  const float* x  = (const float*)d_in[0];
  const float* w1 = (const float*)d_in[1];
  const float* w2 = (const float*)d_in[2];
  const float* w3 = (const float*)d_in[3];
  const float* qw = (const float*)d_in[4];
  const float* fw = (const float*)d_in[5];
  const float* fb = (const float*)d_in[6];
  float* out = (float*)d_out;
  float* W = (float*)d_ws;

  float*  out1   = W + OFF_OUT1;
  ushort* a1h    = (ushort*)(W + OFF_A1H);
  ushort* a1l    = (ushort*)(W + OFF_A1L);
  ushort* w2ph   = (ushort*)(W + OFF_W2PH);
  ushort* w2pl   = (ushort*)(W + OFF_W2PL);
  ushort* w3ph   = (ushort*)(W + OFF_W3PH);
  ushort* w3pl   = (ushort*)(W + OFF_W3PL);
  ushort* uH     = (ushort*)(W + OFF_UH);
  ushort* uL     = (ushort*)(W + OFF_UL);
  float*  pool2raw = W + OFF_POOL2RAW;
  ushort* a2h    = (ushort*)(W + OFF_A2H);
  ushort* a2l    = (ushort*)(W + OFF_A2L);
  float*  featsraw = W + OFF_FEATSRAW;
  float*  qo     = W + OFF_QO;
  float*  part1  = W + OFF_PART1;
  float*  part2  = W + OFF_PART2;
  float*  part3  = W + OFF_PART3;
  float*  stats1 = W + OFF_STATS1;
  float*  stats2 = W + OFF_STATS2;
  float*  stats3 = W + OFF_STATS3;

  k_conv1s<<<NB, 256, 0, stream>>>(x, w1, out1, part1);
  k_stats_finP<<<16, 256, 0, stream>>>(part1, stats1, 16, NB*4, 1.f/((float)NB*H1*W1));
  k_bnelu1<<<NB*4, 256, 0, stream>>>(out1, stats1, a1h, a1l);
  k_cvtw<<<256, 256, 0, stream>>>(w2, w3, w2ph, w2pl, w3ph, w3pl);
  k_buildU<<<128, 256, 0, stream>>>(qw, uH, uL);
  k_conv2f<<<NB*2, 128, 0, stream>>>(a1h, a1l, w2ph, w2pl, pool2raw, part2);
  k_stats_finP<<<32, 256, 0, stream>>>(part2, stats2, 32, NB*2, 1.f/((float)NB*H2*W2));
  k_bn2<<<NB*2, 256, 0, stream>>>(pool2raw, stats2, a2h, a2l);
  k_conv3f<<<NB/2, 256, 0, stream>>>(a2h, a2l, w3ph, w3pl, featsraw, part3);
  k_stats_finP<<<32, 256, 0, stream>>>(part3, stats3, 32, NB/2, 1.f/((float)NB*2*W3));
  k_qgemm<<<NB/2, 256, 0, stream>>>(featsraw, stats3, uH, uL, qo);
  k_fc<<<20, 256, 0, stream>>>(qo, fw, fb, out);
}

// Round 5
// 341.340 us; speedup vs baseline: 4.8414x; 1.1029x over previous
//
#include <hip/hip_runtime.h>
#include <math.h>

#define NB 1024
#define C1 16
#define H1 4
#define W1 153
#define WX 216
#define K1 64
#define C2 32
#define H2 4
#define W2 155
#define W192 192
#define PW2 38
#define C3 32
#define W3 38

typedef short short4v __attribute__((ext_vector_type(4)));
typedef short short8 __attribute__((ext_vector_type(8)));
typedef float f32x16 __attribute__((ext_vector_type(16)));

// ---- workspace float offsets
#define OFF_OUT1     0
#define OFF_A1H      10027008
#define OFF_A1L      16318464
#define OFF_W2PH     22609920
#define OFF_W2PL     22626304
#define OFF_W3PH     22642688
#define OFF_W3PL     22659072
#define OFF_UH       22675456
#define OFF_UL       22806528
#define OFF_POOL2RAW 22937600
#define OFF_A2H      25427968
#define OFF_A2L      27787264
#define OFF_FEATSRAW 30146560
#define OFF_QO       30441472
#define OFF_PART1    30736384
#define OFF_PART2    30867456
#define OFF_PART3    30998528
#define OFF_STATS1   31031296
#define OFF_STATS2   31031328
#define OFF_STATS3   31031392

__device__ __forceinline__ float eluf(float x){ return x > 0.f ? x : expm1f(x); }

__device__ __forceinline__ ushort bf16h(float x){
  unsigned u = __float_as_uint(x);
  unsigned r = u + 0x7fffu + ((u >> 16) & 1u);
  return (ushort)(r >> 16);
}
__device__ __forceinline__ float bf16f(ushort h){ return __uint_as_float(((unsigned)h) << 16); }

__device__ __forceinline__ short8 cat8(short4v a, short4v b){
  return __builtin_shufflevector(a, b, 0,1,2,3,4,5,6,7);
}

// ---------------- conv1 + fused BN stats partial
__global__ __launch_bounds__(256) void k_conv1s(const float* __restrict__ x,
                                                const float* __restrict__ w1,
                                                float* __restrict__ out1,
                                                float* __restrict__ part1){
  __shared__ float xr[4][WX];
  __shared__ float wl[C1*K1];
  int n = blockIdx.x, tid = threadIdx.x;
  for (int i = tid; i < 4*WX; i += 256) xr[i/WX][i%WX] = x[(size_t)n*4*WX + i];
  for (int i = tid; i < C1*K1; i += 256) wl[i] = w1[i];
  __syncthreads();
  int h = tid >> 6, lane = tid & 63;
  float acc[16][3];
  #pragma unroll
  for (int c = 0; c < 16; ++c){ acc[c][0]=0.f; acc[c][1]=0.f; acc[c][2]=0.f; }
  bool v2 = (lane + 128) < W1;
  for (int k = 0; k < 64; ++k){
    float x0 = xr[h][lane + k];
    float x1 = xr[h][lane + 64 + k];
    float x2 = v2 ? xr[h][lane + 128 + k] : 0.f;
    #pragma unroll
    for (int c = 0; c < 16; ++c){
      float wk = wl[c*64 + k];
      acc[c][0] += wk*x0; acc[c][1] += wk*x1; acc[c][2] += wk*x2;
    }
  }
  float ss[16], sq[16];
  #pragma unroll
  for (int c = 0; c < 16; ++c){
    float* ob = out1 + (((size_t)(n*16 + c)*4 + h))*W1;
    ob[lane] = acc[c][0];
    ob[lane + 64] = acc[c][1];
    if (v2) ob[lane + 128] = acc[c][2];
    ss[c] = acc[c][0] + acc[c][1] + acc[c][2];
    sq[c] = acc[c][0]*acc[c][0] + acc[c][1]*acc[c][1] + acc[c][2]*acc[c][2];
  }
  #pragma unroll
  for (int m = 1; m < 64; m <<= 1){
    #pragma unroll
    for (int c = 0; c < 16; ++c){ ss[c] += __shfl_xor(ss[c], m); sq[c] += __shfl_xor(sq[c], m); }
  }
  if (lane == 0){
    #pragma unroll
    for (int c = 0; c < 16; ++c){
      part1[((size_t)(n*4 + h)*16 + c)*2]     = ss[c];
      part1[((size_t)(n*4 + h)*16 + c)*2 + 1] = sq[c];
    }
  }
}

// ---------------- parallel stats finalize: grid = C blocks
__global__ __launch_bounds__(256) void k_stats_finP(const float* __restrict__ part,
                                                    float* __restrict__ stats,
                                                    int C, int nblk, float inv){
  __shared__ float rs[256], rq[256];
  int c = blockIdx.x;
  float s = 0.f, q = 0.f;
  for (int b = threadIdx.x; b < nblk; b += 256){
    s += part[((size_t)b*C + c)*2];
    q += part[((size_t)b*C + c)*2 + 1];
  }
  rs[threadIdx.x] = s; rq[threadIdx.x] = q; __syncthreads();
  for (int st = 128; st > 0; st >>= 1){
    if (threadIdx.x < st){ rs[threadIdx.x] += rs[threadIdx.x+st]; rq[threadIdx.x] += rq[threadIdx.x+st]; }
    __syncthreads();
  }
  if (threadIdx.x == 0){
    float mean = rs[0]*inv;
    float var  = rq[0]*inv - mean*mean;
    stats[c*2]   = mean;
    stats[c*2+1] = rsqrtf(var + 1e-5f);
  }
}

// ---------------- bnelu1: LDS-staged coalesced. block=(n,h)
__global__ __launch_bounds__(256) void k_bnelu1(const float* __restrict__ out1,
                                                const float* __restrict__ stats,
                                                ushort* __restrict__ a1h, ushort* __restrict__ a1l){
  __shared__ float xf[2448];   // 16ci x 153w
  __shared__ float st[32];
  int b = blockIdx.x;          // = n*4 + h
  int n = b >> 2, h = b & 3;
  int tid = threadIdx.x;
  if (tid < 32) st[tid] = stats[tid];
  for (int i = tid; i < 2448; i += 256){
    int ci = i / 153, w = i - ci*153;
    xf[i] = out1[((size_t)(n*16 + ci)*4 + h)*W1 + w];
  }
  __syncthreads();
  for (int i = tid; i < 3072; i += 256){
    int w = i >> 4, ci = i & 15;
    float v = 0.f;
    int ws = w - 16;
    if ((unsigned)ws < (unsigned)W1){
      float xx = xf[ci*153 + ws];
      v = eluf((xx - st[ci*2])*st[ci*2+1]);
    }
    int ciS = ci ^ (((w >> 2) & 3) << 2);
    size_t o = (size_t)b*3072 + w*16 + ciS;
    ushort hs = bf16h(v);
    a1h[o] = hs;
    a1l[o] = bf16h(v - bf16f(hs));
  }
}

// ---------------- weight convert+permute
__global__ void k_cvtw(const float* __restrict__ w2, const float* __restrict__ w3,
                       ushort* __restrict__ w2ph, ushort* __restrict__ w2pl,
                       ushort* __restrict__ w3ph, ushort* __restrict__ w3pl){
  int idx = blockIdx.x*256 + threadIdx.x;
  if (idx < 32768){
    int ci = idx & 15; int co = (idx >> 4) & 31; int rk = idx >> 9;
    int r = rk >> 5, kw = rk & 31;
    float v = w2[((size_t)(co*16 + ci)*2 + r)*32 + kw];
    ushort hs = bf16h(v); float hf = bf16f(hs);
    w2ph[idx] = hs; w2pl[idx] = bf16h(v - hf);
  } else {
    int j = idx - 32768;
    int ci = j & 31; int co = (j >> 5) & 31; int rk = j >> 10;
    int r = rk >> 2, kw = rk & 3;
    float v = w3[((size_t)(co*32 + ci)*8 + r)*4 + kw];
    ushort hs = bf16h(v); float hf = bf16f(hs);
    w3ph[j] = hs; w3pl[j] = bf16h(v - hf);
  }
}

// ---------------- fused conv2 (MFMA 3-term bf16) + stats partial + maxpool(2,4)
// block = (n, ph). 2 waves. Explicit 2-deep software pipeline on A(global) and B(LDS).
__global__ __launch_bounds__(128) void k_conv2f(const ushort* __restrict__ a1h,
                                                const ushort* __restrict__ a1l,
                                                const ushort* __restrict__ w2ph,
                                                const ushort* __restrict__ w2pl,
                                                float* __restrict__ pool2raw,
                                                float* __restrict__ part2){
  __shared__ __align__(16) ushort s_hi[3*3072];
  __shared__ __align__(16) ushort s_lo[3*3072];
  __shared__ float statL[2][32][2];
  float* poolF = (float*)s_hi;   // [2][32][40] overlay, used after barrier
  int b = blockIdx.x;
  int n = b >> 1, ph = b & 1;
  int tid = threadIdx.x;
  int row0 = 2*ph;
  int nrows = ph ? 2 : 3;
  {
    const float4* gh = (const float4*)(a1h + ((size_t)n*4 + row0)*3072);
    const float4* gl = (const float4*)(a1l + ((size_t)n*4 + row0)*3072);
    float4* dh = (float4*)s_hi;
    float4* dl = (float4*)s_lo;
    int cnt = nrows*384;
    for (int i = tid; i < cnt; i += 128){ dh[i] = gh[i]; dl[i] = gl[i]; }
  }
  __syncthreads();
  int wv = tid >> 6, lane = tid & 63;
  int h = 2*ph + wv;
  int l5 = lane >> 5, l31 = lane & 31;

  f32x16 acc[5];
  #pragma unroll
  for (int p = 0; p < 5; ++p)
    #pragma unroll
    for (int e = 0; e < 16; ++e) acc[p][e] = 0.f;

  auto loadAB = [&](int it, short8& Ah, short8& Al, short8 (&Bh)[5], short8 (&Bl)[5]){
    int r = it >> 5, kw = it & 31;
    int rb = (wv + r)*3072;
    int widx = (((r << 5) + kw)*32 + l31)*16 + l5*4;
    Ah = cat8(*(const short4v*)(w2ph + widx), *(const short4v*)(w2ph + widx + 8));
    Al = cat8(*(const short4v*)(w2pl + widx), *(const short4v*)(w2pl + widx + 8));
    #pragma unroll
    for (int p = 0; p < 5; ++p){
      int pos = p*32 + l31 + kw;
      int sw = ((pos >> 2) & 3) << 2;
      int off0 = rb + pos*16 + ((l5*4) ^ sw);
      int off1 = rb + pos*16 + ((l5*4 + 8) ^ sw);
      Bh[p] = cat8(*(const short4v*)(s_hi + off0), *(const short4v*)(s_hi + off1));
      Bl[p] = cat8(*(const short4v*)(s_lo + off0), *(const short4v*)(s_lo + off1));
    }
  };
  auto mfma15 = [&](const short8& Ah, const short8& Al, short8 (&Bh)[5], short8 (&Bl)[5]){
    #pragma unroll
    for (int p = 0; p < 5; ++p) acc[p] = __builtin_amdgcn_mfma_f32_32x32x16_bf16(Ah, Bh[p], acc[p], 0, 0, 0);
    #pragma unroll
    for (int p = 0; p < 5; ++p) acc[p] = __builtin_amdgcn_mfma_f32_32x32x16_bf16(Ah, Bl[p], acc[p], 0, 0, 0);
    #pragma unroll
    for (int p = 0; p < 5; ++p) acc[p] = __builtin_amdgcn_mfma_f32_32x32x16_bf16(Al, Bh[p], acc[p], 0, 0, 0);
  };

  int rmax = (h == 3) ? 1 : 2;
  int total = rmax << 5;   // 32 or 64, always even
  short8 Ah0, Al0, Ah1, Al1;
  short8 Bh0[5], Bl0[5], Bh1[5], Bl1[5];
  loadAB(0, Ah0, Al0, Bh0, Bl0);
  for (int it = 0; it < total; it += 2){
    loadAB(it + 1, Ah1, Al1, Bh1, Bl1);        // prefetch odd iter
    mfma15(Ah0, Al0, Bh0, Bl0);                // compute even iter
    int nx = (it + 2 < total) ? it + 2 : it + 1;
    loadAB(nx, Ah0, Al0, Bh0, Bl0);            // prefetch next even iter
    mfma15(Ah1, Al1, Bh1, Bl1);                // compute odd iter
  }
  __syncthreads();   // staging reads complete; poolF overlay now safe

  // stats partial (mask pos>=155): C/D map col=l31, row=(e&3)+8*(e>>2)+4*l5
  {
    float sreg[16], qreg[16];
    #pragma unroll
    for (int e = 0; e < 16; ++e){ sreg[e] = 0.f; qreg[e] = 0.f; }
    #pragma unroll
    for (int p = 0; p < 5; ++p){
      bool pv = (p < 4) || (l31 < 27);
      #pragma unroll
      for (int e = 0; e < 16; ++e){
        float v = pv ? acc[p][e] : 0.f;
        sreg[e] += v; qreg[e] += v*v;
      }
    }
    #pragma unroll
    for (int m = 1; m < 32; m <<= 1){
      #pragma unroll
      for (int e = 0; e < 16; ++e){
        sreg[e] += __shfl_xor(sreg[e], m);
        qreg[e] += __shfl_xor(qreg[e], m);
      }
    }
    if (l31 == 0){
      #pragma unroll
      for (int e = 0; e < 16; ++e){
        int co = (e & 3) + ((e >> 2) << 3) + (l5 << 2);
        statL[wv][co][0] = sreg[e];
        statL[wv][co][1] = qreg[e];
      }
    }
  }
  // per-wave pooled max over w quads -> poolF overlay
  #pragma unroll
  for (int p = 0; p < 5; ++p){
    #pragma unroll
    for (int e = 0; e < 16; ++e){
      float v = acc[p][e];
      float v1 = fmaxf(v, __shfl_xor(v, 1));
      float v2m = fmaxf(v1, __shfl_xor(v1, 2));
      int pw = p*8 + (l31 >> 2);
      if ((l31 & 3) == 0 && pw < PW2){
        int co = (e & 3) + ((e >> 2) << 3) + (l5 << 2);
        poolF[(wv*32 + co)*40 + pw] = v2m;
      }
    }
  }
  __syncthreads();
  for (int i = tid; i < 32*PW2; i += 128){
    int pw = i % PW2; int co = i / PW2;
    float v = fmaxf(poolF[co*40 + pw], poolF[(32 + co)*40 + pw]);
    pool2raw[(((size_t)n*2 + ph)*32 + co)*PW2 + pw] = v;
  }
  if (tid < 32){
    float s = statL[0][tid][0] + statL[1][tid][0];
    float q = statL[0][tid][1] + statL[1][tid][1];
    part2[((size_t)(n*2 + ph)*32 + tid)*2]     = s;
    part2[((size_t)(n*2 + ph)*32 + tid)*2 + 1] = q;
  }
}

// ---------------- bn2: LDS-staged coalesced. block=(n,hr)
__global__ __launch_bounds__(256) void k_bn2(const float* __restrict__ pool2raw,
                                             const float* __restrict__ stats,
                                             ushort* __restrict__ a2h, ushort* __restrict__ a2l){
  __shared__ float xf[1216];   // 32ci x 38pw
  __shared__ float st[64];
  int b = blockIdx.x;          // = n*2 + hr, 2048
  int tid = threadIdx.x;
  if (tid < 64) st[tid] = stats[tid];
  for (int i = tid; i < 1216; i += 256) xf[i] = pool2raw[(size_t)b*1216 + i];
  __syncthreads();
  for (int i = tid; i < 2304; i += 256){
    int w = i >> 5, ci = i & 31;
    float v = 0.f;
    int pw = w - 2;
    if ((unsigned)pw < (unsigned)PW2)
      v = eluf((xf[ci*38 + pw] - st[ci*2])*st[ci*2+1]);
    int ciS = ci ^ (((w >> 1) & 7) << 2);
    size_t o = (size_t)b*2304 + w*32 + ciS;
    ushort hs = bf16h(v);
    a2h[o] = hs; a2l[o] = bf16h(v - bf16f(hs));
  }
}

// ---------------- fused conv3 (MFMA 3-term bf16) + stats partial + maxpool(2,4)
__global__ __launch_bounds__(256, 2) void k_conv3f(const ushort* __restrict__ a2h,
                                                   const ushort* __restrict__ a2l,
                                                   const ushort* __restrict__ w3ph,
                                                   const ushort* __restrict__ w3pl,
                                                   float* __restrict__ featsraw,
                                                   float* __restrict__ part3){
  __shared__ __align__(16) ushort s3h[9216];
  __shared__ __align__(16) ushort s3l[9216];
  __shared__ float poolL3[4][32][12];
  __shared__ float statL3[4][32][2];
  int nb = blockIdx.x;
  int tid = threadIdx.x;
  {
    const float4* gh = (const float4*)(a2h + (size_t)nb*9216);
    const float4* gl = (const float4*)(a2l + (size_t)nb*9216);
    float4* dh = (float4*)s3h;
    float4* dl = (float4*)s3l;
    for (int i = tid; i < 1152; i += 256){ dh[i] = gh[i]; dl[i] = gl[i]; }
  }
  __syncthreads();
  int wave = tid >> 6, lane = tid & 63;
  int nh = wave >> 1, h = wave & 1;
  int l5 = lane >> 5, l31 = lane & 31;

  f32x16 acc[2];
  #pragma unroll
  for (int p = 0; p < 2; ++p)
    #pragma unroll
    for (int e = 0; e < 16; ++e) acc[p][e] = 0.f;

  #pragma unroll
  for (int ri = 0; ri < 2; ++ri){
    int r = (h == 0) ? (4 + ri) : (3 + ri);
    int rbase = (nh*2 + ri)*72*32;
    #pragma unroll
    for (int kw = 0; kw < 4; ++kw){
      #pragma unroll
      for (int ch = 0; ch < 2; ++ch){
        int widx = ((r*4 + kw)*32 + l31)*32 + ch*16 + l5*4;
        short8 Ah = cat8(*(const short4v*)(w3ph + widx), *(const short4v*)(w3ph + widx + 8));
        short8 Al = cat8(*(const short4v*)(w3pl + widx), *(const short4v*)(w3pl + widx + 8));
        short8 Bh[2], Bl[2];
        #pragma unroll
        for (int p = 0; p < 2; ++p){
          int pos = p*32 + l31 + kw;
          int sw = ((pos >> 1) & 7) << 2;
          int s0 = ch*16 + l5*4;
          int off0 = rbase + pos*32 + (s0 ^ sw);
          int off1 = rbase + pos*32 + ((s0 + 8) ^ sw);
          Bh[p] = cat8(*(const short4v*)(s3h + off0), *(const short4v*)(s3h + off1));
          Bl[p] = cat8(*(const short4v*)(s3l + off0), *(const short4v*)(s3l + off1));
        }
        #pragma unroll
        for (int p = 0; p < 2; ++p) acc[p] = __builtin_amdgcn_mfma_f32_32x32x16_bf16(Ah, Bh[p], acc[p], 0, 0, 0);
        #pragma unroll
        for (int p = 0; p < 2; ++p) acc[p] = __builtin_amdgcn_mfma_f32_32x32x16_bf16(Ah, Bl[p], acc[p], 0, 0, 0);
        #pragma unroll
        for (int p = 0; p < 2; ++p) acc[p] = __builtin_amdgcn_mfma_f32_32x32x16_bf16(Al, Bh[p], acc[p], 0, 0, 0);
      }
    }
  }

  {
    float sreg[16], qreg[16];
    #pragma unroll
    for (int e = 0; e < 16; ++e){ sreg[e] = 0.f; qreg[e] = 0.f; }
    #pragma unroll
    for (int p = 0; p < 2; ++p){
      bool pv = (p == 0) || (l31 < 6);
      #pragma unroll
      for (int e = 0; e < 16; ++e){
        float v = pv ? acc[p][e] : 0.f;
        sreg[e] += v; qreg[e] += v*v;
      }
    }
    #pragma unroll
    for (int m = 1; m < 32; m <<= 1){
      #pragma unroll
      for (int e = 0; e < 16; ++e){
        sreg[e] += __shfl_xor(sreg[e], m);
        qreg[e] += __shfl_xor(qreg[e], m);
      }
    }
    if (l31 == 0){
      #pragma unroll
      for (int e = 0; e < 16; ++e){
        int co = (e & 3) + ((e >> 2) << 3) + (l5 << 2);
        statL3[wave][co][0] = sreg[e];
        statL3[wave][co][1] = qreg[e];
      }
    }
  }
  #pragma unroll
  for (int p = 0; p < 2; ++p){
    #pragma unroll
    for (int e = 0; e < 16; ++e){
      float v = acc[p][e];
      float v1 = fmaxf(v, __shfl_xor(v, 1));
      float v2m = fmaxf(v1, __shfl_xor(v1, 2));
      int pw = p*8 + (l31 >> 2);
      if ((l31 & 3) == 0 && pw < 9){
        int co = (e & 3) + ((e >> 2) << 3) + (l5 << 2);
        poolL3[wave][co][pw] = v2m;
      }
    }
  }
  __syncthreads();
  for (int i = tid; i < 2*32*9; i += 256){
    int pw = i % 9; int t = i / 9; int co = t & 31; int nh2 = t >> 5;
    float v = fmaxf(poolL3[nh2*2][co][pw], poolL3[nh2*2+1][co][pw]);
    featsraw[((size_t)(nb*2 + nh2)*32 + co)*9 + pw] = v;
  }
  if (tid < 32){
    float s = 0.f, q = 0.f;
    #pragma unroll
    for (int wv = 0; wv < 4; ++wv){ s += statL3[wv][tid][0]; q += statL3[wv][tid][1]; }
    part3[((size_t)nb*32 + tid)*2]     = s;
    part3[((size_t)nb*32 + tid)*2 + 1] = q;
  }
}

// ---------------- build U (512x512) by running the fixed circuit on basis states
__global__ __launch_bounds__(256) void k_buildU(const float* __restrict__ qw,
                                                ushort* __restrict__ Uh, ushort* __restrict__ Ul){
  __shared__ float wt[36][2];
  int tid = threadIdx.x;
  if (tid < 36){ float s, c; sincosf(qw[tid]*0.5f, &s, &c); wt[tid][0] = c; wt[tid][1] = s; }
  __syncthreads();
  int wid = tid >> 6, lane = tid & 63;
  int k = blockIdx.x*4 + wid;
  float v[8];
  #pragma unroll
  for (int r = 0; r < 8; ++r) v[r] = (lane*8 + r == k) ? 1.f : 0.f;

  for (int j = 0; j < 4; ++j){
    #pragma unroll
    for (int i = 0; i < 5; ++i){
      int cm = 32>>i, tm = 16>>i;
      bool flip = (lane & cm) != 0;
      #pragma unroll
      for (int r = 0; r < 8; ++r){
        float w = __shfl_xor(v[r], tm);
        v[r] = flip ? w : v[r];
      }
    }
    { bool flip = (lane & 1) != 0;
      #pragma unroll
      for (int r = 0; r < 4; ++r){ float a = v[r], bb = v[r+4]; v[r] = flip?bb:a; v[r+4] = flip?a:bb; } }
    { float t = v[4]; v[4] = v[6]; v[6] = t; t = v[5]; v[5] = v[7]; v[7] = t; }
    { float t = v[2]; v[2] = v[3]; v[3] = t; t = v[6]; v[6] = v[7]; v[7] = t; }
    #pragma unroll
    for (int r = 1; r < 8; r += 2) v[r] = __shfl_xor(v[r], 32);

    #pragma unroll
    for (int i = 0; i < 6; ++i){
      float c = wt[j*9+i][0], s = wt[j*9+i][1];
      int m = 32>>i;
      float sg = (lane & m) ? s : -s;
      #pragma unroll
      for (int r = 0; r < 8; ++r){
        float w = __shfl_xor(v[r], m);
        v[r] = c*v[r] + sg*w;
      }
    }
    { float c = wt[j*9+6][0], s = wt[j*9+6][1];
      #pragma unroll
      for (int r = 0; r < 4; ++r){ float a = v[r], bb = v[r+4]; v[r] = c*a - s*bb; v[r+4] = s*a + c*bb; } }
    { float c = wt[j*9+7][0], s = wt[j*9+7][1]; float a, bb;
      a=v[0]; bb=v[2]; v[0]=c*a-s*bb; v[2]=s*a+c*bb;
      a=v[1]; bb=v[3]; v[1]=c*a-s*bb; v[3]=s*a+c*bb;
      a=v[4]; bb=v[6]; v[4]=c*a-s*bb; v[6]=s*a+c*bb;
      a=v[5]; bb=v[7]; v[5]=c*a-s*bb; v[7]=s*a+c*bb; }
    { float c = wt[j*9+8][0], s = wt[j*9+8][1]; float a, bb;
      a=v[0]; bb=v[1]; v[0]=c*a-s*bb; v[1]=s*a+c*bb;
      a=v[2]; bb=v[3]; v[2]=c*a-s*bb; v[3]=s*a+c*bb;
      a=v[4]; bb=v[5]; v[4]=c*a-s*bb; v[5]=s*a+c*bb;
      a=v[6]; bb=v[7]; v[6]=c*a-s*bb; v[7]=s*a+c*bb; }
  }
  #pragma unroll
  for (int r = 0; r < 8; ++r){
    int s = lane*8 + r;
    int mf = s >> 5, r31 = s & 31;
    int addr = (((k >> 4)*16 + mf)*32 + r31)*16 + (k & 15);
    float f = v[r];
    ushort hi = bf16h(f);
    Uh[addr] = hi;
    Ul[addr] = bf16h(f - bf16f(hi));
  }
}

// ---------------- quantum GEMM: state = U @ b(sample), fused BN+ELU + <Z> epilogue
__global__ __launch_bounds__(256, 1) void k_qgemm(const float* __restrict__ featsraw,
                                                  const float* __restrict__ stats,
                                                  const ushort* __restrict__ Uh,
                                                  const ushort* __restrict__ Ul,
                                                  float* __restrict__ qo){
  __shared__ __align__(16) ushort BhL[32768];
  __shared__ __align__(16) ushort BlL[32768];
  __shared__ float angL[576];
  __shared__ float zred[4][64][9];
  int nb = blockIdx.x;
  int tid = threadIdx.x;
  for (int t = tid; t < 576; t += 256){
    float vr = featsraw[(size_t)nb*576 + t];
    int c = (t/9) & 31;
    angL[t] = 0.5f * eluf((vr - stats[c*2])*stats[c*2+1]);
  }
  __syncthreads();
  {
    int sm = tid >> 2, q = tid & 3;
    float tc[9], ts[9];
    #pragma unroll
    for (int i = 0; i < 9; ++i) sincosf(angL[sm*9 + i], &ts[i], &tc[i]);
    float Pc = ((q & 2) ? ts[0] : tc[0]) * ((q & 1) ? ts[1] : tc[1]);
    int swz = (sm >> 2) & 3;
    short4v* bh4 = (short4v*)BhL;
    short4v* bl4 = (short4v*)BlL;
    int j = 0;
    #pragma unroll
    for (int b2 = 0; b2 < 2; ++b2){ float p2 = Pc*(b2 ? ts[2] : tc[2]);
    #pragma unroll
    for (int b3 = 0; b3 < 2; ++b3){ float p3 = p2*(b3 ? ts[3] : tc[3]);
    #pragma unroll
    for (int b4 = 0; b4 < 2; ++b4){ float p4 = p3*(b4 ? ts[4] : tc[4]);
    #pragma unroll
    for (int b5 = 0; b5 < 2; ++b5){ float p5 = p4*(b5 ? ts[5] : tc[5]);
    #pragma unroll
    for (int b6 = 0; b6 < 2; ++b6){ float p6 = p5*(b6 ? ts[6] : tc[6]);
      float a0 = p6*tc[7]*tc[8];
      float a1 = p6*tc[7]*ts[8];
      float a2 = p6*ts[7]*tc[8];
      float a3 = p6*ts[7]*ts[8];
      ushort h0 = bf16h(a0), h1 = bf16h(a1), h2 = bf16h(a2), h3 = bf16h(a3);
      short4v hv; hv[0]=(short)h0; hv[1]=(short)h1; hv[2]=(short)h2; hv[3]=(short)h3;
      short4v lv; lv[0]=(short)bf16h(a0 - bf16f(h0)); lv[1]=(short)bf16h(a1 - bf16f(h1));
                  lv[2]=(short)bf16h(a2 - bf16f(h2)); lv[3]=(short)bf16h(a3 - bf16f(h3));
      int kk = q*128 + j;
      int kstep = kk >> 4;
      int g = (kk >> 2) & 3;
      int idx4 = (kstep*64 + sm)*4 + (g ^ swz);
      bh4[idx4] = hv; bl4[idx4] = lv;
      j += 4;
    }}}}}
  }
  __syncthreads();
  int wv = tid >> 6, lane = tid & 63, l5 = lane >> 5, l31 = lane & 31;
  f32x16 acc[4][2];
  #pragma unroll
  for (int jj = 0; jj < 4; ++jj)
    #pragma unroll
    for (int nf = 0; nf < 2; ++nf)
      #pragma unroll
      for (int e = 0; e < 16; ++e) acc[jj][nf][e] = 0.f;

  for (int kstep = 0; kstep < 32; ++kstep){
    short8 Bh[2], Bl[2];
    #pragma unroll
    for (int nf = 0; nf < 2; ++nf){
      int sm = nf*32 + l31;
      int base = (kstep*64 + sm)*16;
      int sz = ((sm >> 2) & 3) << 2;
      int e0 = (l5*4) ^ sz;
      int e1 = (l5*4 + 8) ^ sz;
      Bh[nf] = cat8(*(const short4v*)(BhL + base + e0), *(const short4v*)(BhL + base + e1));
      Bl[nf] = cat8(*(const short4v*)(BlL + base + e0), *(const short4v*)(BlL + base + e1));
    }
    #pragma unroll
    for (int jj = 0; jj < 4; ++jj){
      int mf = wv*4 + jj;
      const ushort* ah = Uh + ((kstep*16 + mf)*32 + l31)*16 + l5*4;
      const ushort* al = Ul + ((kstep*16 + mf)*32 + l31)*16 + l5*4;
      short8 Ah = cat8(*(const short4v*)ah, *(const short4v*)(ah + 8));
      short8 Al = cat8(*(const short4v*)al, *(const short4v*)(al + 8));
      acc[jj][0] = __builtin_amdgcn_mfma_f32_32x32x16_bf16(Ah, Bh[0], acc[jj][0], 0, 0, 0);
      acc[jj][1] = __builtin_amdgcn_mfma_f32_32x32x16_bf16(Ah, Bh[1], acc[jj][1], 0, 0, 0);
      acc[jj][0] = __builtin_amdgcn_mfma_f32_32x32x16_bf16(Ah, Bl[0], acc[jj][0], 0, 0, 0);
      acc[jj][1] = __builtin_amdgcn_mfma_f32_32x32x16_bf16(Ah, Bl[1], acc[jj][1], 0, 0, 0);
      acc[jj][0] = __builtin_amdgcn_mfma_f32_32x32x16_bf16(Al, Bh[0], acc[jj][0], 0, 0, 0);
      acc[jj][1] = __builtin_amdgcn_mfma_f32_32x32x16_bf16(Al, Bh[1], acc[jj][1], 0, 0, 0);
    }
  }
  float zz[2][9];
  #pragma unroll
  for (int nf = 0; nf < 2; ++nf)
    #pragma unroll
    for (int i = 0; i < 9; ++i) zz[nf][i] = 0.f;
  #pragma unroll
  for (int jj = 0; jj < 4; ++jj){
    int mf = wv*4 + jj;
    float sg0 = (mf & 8) ? -1.f : 1.f;
    float sg1 = (mf & 4) ? -1.f : 1.f;
    float sg2 = (mf & 2) ? -1.f : 1.f;
    float sg3 = (mf & 1) ? -1.f : 1.f;
    #pragma unroll
    for (int nf = 0; nf < 2; ++nf){
      float psum = 0.f, z4 = 0.f, z5 = 0.f, z7 = 0.f, z8 = 0.f;
      #pragma unroll
      for (int e = 0; e < 16; ++e){
        float qv = acc[jj][nf][e]*acc[jj][nf][e];
        psum += qv;
        z4 += ((e >> 3) & 1) ? -qv : qv;
        z5 += ((e >> 2) & 1) ? -qv : qv;
        z7 += ((e >> 1) & 1) ? -qv : qv;
        z8 += (e & 1) ? -qv : qv;
      }
      zz[nf][0] += sg0*psum; zz[nf][1] += sg1*psum;
      zz[nf][2] += sg2*psum; zz[nf][3] += sg3*psum;
      zz[nf][4] += z4; zz[nf][5] += z5;
      zz[nf][6] += l5 ? -psum : psum;
      zz[nf][7] += z7; zz[nf][8] += z8;
    }
  }
  #pragma unroll
  for (int nf = 0; nf < 2; ++nf)
    #pragma unroll
    for (int i = 0; i < 9; ++i) zz[nf][i] += __shfl_xor(zz[nf][i], 32);
  if (l5 == 0){
    #pragma unroll
    for (int nf = 0; nf < 2; ++nf)
      #pragma unroll
      for (int i = 0; i < 9; ++i) zred[wv][nf*32 + l31][i] = zz[nf][i];
  }
  __syncthreads();
  for (int t = tid; t < 576; t += 256){
    int sm = t / 9, i = t - sm*9;
    float s = zred[0][sm][i] + zred[1][sm][i] + zred[2][sm][i] + zred[3][sm][i];
    qo[(size_t)(nb*64 + sm)*9 + i] = s;
  }
}

// ---------------- fc
__global__ void k_fc(const float* __restrict__ q, const float* __restrict__ fw,
                     const float* __restrict__ fb, float* __restrict__ out){
  int idx = blockIdx.x*256 + threadIdx.x;
  if (idx >= NB*5) return;
  int b = idx / 5, o = idx - b*5;
  const float* qr = q + (size_t)b*288;
  const float* wr = fw + (size_t)o*288;
  float s = 0.f;
  for (int j = 0; j < 288; ++j) s += qr[j]*wr[j];
  out[idx] = s + fb[o];
}

extern "C" void kernel_launch(void* const* d_in, const int* in_sizes, int n_in,
                              void* d_out, int out_size, void* d_ws, size_t ws_size,
                              hipStream_t stream){
  const float* x  = (const float*)d_in[0];
  const float* w1 = (const float*)d_in[1];
  const float* w2 = (const float*)d_in[2];
  const float* w3 = (const float*)d_in[3];
  const float* qw = (const float*)d_in[4];
  const float* fw = (const float*)d_in[5];
  const float* fb = (const float*)d_in[6];
  float* out = (float*)d_out;
  float* W = (float*)d_ws;

  float*  out1   = W + OFF_OUT1;
  ushort* a1h    = (ushort*)(W + OFF_A1H);
  ushort* a1l    = (ushort*)(W + OFF_A1L);
  ushort* w2ph   = (ushort*)(W + OFF_W2PH);
  ushort* w2pl   = (ushort*)(W + OFF_W2PL);
  ushort* w3ph   = (ushort*)(W + OFF_W3PH);
  ushort* w3pl   = (ushort*)(W + OFF_W3PL);
  ushort* uH     = (ushort*)(W + OFF_UH);
  ushort* uL     = (ushort*)(W + OFF_UL);
  float*  pool2raw = W + OFF_POOL2RAW;
  ushort* a2h    = (ushort*)(W + OFF_A2H);
  ushort* a2l    = (ushort*)(W + OFF_A2L);
  float*  featsraw = W + OFF_FEATSRAW;
  float*  qo     = W + OFF_QO;
  float*  part1  = W + OFF_PART1;
  float*  part2  = W + OFF_PART2;
  float*  part3  = W + OFF_PART3;
  float*  stats1 = W + OFF_STATS1;
  float*  stats2 = W + OFF_STATS2;
  float*  stats3 = W + OFF_STATS3;

  k_conv1s<<<NB, 256, 0, stream>>>(x, w1, out1, part1);
  k_stats_finP<<<16, 256, 0, stream>>>(part1, stats1, 16, NB*4, 1.f/((float)NB*H1*W1));
  k_bnelu1<<<NB*4, 256, 0, stream>>>(out1, stats1, a1h, a1l);
  k_cvtw<<<256, 256, 0, stream>>>(w2, w3, w2ph, w2pl, w3ph, w3pl);
  k_buildU<<<128, 256, 0, stream>>>(qw, uH, uL);
  k_conv2f<<<NB*2, 128, 0, stream>>>(a1h, a1l, w2ph, w2pl, pool2raw, part2);
  k_stats_finP<<<32, 256, 0, stream>>>(part2, stats2, 32, NB*2, 1.f/((float)NB*H2*W2));
  k_bn2<<<NB*2, 256, 0, stream>>>(pool2raw, stats2, a2h, a2l);
  k_conv3f<<<NB/2, 256, 0, stream>>>(a2h, a2l, w3ph, w3pl, featsraw, part3);
  k_stats_finP<<<32, 256, 0, stream>>>(part3, stats3, 32, NB/2, 1.f/((float)NB*2*W3));
  k_qgemm<<<NB/2, 256, 0, stream>>>(featsraw, stats3, uH, uL, qo);
  k_fc<<<20, 256, 0, stream>>>(qo, fw, fb, out);
}

// Round 6
// 338.250 us; speedup vs baseline: 4.8856x; 1.0091x over previous
//
#include <hip/hip_runtime.h>
#include <math.h>

#define NB 1024
#define C1 16
#define H1 4
#define W1 153
#define WX 216
#define K1 64
#define C2 32
#define H2 4
#define W2 155
#define W192 192
#define PW2 38
#define C3 32
#define W3 38

typedef short short4v __attribute__((ext_vector_type(4)));
typedef short short8 __attribute__((ext_vector_type(8)));
typedef float f32x16 __attribute__((ext_vector_type(16)));

// ---- workspace float offsets
#define OFF_OUT1     0
#define OFF_A1H      10027008
#define OFF_A1L      16318464
#define OFF_W2PH     22609920
#define OFF_W2PL     22626304
#define OFF_W3PH     22642688
#define OFF_W3PL     22659072
#define OFF_UH       22675456
#define OFF_UL       22806528
#define OFF_POOL2RAW 22937600
#define OFF_A2H      25427968
#define OFF_A2L      27787264
#define OFF_FEATSRAW 30146560
#define OFF_QO       30441472
#define OFF_PART1    30736384
#define OFF_PART2    30867456
#define OFF_PART3    30998528
#define OFF_STATS1   31031296
#define OFF_STATS2   31031328
#define OFF_STATS3   31031392

__device__ __forceinline__ float eluf(float x){ return x > 0.f ? x : expm1f(x); }

__device__ __forceinline__ ushort bf16h(float x){
  unsigned u = __float_as_uint(x);
  unsigned r = u + 0x7fffu + ((u >> 16) & 1u);
  return (ushort)(r >> 16);
}
__device__ __forceinline__ float bf16f(ushort h){ return __uint_as_float(((unsigned)h) << 16); }

__device__ __forceinline__ short8 cat8(short4v a, short4v b){
  return __builtin_shufflevector(a, b, 0,1,2,3,4,5,6,7);
}

// ---------------- conv1 + fused BN stats partial
__global__ __launch_bounds__(256) void k_conv1s(const float* __restrict__ x,
                                                const float* __restrict__ w1,
                                                float* __restrict__ out1,
                                                float* __restrict__ part1){
  __shared__ float xr[4][WX];
  __shared__ float wl[C1*K1];
  int n = blockIdx.x, tid = threadIdx.x;
  for (int i = tid; i < 4*WX; i += 256) xr[i/WX][i%WX] = x[(size_t)n*4*WX + i];
  for (int i = tid; i < C1*K1; i += 256) wl[i] = w1[i];
  __syncthreads();
  int h = tid >> 6, lane = tid & 63;
  float acc[16][3];
  #pragma unroll
  for (int c = 0; c < 16; ++c){ acc[c][0]=0.f; acc[c][1]=0.f; acc[c][2]=0.f; }
  bool v2 = (lane + 128) < W1;
  for (int k = 0; k < 64; ++k){
    float x0 = xr[h][lane + k];
    float x1 = xr[h][lane + 64 + k];
    float x2 = v2 ? xr[h][lane + 128 + k] : 0.f;
    #pragma unroll
    for (int c = 0; c < 16; ++c){
      float wk = wl[c*64 + k];
      acc[c][0] += wk*x0; acc[c][1] += wk*x1; acc[c][2] += wk*x2;
    }
  }
  float ss[16], sq[16];
  #pragma unroll
  for (int c = 0; c < 16; ++c){
    float* ob = out1 + (((size_t)(n*16 + c)*4 + h))*W1;
    ob[lane] = acc[c][0];
    ob[lane + 64] = acc[c][1];
    if (v2) ob[lane + 128] = acc[c][2];
    ss[c] = acc[c][0] + acc[c][1] + acc[c][2];
    sq[c] = acc[c][0]*acc[c][0] + acc[c][1]*acc[c][1] + acc[c][2]*acc[c][2];
  }
  #pragma unroll
  for (int m = 1; m < 64; m <<= 1){
    #pragma unroll
    for (int c = 0; c < 16; ++c){ ss[c] += __shfl_xor(ss[c], m); sq[c] += __shfl_xor(sq[c], m); }
  }
  if (lane == 0){
    #pragma unroll
    for (int c = 0; c < 16; ++c){
      part1[((size_t)(n*4 + h)*16 + c)*2]     = ss[c];
      part1[((size_t)(n*4 + h)*16 + c)*2 + 1] = sq[c];
    }
  }
}

// ---------------- parallel stats finalize: grid = C blocks
__global__ __launch_bounds__(256) void k_stats_finP(const float* __restrict__ part,
                                                    float* __restrict__ stats,
                                                    int C, int nblk, float inv){
  __shared__ float rs[256], rq[256];
  int c = blockIdx.x;
  float s = 0.f, q = 0.f;
  for (int b = threadIdx.x; b < nblk; b += 256){
    s += part[((size_t)b*C + c)*2];
    q += part[((size_t)b*C + c)*2 + 1];
  }
  rs[threadIdx.x] = s; rq[threadIdx.x] = q; __syncthreads();
  for (int st = 128; st > 0; st >>= 1){
    if (threadIdx.x < st){ rs[threadIdx.x] += rs[threadIdx.x+st]; rq[threadIdx.x] += rq[threadIdx.x+st]; }
    __syncthreads();
  }
  if (threadIdx.x == 0){
    float mean = rs[0]*inv;
    float var  = rq[0]*inv - mean*mean;
    stats[c*2]   = mean;
    stats[c*2+1] = rsqrtf(var + 1e-5f);
  }
}

// ---------------- bnelu1: LDS-staged coalesced. block=(n,h)
__global__ __launch_bounds__(256) void k_bnelu1(const float* __restrict__ out1,
                                                const float* __restrict__ stats,
                                                ushort* __restrict__ a1h, ushort* __restrict__ a1l){
  __shared__ float xf[2448];   // 16ci x 153w
  __shared__ float st[32];
  int b = blockIdx.x;          // = n*4 + h
  int n = b >> 2, h = b & 3;
  int tid = threadIdx.x;
  if (tid < 32) st[tid] = stats[tid];
  for (int i = tid; i < 2448; i += 256){
    int ci = i / 153, w = i - ci*153;
    xf[i] = out1[((size_t)(n*16 + ci)*4 + h)*W1 + w];
  }
  __syncthreads();
  for (int i = tid; i < 3072; i += 256){
    int w = i >> 4, ci = i & 15;
    float v = 0.f;
    int ws = w - 16;
    if ((unsigned)ws < (unsigned)W1){
      float xx = xf[ci*153 + ws];
      v = eluf((xx - st[ci*2])*st[ci*2+1]);
    }
    int ciS = ci ^ (((w >> 2) & 3) << 2);
    size_t o = (size_t)b*3072 + w*16 + ciS;
    ushort hs = bf16h(v);
    a1h[o] = hs;
    a1l[o] = bf16h(v - bf16f(hs));
  }
}

// ---------------- weight convert+permute
__global__ void k_cvtw(const float* __restrict__ w2, const float* __restrict__ w3,
                       ushort* __restrict__ w2ph, ushort* __restrict__ w2pl,
                       ushort* __restrict__ w3ph, ushort* __restrict__ w3pl){
  int idx = blockIdx.x*256 + threadIdx.x;
  if (idx < 32768){
    int ci = idx & 15; int co = (idx >> 4) & 31; int rk = idx >> 9;
    int r = rk >> 5, kw = rk & 31;
    float v = w2[((size_t)(co*16 + ci)*2 + r)*32 + kw];
    ushort hs = bf16h(v); float hf = bf16f(hs);
    w2ph[idx] = hs; w2pl[idx] = bf16h(v - hf);
  } else {
    int j = idx - 32768;
    int ci = j & 31; int co = (j >> 5) & 31; int rk = j >> 10;
    int r = rk >> 2, kw = rk & 3;
    float v = w3[((size_t)(co*32 + ci)*8 + r)*4 + kw];
    ushort hs = bf16h(v); float hf = bf16f(hs);
    w3ph[j] = hs; w3pl[j] = bf16h(v - hf);
  }
}

// ---------------- fused conv2 v3: block = n, 4 waves = (h-pair HG) x (pos-split PS).
// Wave owns BOTH h of pool pair -> B-row fragments reused across (h,r) combos,
// in-register cross-h pool, no pool LDS.
template<int HG, int PS>
__device__ __forceinline__ void conv2_body(const ushort* s_hi, const ushort* s_lo,
                                           const ushort* __restrict__ w2ph,
                                           const ushort* __restrict__ w2pl,
                                           float* __restrict__ pool2raw,
                                           float (*statW)[32][2],
                                           int n, int l31, int l5){
  constexpr int P0 = PS ? 3 : 0;
  constexpr int NP = PS ? 2 : 3;
  constexpr int NR = (HG == 0) ? 3 : 2;   // physical rows 2*HG .. 2*HG+NR-1

  f32x16 acc[2][NP];
  #pragma unroll
  for (int lh = 0; lh < 2; ++lh)
    #pragma unroll
    for (int p = 0; p < NP; ++p)
      #pragma unroll
      for (int e = 0; e < 16; ++e) acc[lh][p][e] = 0.f;

  for (int kw = 0; kw < 32; ++kw){
    short8 Ah[2], Al[2];
    #pragma unroll
    for (int r = 0; r < 2; ++r){
      int widx = ((r*32 + kw)*32 + l31)*16 + l5*4;
      Ah[r] = cat8(*(const short4v*)(w2ph + widx), *(const short4v*)(w2ph + widx + 8));
      Al[r] = cat8(*(const short4v*)(w2pl + widx), *(const short4v*)(w2pl + widx + 8));
    }
    #pragma unroll
    for (int j = 0; j < NR; ++j){
      int rb = (2*HG + j)*3072;
      short8 bh[NP], bl[NP];
      #pragma unroll
      for (int p = 0; p < NP; ++p){
        int pos = (P0 + p)*32 + l31 + kw;
        int sw = ((pos >> 2) & 3) << 2;
        int off0 = rb + pos*16 + ((l5*4) ^ sw);
        int off1 = rb + pos*16 + ((l5*4 + 8) ^ sw);
        bh[p] = cat8(*(const short4v*)(s_hi + off0), *(const short4v*)(s_hi + off1));
        bl[p] = cat8(*(const short4v*)(s_lo + off0), *(const short4v*)(s_lo + off1));
      }
      // combos (lh, r) with lh + r == j   (h = 2*HG+lh uses W[r] on row 2*HG+lh+r)
      #pragma unroll
      for (int lh = 0; lh < 2; ++lh){
        #pragma unroll
        for (int r = 0; r < 2; ++r){
          if (lh + r != j) continue;
          #pragma unroll
          for (int p = 0; p < NP; ++p){
            acc[lh][p] = __builtin_amdgcn_mfma_f32_32x32x16_bf16(Ah[r], bh[p], acc[lh][p], 0, 0, 0);
            acc[lh][p] = __builtin_amdgcn_mfma_f32_32x32x16_bf16(Ah[r], bl[p], acc[lh][p], 0, 0, 0);
            acc[lh][p] = __builtin_amdgcn_mfma_f32_32x32x16_bf16(Al[r], bh[p], acc[lh][p], 0, 0, 0);
          }
        }
      }
    }
  }

  // ---- stats partial (mask pos>=155); C/D map col=l31, row co=(e&3)+8*(e>>2)+4*l5
  {
    float sreg[16], qreg[16];
    #pragma unroll
    for (int e = 0; e < 16; ++e){ sreg[e] = 0.f; qreg[e] = 0.f; }
    #pragma unroll
    for (int lh = 0; lh < 2; ++lh){
      #pragma unroll
      for (int p = 0; p < NP; ++p){
        bool pv = ((P0 + p) < 4) || (l31 < 27);
        #pragma unroll
        for (int e = 0; e < 16; ++e){
          float v = pv ? acc[lh][p][e] : 0.f;
          sreg[e] += v; qreg[e] += v*v;
        }
      }
    }
    #pragma unroll
    for (int m = 1; m < 32; m <<= 1){
      #pragma unroll
      for (int e = 0; e < 16; ++e){
        sreg[e] += __shfl_xor(sreg[e], m);
        qreg[e] += __shfl_xor(qreg[e], m);
      }
    }
    if (l31 == 0){
      #pragma unroll
      for (int e = 0; e < 16; ++e){
        int co = (e & 3) + ((e >> 2) << 3) + (l5 << 2);
        statW[HG*2 + PS][co][0] = sreg[e];
        statW[HG*2 + PS][co][1] = qreg[e];
      }
    }
  }
  // ---- in-register cross-h max + quad pool, direct global write
  #pragma unroll
  for (int p = 0; p < NP; ++p){
    #pragma unroll
    for (int e = 0; e < 16; ++e){
      float m0 = fmaxf(acc[0][p][e], acc[1][p][e]);
      float v1 = fmaxf(m0, __shfl_xor(m0, 1));
      float v2m = fmaxf(v1, __shfl_xor(v1, 2));
      int pw = (P0 + p)*8 + (l31 >> 2);
      if ((l31 & 3) == 0 && pw < PW2){
        int co = (e & 3) + ((e >> 2) << 3) + (l5 << 2);
        pool2raw[(((size_t)n*2 + HG)*32 + co)*PW2 + pw] = v2m;
      }
    }
  }
}

__global__ __launch_bounds__(256) void k_conv2f(const ushort* __restrict__ a1h,
                                                const ushort* __restrict__ a1l,
                                                const ushort* __restrict__ w2ph,
                                                const ushort* __restrict__ w2pl,
                                                float* __restrict__ pool2raw,
                                                float* __restrict__ part2){
  __shared__ __align__(16) ushort s_hi[4*3072];
  __shared__ __align__(16) ushort s_lo[4*3072];
  __shared__ float statW[4][32][2];
  int n = blockIdx.x;
  int tid = threadIdx.x;
  {
    const float4* gh = (const float4*)(a1h + (size_t)n*12288);
    const float4* gl = (const float4*)(a1l + (size_t)n*12288);
    float4* dh = (float4*)s_hi;
    float4* dl = (float4*)s_lo;
    #pragma unroll
    for (int i = 0; i < 6; ++i){ dh[tid + 256*i] = gh[tid + 256*i]; dl[tid + 256*i] = gl[tid + 256*i]; }
  }
  __syncthreads();
  int wv = tid >> 6, lane = tid & 63;
  int l5 = lane >> 5, l31 = lane & 31;
  int role = (wv + n) & 3;   // permute roles across blocks for SIMD load balance
  switch (role){
    case 0: conv2_body<0,0>(s_hi, s_lo, w2ph, w2pl, pool2raw, statW, n, l31, l5); break;
    case 1: conv2_body<0,1>(s_hi, s_lo, w2ph, w2pl, pool2raw, statW, n, l31, l5); break;
    case 2: conv2_body<1,0>(s_hi, s_lo, w2ph, w2pl, pool2raw, statW, n, l31, l5); break;
    default: conv2_body<1,1>(s_hi, s_lo, w2ph, w2pl, pool2raw, statW, n, l31, l5); break;
  }
  __syncthreads();
  if (tid < 64){
    int hg = tid >> 5, co = tid & 31;
    float s = statW[hg*2][co][0] + statW[hg*2 + 1][co][0];
    float q = statW[hg*2][co][1] + statW[hg*2 + 1][co][1];
    part2[(((size_t)n*2 + hg)*32 + co)*2]     = s;
    part2[(((size_t)n*2 + hg)*32 + co)*2 + 1] = q;
  }
}

// ---------------- bn2: LDS-staged coalesced. block=(n,hr)
__global__ __launch_bounds__(256) void k_bn2(const float* __restrict__ pool2raw,
                                             const float* __restrict__ stats,
                                             ushort* __restrict__ a2h, ushort* __restrict__ a2l){
  __shared__ float xf[1216];   // 32ci x 38pw
  __shared__ float st[64];
  int b = blockIdx.x;          // = n*2 + hr, 2048
  int tid = threadIdx.x;
  if (tid < 64) st[tid] = stats[tid];
  for (int i = tid; i < 1216; i += 256) xf[i] = pool2raw[(size_t)b*1216 + i];
  __syncthreads();
  for (int i = tid; i < 2304; i += 256){
    int w = i >> 5, ci = i & 31;
    float v = 0.f;
    int pw = w - 2;
    if ((unsigned)pw < (unsigned)PW2)
      v = eluf((xf[ci*38 + pw] - st[ci*2])*st[ci*2+1]);
    int ciS = ci ^ (((w >> 1) & 7) << 2);
    size_t o = (size_t)b*2304 + w*32 + ciS;
    ushort hs = bf16h(v);
    a2h[o] = hs; a2l[o] = bf16h(v - bf16f(hs));
  }
}

// ---------------- fused conv3 (MFMA 3-term bf16) + stats partial + maxpool(2,4)
__global__ __launch_bounds__(256, 2) void k_conv3f(const ushort* __restrict__ a2h,
                                                   const ushort* __restrict__ a2l,
                                                   const ushort* __restrict__ w3ph,
                                                   const ushort* __restrict__ w3pl,
                                                   float* __restrict__ featsraw,
                                                   float* __restrict__ part3){
  __shared__ __align__(16) ushort s3h[9216];
  __shared__ __align__(16) ushort s3l[9216];
  __shared__ float poolL3[4][32][12];
  __shared__ float statL3[4][32][2];
  int nb = blockIdx.x;
  int tid = threadIdx.x;
  {
    const float4* gh = (const float4*)(a2h + (size_t)nb*9216);
    const float4* gl = (const float4*)(a2l + (size_t)nb*9216);
    float4* dh = (float4*)s3h;
    float4* dl = (float4*)s3l;
    for (int i = tid; i < 1152; i += 256){ dh[i] = gh[i]; dl[i] = gl[i]; }
  }
  __syncthreads();
  int wave = tid >> 6, lane = tid & 63;
  int nh = wave >> 1, h = wave & 1;
  int l5 = lane >> 5, l31 = lane & 31;

  f32x16 acc[2];
  #pragma unroll
  for (int p = 0; p < 2; ++p)
    #pragma unroll
    for (int e = 0; e < 16; ++e) acc[p][e] = 0.f;

  #pragma unroll
  for (int ri = 0; ri < 2; ++ri){
    int r = (h == 0) ? (4 + ri) : (3 + ri);
    int rbase = (nh*2 + ri)*72*32;
    #pragma unroll
    for (int kw = 0; kw < 4; ++kw){
      #pragma unroll
      for (int ch = 0; ch < 2; ++ch){
        int widx = ((r*4 + kw)*32 + l31)*32 + ch*16 + l5*4;
        short8 Ah = cat8(*(const short4v*)(w3ph + widx), *(const short4v*)(w3ph + widx + 8));
        short8 Al = cat8(*(const short4v*)(w3pl + widx), *(const short4v*)(w3pl + widx + 8));
        short8 Bh[2], Bl[2];
        #pragma unroll
        for (int p = 0; p < 2; ++p){
          int pos = p*32 + l31 + kw;
          int sw = ((pos >> 1) & 7) << 2;
          int s0 = ch*16 + l5*4;
          int off0 = rbase + pos*32 + (s0 ^ sw);
          int off1 = rbase + pos*32 + ((s0 + 8) ^ sw);
          Bh[p] = cat8(*(const short4v*)(s3h + off0), *(const short4v*)(s3h + off1));
          Bl[p] = cat8(*(const short4v*)(s3l + off0), *(const short4v*)(s3l + off1));
        }
        #pragma unroll
        for (int p = 0; p < 2; ++p) acc[p] = __builtin_amdgcn_mfma_f32_32x32x16_bf16(Ah, Bh[p], acc[p], 0, 0, 0);
        #pragma unroll
        for (int p = 0; p < 2; ++p) acc[p] = __builtin_amdgcn_mfma_f32_32x32x16_bf16(Ah, Bl[p], acc[p], 0, 0, 0);
        #pragma unroll
        for (int p = 0; p < 2; ++p) acc[p] = __builtin_amdgcn_mfma_f32_32x32x16_bf16(Al, Bh[p], acc[p], 0, 0, 0);
      }
    }
  }

  {
    float sreg[16], qreg[16];
    #pragma unroll
    for (int e = 0; e < 16; ++e){ sreg[e] = 0.f; qreg[e] = 0.f; }
    #pragma unroll
    for (int p = 0; p < 2; ++p){
      bool pv = (p == 0) || (l31 < 6);
      #pragma unroll
      for (int e = 0; e < 16; ++e){
        float v = pv ? acc[p][e] : 0.f;
        sreg[e] += v; qreg[e] += v*v;
      }
    }
    #pragma unroll
    for (int m = 1; m < 32; m <<= 1){
      #pragma unroll
      for (int e = 0; e < 16; ++e){
        sreg[e] += __shfl_xor(sreg[e], m);
        qreg[e] += __shfl_xor(qreg[e], m);
      }
    }
    if (l31 == 0){
      #pragma unroll
      for (int e = 0; e < 16; ++e){
        int co = (e & 3) + ((e >> 2) << 3) + (l5 << 2);
        statL3[wave][co][0] = sreg[e];
        statL3[wave][co][1] = qreg[e];
      }
    }
  }
  #pragma unroll
  for (int p = 0; p < 2; ++p){
    #pragma unroll
    for (int e = 0; e < 16; ++e){
      float v = acc[p][e];
      float v1 = fmaxf(v, __shfl_xor(v, 1));
      float v2m = fmaxf(v1, __shfl_xor(v1, 2));
      int pw = p*8 + (l31 >> 2);
      if ((l31 & 3) == 0 && pw < 9){
        int co = (e & 3) + ((e >> 2) << 3) + (l5 << 2);
        poolL3[wave][co][pw] = v2m;
      }
    }
  }
  __syncthreads();
  for (int i = tid; i < 2*32*9; i += 256){
    int pw = i % 9; int t = i / 9; int co = t & 31; int nh2 = t >> 5;
    float v = fmaxf(poolL3[nh2*2][co][pw], poolL3[nh2*2+1][co][pw]);
    featsraw[((size_t)(nb*2 + nh2)*32 + co)*9 + pw] = v;
  }
  if (tid < 32){
    float s = 0.f, q = 0.f;
    #pragma unroll
    for (int wv = 0; wv < 4; ++wv){ s += statL3[wv][tid][0]; q += statL3[wv][tid][1]; }
    part3[((size_t)nb*32 + tid)*2]     = s;
    part3[((size_t)nb*32 + tid)*2 + 1] = q;
  }
}

// ---------------- build U (512x512) by running the fixed circuit on basis states
__global__ __launch_bounds__(256) void k_buildU(const float* __restrict__ qw,
                                                ushort* __restrict__ Uh, ushort* __restrict__ Ul){
  __shared__ float wt[36][2];
  int tid = threadIdx.x;
  if (tid < 36){ float s, c; sincosf(qw[tid]*0.5f, &s, &c); wt[tid][0] = c; wt[tid][1] = s; }
  __syncthreads();
  int wid = tid >> 6, lane = tid & 63;
  int k = blockIdx.x*4 + wid;
  float v[8];
  #pragma unroll
  for (int r = 0; r < 8; ++r) v[r] = (lane*8 + r == k) ? 1.f : 0.f;

  for (int j = 0; j < 4; ++j){
    #pragma unroll
    for (int i = 0; i < 5; ++i){
      int cm = 32>>i, tm = 16>>i;
      bool flip = (lane & cm) != 0;
      #pragma unroll
      for (int r = 0; r < 8; ++r){
        float w = __shfl_xor(v[r], tm);
        v[r] = flip ? w : v[r];
      }
    }
    { bool flip = (lane & 1) != 0;
      #pragma unroll
      for (int r = 0; r < 4; ++r){ float a = v[r], bb = v[r+4]; v[r] = flip?bb:a; v[r+4] = flip?a:bb; } }
    { float t = v[4]; v[4] = v[6]; v[6] = t; t = v[5]; v[5] = v[7]; v[7] = t; }
    { float t = v[2]; v[2] = v[3]; v[3] = t; t = v[6]; v[6] = v[7]; v[7] = t; }
    #pragma unroll
    for (int r = 1; r < 8; r += 2) v[r] = __shfl_xor(v[r], 32);

    #pragma unroll
    for (int i = 0; i < 6; ++i){
      float c = wt[j*9+i][0], s = wt[j*9+i][1];
      int m = 32>>i;
      float sg = (lane & m) ? s : -s;
      #pragma unroll
      for (int r = 0; r < 8; ++r){
        float w = __shfl_xor(v[r], m);
        v[r] = c*v[r] + sg*w;
      }
    }
    { float c = wt[j*9+6][0], s = wt[j*9+6][1];
      #pragma unroll
      for (int r = 0; r < 4; ++r){ float a = v[r], bb = v[r+4]; v[r] = c*a - s*bb; v[r+4] = s*a + c*bb; } }
    { float c = wt[j*9+7][0], s = wt[j*9+7][1]; float a, bb;
      a=v[0]; bb=v[2]; v[0]=c*a-s*bb; v[2]=s*a+c*bb;
      a=v[1]; bb=v[3]; v[1]=c*a-s*bb; v[3]=s*a+c*bb;
      a=v[4]; bb=v[6]; v[4]=c*a-s*bb; v[6]=s*a+c*bb;
      a=v[5]; bb=v[7]; v[5]=c*a-s*bb; v[7]=s*a+c*bb; }
    { float c = wt[j*9+8][0], s = wt[j*9+8][1]; float a, bb;
      a=v[0]; bb=v[1]; v[0]=c*a-s*bb; v[1]=s*a+c*bb;
      a=v[2]; bb=v[3]; v[2]=c*a-s*bb; v[3]=s*a+c*bb;
      a=v[4]; bb=v[5]; v[4]=c*a-s*bb; v[5]=s*a+c*bb;
      a=v[6]; bb=v[7]; v[6]=c*a-s*bb; v[7]=s*a+c*bb; }
  }
  #pragma unroll
  for (int r = 0; r < 8; ++r){
    int s = lane*8 + r;
    int mf = s >> 5, r31 = s & 31;
    int addr = (((k >> 4)*16 + mf)*32 + r31)*16 + (k & 15);
    float f = v[r];
    ushort hi = bf16h(f);
    Uh[addr] = hi;
    Ul[addr] = bf16h(f - bf16f(hi));
  }
}

// ---------------- quantum GEMM: state = U @ b(sample), fused BN+ELU + <Z> epilogue
__global__ __launch_bounds__(256, 1) void k_qgemm(const float* __restrict__ featsraw,
                                                  const float* __restrict__ stats,
                                                  const ushort* __restrict__ Uh,
                                                  const ushort* __restrict__ Ul,
                                                  float* __restrict__ qo){
  __shared__ __align__(16) ushort BhL[32768];
  __shared__ __align__(16) ushort BlL[32768];
  __shared__ float angL[576];
  __shared__ float zred[4][64][9];
  int nb = blockIdx.x;
  int tid = threadIdx.x;
  for (int t = tid; t < 576; t += 256){
    float vr = featsraw[(size_t)nb*576 + t];
    int c = (t/9) & 31;
    angL[t] = 0.5f * eluf((vr - stats[c*2])*stats[c*2+1]);
  }
  __syncthreads();
  {
    int sm = tid >> 2, q = tid & 3;
    float tc[9], ts[9];
    #pragma unroll
    for (int i = 0; i < 9; ++i) sincosf(angL[sm*9 + i], &ts[i], &tc[i]);
    float Pc = ((q & 2) ? ts[0] : tc[0]) * ((q & 1) ? ts[1] : tc[1]);
    int swz = (sm >> 2) & 3;
    short4v* bh4 = (short4v*)BhL;
    short4v* bl4 = (short4v*)BlL;
    int j = 0;
    #pragma unroll
    for (int b2 = 0; b2 < 2; ++b2){ float p2 = Pc*(b2 ? ts[2] : tc[2]);
    #pragma unroll
    for (int b3 = 0; b3 < 2; ++b3){ float p3 = p2*(b3 ? ts[3] : tc[3]);
    #pragma unroll
    for (int b4 = 0; b4 < 2; ++b4){ float p4 = p3*(b4 ? ts[4] : tc[4]);
    #pragma unroll
    for (int b5 = 0; b5 < 2; ++b5){ float p5 = p4*(b5 ? ts[5] : tc[5]);
    #pragma unroll
    for (int b6 = 0; b6 < 2; ++b6){ float p6 = p5*(b6 ? ts[6] : tc[6]);
      float a0 = p6*tc[7]*tc[8];
      float a1 = p6*tc[7]*ts[8];
      float a2 = p6*ts[7]*tc[8];
      float a3 = p6*ts[7]*ts[8];
      ushort h0 = bf16h(a0), h1 = bf16h(a1), h2 = bf16h(a2), h3 = bf16h(a3);
      short4v hv; hv[0]=(short)h0; hv[1]=(short)h1; hv[2]=(short)h2; hv[3]=(short)h3;
      short4v lv; lv[0]=(short)bf16h(a0 - bf16f(h0)); lv[1]=(short)bf16h(a1 - bf16f(h1));
                  lv[2]=(short)bf16h(a2 - bf16f(h2)); lv[3]=(short)bf16h(a3 - bf16f(h3));
      int kk = q*128 + j;
      int kstep = kk >> 4;
      int g = (kk >> 2) & 3;
      int idx4 = (kstep*64 + sm)*4 + (g ^ swz);
      bh4[idx4] = hv; bl4[idx4] = lv;
      j += 4;
    }}}}}
  }
  __syncthreads();
  int wv = tid >> 6, lane = tid & 63, l5 = lane >> 5, l31 = lane & 31;
  f32x16 acc[4][2];
  #pragma unroll
  for (int jj = 0; jj < 4; ++jj)
    #pragma unroll
    for (int nf = 0; nf < 2; ++nf)
      #pragma unroll
      for (int e = 0; e < 16; ++e) acc[jj][nf][e] = 0.f;

  for (int kstep = 0; kstep < 32; ++kstep){
    short8 Bh[2], Bl[2];
    #pragma unroll
    for (int nf = 0; nf < 2; ++nf){
      int sm = nf*32 + l31;
      int base = (kstep*64 + sm)*16;
      int sz = ((sm >> 2) & 3) << 2;
      int e0 = (l5*4) ^ sz;
      int e1 = (l5*4 + 8) ^ sz;
      Bh[nf] = cat8(*(const short4v*)(BhL + base + e0), *(const short4v*)(BhL + base + e1));
      Bl[nf] = cat8(*(const short4v*)(BlL + base + e0), *(const short4v*)(BlL + base + e1));
    }
    #pragma unroll
    for (int jj = 0; jj < 4; ++jj){
      int mf = wv*4 + jj;
      const ushort* ah = Uh + ((kstep*16 + mf)*32 + l31)*16 + l5*4;
      const ushort* al = Ul + ((kstep*16 + mf)*32 + l31)*16 + l5*4;
      short8 Ah = cat8(*(const short4v*)ah, *(const short4v*)(ah + 8));
      short8 Al = cat8(*(const short4v*)al, *(const short4v*)(al + 8));
      acc[jj][0] = __builtin_amdgcn_mfma_f32_32x32x16_bf16(Ah, Bh[0], acc[jj][0], 0, 0, 0);
      acc[jj][1] = __builtin_amdgcn_mfma_f32_32x32x16_bf16(Ah, Bh[1], acc[jj][1], 0, 0, 0);
      acc[jj][0] = __builtin_amdgcn_mfma_f32_32x32x16_bf16(Ah, Bl[0], acc[jj][0], 0, 0, 0);
      acc[jj][1] = __builtin_amdgcn_mfma_f32_32x32x16_bf16(Ah, Bl[1], acc[jj][1], 0, 0, 0);
      acc[jj][0] = __builtin_amdgcn_mfma_f32_32x32x16_bf16(Al, Bh[0], acc[jj][0], 0, 0, 0);
      acc[jj][1] = __builtin_amdgcn_mfma_f32_32x32x16_bf16(Al, Bh[1], acc[jj][1], 0, 0, 0);
    }
  }
  float zz[2][9];
  #pragma unroll
  for (int nf = 0; nf < 2; ++nf)
    #pragma unroll
    for (int i = 0; i < 9; ++i) zz[nf][i] = 0.f;
  #pragma unroll
  for (int jj = 0; jj < 4; ++jj){
    int mf = wv*4 + jj;
    float sg0 = (mf & 8) ? -1.f : 1.f;
    float sg1 = (mf & 4) ? -1.f : 1.f;
    float sg2 = (mf & 2) ? -1.f : 1.f;
    float sg3 = (mf & 1) ? -1.f : 1.f;
    #pragma unroll
    for (int nf = 0; nf < 2; ++nf){
      float psum = 0.f, z4 = 0.f, z5 = 0.f, z7 = 0.f, z8 = 0.f;
      #pragma unroll
      for (int e = 0; e < 16; ++e){
        float qv = acc[jj][nf][e]*acc[jj][nf][e];
        psum += qv;
        z4 += ((e >> 3) & 1) ? -qv : qv;
        z5 += ((e >> 2) & 1) ? -qv : qv;
        z7 += ((e >> 1) & 1) ? -qv : qv;
        z8 += (e & 1) ? -qv : qv;
      }
      zz[nf][0] += sg0*psum; zz[nf][1] += sg1*psum;
      zz[nf][2] += sg2*psum; zz[nf][3] += sg3*psum;
      zz[nf][4] += z4; zz[nf][5] += z5;
      zz[nf][6] += l5 ? -psum : psum;
      zz[nf][7] += z7; zz[nf][8] += z8;
    }
  }
  #pragma unroll
  for (int nf = 0; nf < 2; ++nf)
    #pragma unroll
    for (int i = 0; i < 9; ++i) zz[nf][i] += __shfl_xor(zz[nf][i], 32);
  if (l5 == 0){
    #pragma unroll
    for (int nf = 0; nf < 2; ++nf)
      #pragma unroll
      for (int i = 0; i < 9; ++i) zred[wv][nf*32 + l31][i] = zz[nf][i];
  }
  __syncthreads();
  for (int t = tid; t < 576; t += 256){
    int sm = t / 9, i = t - sm*9;
    float s = zred[0][sm][i] + zred[1][sm][i] + zred[2][sm][i] + zred[3][sm][i];
    qo[(size_t)(nb*64 + sm)*9 + i] = s;
  }
}

// ---------------- fc
__global__ void k_fc(const float* __restrict__ q, const float* __restrict__ fw,
                     const float* __restrict__ fb, float* __restrict__ out){
  int idx = blockIdx.x*256 + threadIdx.x;
  if (idx >= NB*5) return;
  int b = idx / 5, o = idx - b*5;
  const float* qr = q + (size_t)b*288;
  const float* wr = fw + (size_t)o*288;
  float s = 0.f;
  for (int j = 0; j < 288; ++j) s += qr[j]*wr[j];
  out[idx] = s + fb[o];
}

extern "C" void kernel_launch(void* const* d_in, const int* in_sizes, int n_in,
                              void* d_out, int out_size, void* d_ws, size_t ws_size,
                              hipStream_t stream){
  const float* x  = (const float*)d_in[0];
  const float* w1 = (const float*)d_in[1];
  const float* w2 = (const float*)d_in[2];
  const float* w3 = (const float*)d_in[3];
  const float* qw = (const float*)d_in[4];
  const float* fw = (const float*)d_in[5];
  const float* fb = (const float*)d_in[6];
  float* out = (float*)d_out;
  float* W = (float*)d_ws;

  float*  out1   = W + OFF_OUT1;
  ushort* a1h    = (ushort*)(W + OFF_A1H);
  ushort* a1l    = (ushort*)(W + OFF_A1L);
  ushort* w2ph   = (ushort*)(W + OFF_W2PH);
  ushort* w2pl   = (ushort*)(W + OFF_W2PL);
  ushort* w3ph   = (ushort*)(W + OFF_W3PH);
  ushort* w3pl   = (ushort*)(W + OFF_W3PL);
  ushort* uH     = (ushort*)(W + OFF_UH);
  ushort* uL     = (ushort*)(W + OFF_UL);
  float*  pool2raw = W + OFF_POOL2RAW;
  ushort* a2h    = (ushort*)(W + OFF_A2H);
  ushort* a2l    = (ushort*)(W + OFF_A2L);
  float*  featsraw = W + OFF_FEATSRAW;
  float*  qo     = W + OFF_QO;
  float*  part1  = W + OFF_PART1;
  float*  part2  = W + OFF_PART2;
  float*  part3  = W + OFF_PART3;
  float*  stats1 = W + OFF_STATS1;
  float*  stats2 = W + OFF_STATS2;
  float*  stats3 = W + OFF_STATS3;

  k_conv1s<<<NB, 256, 0, stream>>>(x, w1, out1, part1);
  k_stats_finP<<<16, 256, 0, stream>>>(part1, stats1, 16, NB*4, 1.f/((float)NB*H1*W1));
  k_bnelu1<<<NB*4, 256, 0, stream>>>(out1, stats1, a1h, a1l);
  k_cvtw<<<256, 256, 0, stream>>>(w2, w3, w2ph, w2pl, w3ph, w3pl);
  k_buildU<<<128, 256, 0, stream>>>(qw, uH, uL);
  k_conv2f<<<NB, 256, 0, stream>>>(a1h, a1l, w2ph, w2pl, pool2raw, part2);
  k_stats_finP<<<32, 256, 0, stream>>>(part2, stats2, 32, NB*2, 1.f/((float)NB*H2*W2));
  k_bn2<<<NB*2, 256, 0, stream>>>(pool2raw, stats2, a2h, a2l);
  k_conv3f<<<NB/2, 256, 0, stream>>>(a2h, a2l, w3ph, w3pl, featsraw, part3);
  k_stats_finP<<<32, 256, 0, stream>>>(part3, stats3, 32, NB/2, 1.f/((float)NB*2*W3));
  k_qgemm<<<NB/2, 256, 0, stream>>>(featsraw, stats3, uH, uL, qo);
  k_fc<<<20, 256, 0, stream>>>(qo, fw, fb, out);
}

// Round 7
// 315.696 us; speedup vs baseline: 5.2347x; 1.0714x over previous
//
#include <hip/hip_runtime.h>
#include <math.h>

#define NB 1024
#define C1 16
#define H1 4
#define W1 153
#define WX 216
#define K1 64
#define C2 32
#define H2 4
#define W2 155
#define W192 192
#define PW2 38
#define C3 32
#define W3 38

typedef short short4v __attribute__((ext_vector_type(4)));
typedef short short8 __attribute__((ext_vector_type(8)));
typedef float f32x16 __attribute__((ext_vector_type(16)));

// ---- workspace float offsets
#define OFF_OUT1     0
#define OFF_A1H      10027008
#define OFF_A1L      16318464
#define OFF_W2PH     22609920
#define OFF_W2PL     22626304
#define OFF_W3PH     22642688
#define OFF_W3PL     22659072
#define OFF_UH       22675456
#define OFF_UL       22806528
#define OFF_POOL2RAW 22937600
#define OFF_A2H      25427968
#define OFF_A2L      27787264
#define OFF_FEATSRAW 30146560
#define OFF_QO       30441472
#define OFF_PART1    30736384
#define OFF_PART2    30867456
#define OFF_PART3    30998528
#define OFF_STATS1   31031296
#define OFF_STATS2   31031328
#define OFF_STATS3   31031392

__device__ __forceinline__ float eluf(float x){ return x > 0.f ? x : expm1f(x); }

__device__ __forceinline__ ushort bf16h(float x){
  unsigned u = __float_as_uint(x);
  unsigned r = u + 0x7fffu + ((u >> 16) & 1u);
  return (ushort)(r >> 16);
}
__device__ __forceinline__ float bf16f(ushort h){ return __uint_as_float(((unsigned)h) << 16); }

__device__ __forceinline__ short8 cat8(short4v a, short4v b){
  return __builtin_shufflevector(a, b, 0,1,2,3,4,5,6,7);
}

// ---------------- conv1 + fused BN stats partial
__global__ __launch_bounds__(256) void k_conv1s(const float* __restrict__ x,
                                                const float* __restrict__ w1,
                                                float* __restrict__ out1,
                                                float* __restrict__ part1){
  __shared__ float xr[4][WX];
  __shared__ float wl[C1*K1];
  int n = blockIdx.x, tid = threadIdx.x;
  for (int i = tid; i < 4*WX; i += 256) xr[i/WX][i%WX] = x[(size_t)n*4*WX + i];
  for (int i = tid; i < C1*K1; i += 256) wl[i] = w1[i];
  __syncthreads();
  int h = tid >> 6, lane = tid & 63;
  float acc[16][3];
  #pragma unroll
  for (int c = 0; c < 16; ++c){ acc[c][0]=0.f; acc[c][1]=0.f; acc[c][2]=0.f; }
  bool v2 = (lane + 128) < W1;
  for (int k = 0; k < 64; ++k){
    float x0 = xr[h][lane + k];
    float x1 = xr[h][lane + 64 + k];
    float x2 = v2 ? xr[h][lane + 128 + k] : 0.f;
    #pragma unroll
    for (int c = 0; c < 16; ++c){
      float wk = wl[c*64 + k];
      acc[c][0] += wk*x0; acc[c][1] += wk*x1; acc[c][2] += wk*x2;
    }
  }
  float ss[16], sq[16];
  #pragma unroll
  for (int c = 0; c < 16; ++c){
    float* ob = out1 + (((size_t)(n*16 + c)*4 + h))*W1;
    ob[lane] = acc[c][0];
    ob[lane + 64] = acc[c][1];
    if (v2) ob[lane + 128] = acc[c][2];
    ss[c] = acc[c][0] + acc[c][1] + acc[c][2];
    sq[c] = acc[c][0]*acc[c][0] + acc[c][1]*acc[c][1] + acc[c][2]*acc[c][2];
  }
  #pragma unroll
  for (int m = 1; m < 64; m <<= 1){
    #pragma unroll
    for (int c = 0; c < 16; ++c){ ss[c] += __shfl_xor(ss[c], m); sq[c] += __shfl_xor(sq[c], m); }
  }
  if (lane == 0){
    #pragma unroll
    for (int c = 0; c < 16; ++c){
      part1[((size_t)(n*4 + h)*16 + c)*2]     = ss[c];
      part1[((size_t)(n*4 + h)*16 + c)*2 + 1] = sq[c];
    }
  }
}

// ---------------- parallel stats finalize: grid = C blocks
__global__ __launch_bounds__(256) void k_stats_finP(const float* __restrict__ part,
                                                    float* __restrict__ stats,
                                                    int C, int nblk, float inv){
  __shared__ float rs[256], rq[256];
  int c = blockIdx.x;
  float s = 0.f, q = 0.f;
  for (int b = threadIdx.x; b < nblk; b += 256){
    s += part[((size_t)b*C + c)*2];
    q += part[((size_t)b*C + c)*2 + 1];
  }
  rs[threadIdx.x] = s; rq[threadIdx.x] = q; __syncthreads();
  for (int st = 128; st > 0; st >>= 1){
    if (threadIdx.x < st){ rs[threadIdx.x] += rs[threadIdx.x+st]; rq[threadIdx.x] += rq[threadIdx.x+st]; }
    __syncthreads();
  }
  if (threadIdx.x == 0){
    float mean = rs[0]*inv;
    float var  = rq[0]*inv - mean*mean;
    stats[c*2]   = mean;
    stats[c*2+1] = rsqrtf(var + 1e-5f);
  }
}

// ---------------- bnelu1: LDS-staged coalesced. block=(n,h). 8-granular ci swizzle.
__global__ __launch_bounds__(256) void k_bnelu1(const float* __restrict__ out1,
                                                const float* __restrict__ stats,
                                                ushort* __restrict__ a1h, ushort* __restrict__ a1l){
  __shared__ float xf[2448];   // 16ci x 153w
  __shared__ float st[32];
  int b = blockIdx.x;          // = n*4 + h
  int n = b >> 2, h = b & 3;
  int tid = threadIdx.x;
  if (tid < 32) st[tid] = stats[tid];
  for (int i = tid; i < 2448; i += 256){
    int ci = i / 153, w = i - ci*153;
    xf[i] = out1[((size_t)(n*16 + ci)*4 + h)*W1 + w];
  }
  __syncthreads();
  for (int i = tid; i < 3072; i += 256){
    int w = i >> 4, ci = i & 15;
    float v = 0.f;
    int ws = w - 16;
    if ((unsigned)ws < (unsigned)W1){
      float xx = xf[ci*153 + ws];
      v = eluf((xx - st[ci*2])*st[ci*2+1]);
    }
    int ciS = ci ^ (((w >> 2) & 1) << 3);   // 8-granular swizzle (matches conv2f b128 reads)
    size_t o = (size_t)b*3072 + w*16 + ciS;
    ushort hs = bf16h(v);
    a1h[o] = hs;
    a1l[o] = bf16h(v - bf16f(hs));
  }
}

// ---------------- weight convert+permute
__global__ void k_cvtw(const float* __restrict__ w2, const float* __restrict__ w3,
                       ushort* __restrict__ w2ph, ushort* __restrict__ w2pl,
                       ushort* __restrict__ w3ph, ushort* __restrict__ w3pl){
  int idx = blockIdx.x*256 + threadIdx.x;
  if (idx < 32768){
    int ci = idx & 15; int co = (idx >> 4) & 31; int rk = idx >> 9;
    int r = rk >> 5, kw = rk & 31;
    float v = w2[((size_t)(co*16 + ci)*2 + r)*32 + kw];
    ushort hs = bf16h(v); float hf = bf16f(hs);
    w2ph[idx] = hs; w2pl[idx] = bf16h(v - hf);
  } else {
    int j = idx - 32768;
    int ci = j & 31; int co = (j >> 5) & 31; int rk = j >> 10;
    int r = rk >> 2, kw = rk & 3;
    float v = w3[((size_t)(co*32 + ci)*8 + r)*4 + kw];
    ushort hs = bf16h(v); float hf = bf16f(hs);
    w3ph[j] = hs; w3pl[j] = bf16h(v - hf);
  }
}

// ---------------- fused conv2 v4: block = (n, HG h-pair), 4 waves = PS position split.
// Occupancy-first: VGPR<=128 (4 waves/SIMD), one ds_read_b128 per fragment,
// k-slot map (l5,j) -> l5*8+j on BOTH A and B, 8-granular XOR swizzle.
template<int HG, int PS>
__device__ __forceinline__ void conv2_body(const ushort* s_hi, const ushort* s_lo,
                                           const ushort* __restrict__ w2ph,
                                           const ushort* __restrict__ w2pl,
                                           float* __restrict__ pool2raw,
                                           float (*statW)[32][2],
                                           int n, int l31, int l5){
  constexpr int P0 = (PS == 0) ? 0 : (PS + 1);   // PS0:{0,1}, PS1:{2}, PS2:{3}, PS3:{4}
  constexpr int NP = (PS == 0) ? 2 : 1;
  constexpr int NR = (HG == 0) ? 3 : 2;          // staged rows (local j = 0..NR-1)
  int e8 = l5*8;

  f32x16 acc[2][NP];
  #pragma unroll
  for (int lh = 0; lh < 2; ++lh)
    #pragma unroll
    for (int p = 0; p < NP; ++p)
      #pragma unroll
      for (int e = 0; e < 16; ++e) acc[lh][p][e] = 0.f;

  for (int kw = 0; kw < 32; ++kw){
    short8 Ah[2], Al[2];
    #pragma unroll
    for (int r = 0; r < 2; ++r){
      int widx = ((r*32 + kw)*32 + l31)*16 + e8;
      Ah[r] = *(const short8*)(w2ph + widx);
      Al[r] = *(const short8*)(w2pl + widx);
    }
    #pragma unroll
    for (int j = 0; j < NR; ++j){
      int rb = j*3072;
      short8 bh[NP], bl[NP];
      #pragma unroll
      for (int p = 0; p < NP; ++p){
        int pos = (P0 + p)*32 + l31 + kw;
        int off = rb + pos*16 + (e8 ^ (((pos >> 2) & 1) << 3));
        bh[p] = *(const short8*)(s_hi + off);
        bl[p] = *(const short8*)(s_lo + off);
      }
      // combos (lh, r) with lh + r == j
      #pragma unroll
      for (int lh = 0; lh < 2; ++lh){
        #pragma unroll
        for (int r = 0; r < 2; ++r){
          if (lh + r != j) continue;
          #pragma unroll
          for (int p = 0; p < NP; ++p){
            acc[lh][p] = __builtin_amdgcn_mfma_f32_32x32x16_bf16(Ah[r], bh[p], acc[lh][p], 0, 0, 0);
            acc[lh][p] = __builtin_amdgcn_mfma_f32_32x32x16_bf16(Ah[r], bl[p], acc[lh][p], 0, 0, 0);
            acc[lh][p] = __builtin_amdgcn_mfma_f32_32x32x16_bf16(Al[r], bh[p], acc[lh][p], 0, 0, 0);
          }
        }
      }
    }
  }

  // ---- stats partial (mask pos>=155); C/D map col=l31, row co=(e&3)+8*(e>>2)+4*l5
  {
    float sreg[16], qreg[16];
    #pragma unroll
    for (int e = 0; e < 16; ++e){ sreg[e] = 0.f; qreg[e] = 0.f; }
    #pragma unroll
    for (int lh = 0; lh < 2; ++lh){
      #pragma unroll
      for (int p = 0; p < NP; ++p){
        bool pv = ((P0 + p) < 4) || (l31 < 27);
        #pragma unroll
        for (int e = 0; e < 16; ++e){
          float v = pv ? acc[lh][p][e] : 0.f;
          sreg[e] += v; qreg[e] += v*v;
        }
      }
    }
    #pragma unroll
    for (int m = 1; m < 32; m <<= 1){
      #pragma unroll
      for (int e = 0; e < 16; ++e){
        sreg[e] += __shfl_xor(sreg[e], m);
        qreg[e] += __shfl_xor(qreg[e], m);
      }
    }
    if (l31 == 0){
      #pragma unroll
      for (int e = 0; e < 16; ++e){
        int co = (e & 3) + ((e >> 2) << 3) + (l5 << 2);
        statW[PS][co][0] = sreg[e];
        statW[PS][co][1] = qreg[e];
      }
    }
  }
  // ---- in-register cross-h max + quad pool, direct global write
  #pragma unroll
  for (int p = 0; p < NP; ++p){
    #pragma unroll
    for (int e = 0; e < 16; ++e){
      float m0 = fmaxf(acc[0][p][e], acc[1][p][e]);
      float v1 = fmaxf(m0, __shfl_xor(m0, 1));
      float v2m = fmaxf(v1, __shfl_xor(v1, 2));
      int pw = (P0 + p)*8 + (l31 >> 2);
      if ((l31 & 3) == 0 && pw < PW2){
        int co = (e & 3) + ((e >> 2) << 3) + (l5 << 2);
        pool2raw[(((size_t)n*2 + HG)*32 + co)*PW2 + pw] = v2m;
      }
    }
  }
}

__global__ __launch_bounds__(256, 4) void k_conv2f(const ushort* __restrict__ a1h,
                                                   const ushort* __restrict__ a1l,
                                                   const ushort* __restrict__ w2ph,
                                                   const ushort* __restrict__ w2pl,
                                                   float* __restrict__ pool2raw,
                                                   float* __restrict__ part2){
  __shared__ __align__(16) ushort s_hi[3*3072];
  __shared__ __align__(16) ushort s_lo[3*3072];
  __shared__ float statW[4][32][2];
  int b = blockIdx.x;          // 2048: (n, HG)
  int n = b >> 1, HG = b & 1;
  int tid = threadIdx.x;
  int nrows = HG ? 2 : 3;
  {
    const float4* gh = (const float4*)(a1h + ((size_t)n*4 + 2*HG)*3072);
    const float4* gl = (const float4*)(a1l + ((size_t)n*4 + 2*HG)*3072);
    float4* dh = (float4*)s_hi;
    float4* dl = (float4*)s_lo;
    int cnt = nrows*384;
    for (int i = tid; i < cnt; i += 256){ dh[i] = gh[i]; dl[i] = gl[i]; }
  }
  __syncthreads();
  int wv = tid >> 6, lane = tid & 63;
  int l5 = lane >> 5, l31 = lane & 31;
  int ps = (wv + b) & 3;   // permute roles across blocks for SIMD load balance
  if (HG == 0){
    switch (ps){
      case 0: conv2_body<0,0>(s_hi, s_lo, w2ph, w2pl, pool2raw, statW, n, l31, l5); break;
      case 1: conv2_body<0,1>(s_hi, s_lo, w2ph, w2pl, pool2raw, statW, n, l31, l5); break;
      case 2: conv2_body<0,2>(s_hi, s_lo, w2ph, w2pl, pool2raw, statW, n, l31, l5); break;
      default: conv2_body<0,3>(s_hi, s_lo, w2ph, w2pl, pool2raw, statW, n, l31, l5); break;
    }
  } else {
    switch (ps){
      case 0: conv2_body<1,0>(s_hi, s_lo, w2ph, w2pl, pool2raw, statW, n, l31, l5); break;
      case 1: conv2_body<1,1>(s_hi, s_lo, w2ph, w2pl, pool2raw, statW, n, l31, l5); break;
      case 2: conv2_body<1,2>(s_hi, s_lo, w2ph, w2pl, pool2raw, statW, n, l31, l5); break;
      default: conv2_body<1,3>(s_hi, s_lo, w2ph, w2pl, pool2raw, statW, n, l31, l5); break;
    }
  }
  __syncthreads();
  if (tid < 32){
    float s = statW[0][tid][0] + statW[1][tid][0] + statW[2][tid][0] + statW[3][tid][0];
    float q = statW[0][tid][1] + statW[1][tid][1] + statW[2][tid][1] + statW[3][tid][1];
    part2[(((size_t)n*2 + HG)*32 + tid)*2]     = s;
    part2[(((size_t)n*2 + HG)*32 + tid)*2 + 1] = q;
  }
}

// ---------------- bn2: LDS-staged coalesced. block=(n,hr)
__global__ __launch_bounds__(256) void k_bn2(const float* __restrict__ pool2raw,
                                             const float* __restrict__ stats,
                                             ushort* __restrict__ a2h, ushort* __restrict__ a2l){
  __shared__ float xf[1216];   // 32ci x 38pw
  __shared__ float st[64];
  int b = blockIdx.x;          // = n*2 + hr, 2048
  int tid = threadIdx.x;
  if (tid < 64) st[tid] = stats[tid];
  for (int i = tid; i < 1216; i += 256) xf[i] = pool2raw[(size_t)b*1216 + i];
  __syncthreads();
  for (int i = tid; i < 2304; i += 256){
    int w = i >> 5, ci = i & 31;
    float v = 0.f;
    int pw = w - 2;
    if ((unsigned)pw < (unsigned)PW2)
      v = eluf((xf[ci*38 + pw] - st[ci*2])*st[ci*2+1]);
    int ciS = ci ^ (((w >> 1) & 7) << 2);
    size_t o = (size_t)b*2304 + w*32 + ciS;
    ushort hs = bf16h(v);
    a2h[o] = hs; a2l[o] = bf16h(v - bf16f(hs));
  }
}

// ---------------- fused conv3 (MFMA 3-term bf16) + stats partial + maxpool(2,4)
__global__ __launch_bounds__(256, 2) void k_conv3f(const ushort* __restrict__ a2h,
                                                   const ushort* __restrict__ a2l,
                                                   const ushort* __restrict__ w3ph,
                                                   const ushort* __restrict__ w3pl,
                                                   float* __restrict__ featsraw,
                                                   float* __restrict__ part3){
  __shared__ __align__(16) ushort s3h[9216];
  __shared__ __align__(16) ushort s3l[9216];
  __shared__ float poolL3[4][32][12];
  __shared__ float statL3[4][32][2];
  int nb = blockIdx.x;
  int tid = threadIdx.x;
  {
    const float4* gh = (const float4*)(a2h + (size_t)nb*9216);
    const float4* gl = (const float4*)(a2l + (size_t)nb*9216);
    float4* dh = (float4*)s3h;
    float4* dl = (float4*)s3l;
    for (int i = tid; i < 1152; i += 256){ dh[i] = gh[i]; dl[i] = gl[i]; }
  }
  __syncthreads();
  int wave = tid >> 6, lane = tid & 63;
  int nh = wave >> 1, h = wave & 1;
  int l5 = lane >> 5, l31 = lane & 31;

  f32x16 acc[2];
  #pragma unroll
  for (int p = 0; p < 2; ++p)
    #pragma unroll
    for (int e = 0; e < 16; ++e) acc[p][e] = 0.f;

  #pragma unroll
  for (int ri = 0; ri < 2; ++ri){
    int r = (h == 0) ? (4 + ri) : (3 + ri);
    int rbase = (nh*2 + ri)*72*32;
    #pragma unroll
    for (int kw = 0; kw < 4; ++kw){
      #pragma unroll
      for (int ch = 0; ch < 2; ++ch){
        int widx = ((r*4 + kw)*32 + l31)*32 + ch*16 + l5*4;
        short8 Ah = cat8(*(const short4v*)(w3ph + widx), *(const short4v*)(w3ph + widx + 8));
        short8 Al = cat8(*(const short4v*)(w3pl + widx), *(const short4v*)(w3pl + widx + 8));
        short8 Bh[2], Bl[2];
        #pragma unroll
        for (int p = 0; p < 2; ++p){
          int pos = p*32 + l31 + kw;
          int sw = ((pos >> 1) & 7) << 2;
          int s0 = ch*16 + l5*4;
          int off0 = rbase + pos*32 + (s0 ^ sw);
          int off1 = rbase + pos*32 + ((s0 + 8) ^ sw);
          Bh[p] = cat8(*(const short4v*)(s3h + off0), *(const short4v*)(s3h + off1));
          Bl[p] = cat8(*(const short4v*)(s3l + off0), *(const short4v*)(s3l + off1));
        }
        #pragma unroll
        for (int p = 0; p < 2; ++p) acc[p] = __builtin_amdgcn_mfma_f32_32x32x16_bf16(Ah, Bh[p], acc[p], 0, 0, 0);
        #pragma unroll
        for (int p = 0; p < 2; ++p) acc[p] = __builtin_amdgcn_mfma_f32_32x32x16_bf16(Ah, Bl[p], acc[p], 0, 0, 0);
        #pragma unroll
        for (int p = 0; p < 2; ++p) acc[p] = __builtin_amdgcn_mfma_f32_32x32x16_bf16(Al, Bh[p], acc[p], 0, 0, 0);
      }
    }
  }

  {
    float sreg[16], qreg[16];
    #pragma unroll
    for (int e = 0; e < 16; ++e){ sreg[e] = 0.f; qreg[e] = 0.f; }
    #pragma unroll
    for (int p = 0; p < 2; ++p){
      bool pv = (p == 0) || (l31 < 6);
      #pragma unroll
      for (int e = 0; e < 16; ++e){
        float v = pv ? acc[p][e] : 0.f;
        sreg[e] += v; qreg[e] += v*v;
      }
    }
    #pragma unroll
    for (int m = 1; m < 32; m <<= 1){
      #pragma unroll
      for (int e = 0; e < 16; ++e){
        sreg[e] += __shfl_xor(sreg[e], m);
        qreg[e] += __shfl_xor(qreg[e], m);
      }
    }
    if (l31 == 0){
      #pragma unroll
      for (int e = 0; e < 16; ++e){
        int co = (e & 3) + ((e >> 2) << 3) + (l5 << 2);
        statL3[wave][co][0] = sreg[e];
        statL3[wave][co][1] = qreg[e];
      }
    }
  }
  #pragma unroll
  for (int p = 0; p < 2; ++p){
    #pragma unroll
    for (int e = 0; e < 16; ++e){
      float v = acc[p][e];
      float v1 = fmaxf(v, __shfl_xor(v, 1));
      float v2m = fmaxf(v1, __shfl_xor(v1, 2));
      int pw = p*8 + (l31 >> 2);
      if ((l31 & 3) == 0 && pw < 9){
        int co = (e & 3) + ((e >> 2) << 3) + (l5 << 2);
        poolL3[wave][co][pw] = v2m;
      }
    }
  }
  __syncthreads();
  for (int i = tid; i < 2*32*9; i += 256){
    int pw = i % 9; int t = i / 9; int co = t & 31; int nh2 = t >> 5;
    float v = fmaxf(poolL3[nh2*2][co][pw], poolL3[nh2*2+1][co][pw]);
    featsraw[((size_t)(nb*2 + nh2)*32 + co)*9 + pw] = v;
  }
  if (tid < 32){
    float s = 0.f, q = 0.f;
    #pragma unroll
    for (int wv = 0; wv < 4; ++wv){ s += statL3[wv][tid][0]; q += statL3[wv][tid][1]; }
    part3[((size_t)nb*32 + tid)*2]     = s;
    part3[((size_t)nb*32 + tid)*2 + 1] = q;
  }
}

// ---------------- build U (512x512) by running the fixed circuit on basis states
__global__ __launch_bounds__(256) void k_buildU(const float* __restrict__ qw,
                                                ushort* __restrict__ Uh, ushort* __restrict__ Ul){
  __shared__ float wt[36][2];
  int tid = threadIdx.x;
  if (tid < 36){ float s, c; sincosf(qw[tid]*0.5f, &s, &c); wt[tid][0] = c; wt[tid][1] = s; }
  __syncthreads();
  int wid = tid >> 6, lane = tid & 63;
  int k = blockIdx.x*4 + wid;
  float v[8];
  #pragma unroll
  for (int r = 0; r < 8; ++r) v[r] = (lane*8 + r == k) ? 1.f : 0.f;

  for (int j = 0; j < 4; ++j){
    #pragma unroll
    for (int i = 0; i < 5; ++i){
      int cm = 32>>i, tm = 16>>i;
      bool flip = (lane & cm) != 0;
      #pragma unroll
      for (int r = 0; r < 8; ++r){
        float w = __shfl_xor(v[r], tm);
        v[r] = flip ? w : v[r];
      }
    }
    { bool flip = (lane & 1) != 0;
      #pragma unroll
      for (int r = 0; r < 4; ++r){ float a = v[r], bb = v[r+4]; v[r] = flip?bb:a; v[r+4] = flip?a:bb; } }
    { float t = v[4]; v[4] = v[6]; v[6] = t; t = v[5]; v[5] = v[7]; v[7] = t; }
    { float t = v[2]; v[2] = v[3]; v[3] = t; t = v[6]; v[6] = v[7]; v[7] = t; }
    #pragma unroll
    for (int r = 1; r < 8; r += 2) v[r] = __shfl_xor(v[r], 32);

    #pragma unroll
    for (int i = 0; i < 6; ++i){
      float c = wt[j*9+i][0], s = wt[j*9+i][1];
      int m = 32>>i;
      float sg = (lane & m) ? s : -s;
      #pragma unroll
      for (int r = 0; r < 8; ++r){
        float w = __shfl_xor(v[r], m);
        v[r] = c*v[r] + sg*w;
      }
    }
    { float c = wt[j*9+6][0], s = wt[j*9+6][1];
      #pragma unroll
      for (int r = 0; r < 4; ++r){ float a = v[r], bb = v[r+4]; v[r] = c*a - s*bb; v[r+4] = s*a + c*bb; } }
    { float c = wt[j*9+7][0], s = wt[j*9+7][1]; float a, bb;
      a=v[0]; bb=v[2]; v[0]=c*a-s*bb; v[2]=s*a+c*bb;
      a=v[1]; bb=v[3]; v[1]=c*a-s*bb; v[3]=s*a+c*bb;
      a=v[4]; bb=v[6]; v[4]=c*a-s*bb; v[6]=s*a+c*bb;
      a=v[5]; bb=v[7]; v[5]=c*a-s*bb; v[7]=s*a+c*bb; }
    { float c = wt[j*9+8][0], s = wt[j*9+8][1]; float a, bb;
      a=v[0]; bb=v[1]; v[0]=c*a-s*bb; v[1]=s*a+c*bb;
      a=v[2]; bb=v[3]; v[2]=c*a-s*bb; v[3]=s*a+c*bb;
      a=v[4]; bb=v[5]; v[4]=c*a-s*bb; v[5]=s*a+c*bb;
      a=v[6]; bb=v[7]; v[6]=c*a-s*bb; v[7]=s*a+c*bb; }
  }
  #pragma unroll
  for (int r = 0; r < 8; ++r){
    int s = lane*8 + r;
    int mf = s >> 5, r31 = s & 31;
    int addr = (((k >> 4)*16 + mf)*32 + r31)*16 + (k & 15);
    float f = v[r];
    ushort hi = bf16h(f);
    Uh[addr] = hi;
    Ul[addr] = bf16h(f - bf16f(hi));
  }
}

// ---------------- quantum GEMM: state = U @ b(sample), fused BN+ELU + <Z> epilogue
__global__ __launch_bounds__(256, 1) void k_qgemm(const float* __restrict__ featsraw,
                                                  const float* __restrict__ stats,
                                                  const ushort* __restrict__ Uh,
                                                  const ushort* __restrict__ Ul,
                                                  float* __restrict__ qo){
  __shared__ __align__(16) ushort BhL[32768];
  __shared__ __align__(16) ushort BlL[32768];
  __shared__ float angL[576];
  __shared__ float zred[4][64][9];
  int nb = blockIdx.x;
  int tid = threadIdx.x;
  for (int t = tid; t < 576; t += 256){
    float vr = featsraw[(size_t)nb*576 + t];
    int c = (t/9) & 31;
    angL[t] = 0.5f * eluf((vr - stats[c*2])*stats[c*2+1]);
  }
  __syncthreads();
  {
    int sm = tid >> 2, q = tid & 3;
    float tc[9], ts[9];
    #pragma unroll
    for (int i = 0; i < 9; ++i) sincosf(angL[sm*9 + i], &ts[i], &tc[i]);
    float Pc = ((q & 2) ? ts[0] : tc[0]) * ((q & 1) ? ts[1] : tc[1]);
    int swz = (sm >> 2) & 3;
    short4v* bh4 = (short4v*)BhL;
    short4v* bl4 = (short4v*)BlL;
    int j = 0;
    #pragma unroll
    for (int b2 = 0; b2 < 2; ++b2){ float p2 = Pc*(b2 ? ts[2] : tc[2]);
    #pragma unroll
    for (int b3 = 0; b3 < 2; ++b3){ float p3 = p2*(b3 ? ts[3] : tc[3]);
    #pragma unroll
    for (int b4 = 0; b4 < 2; ++b4){ float p4 = p3*(b4 ? ts[4] : tc[4]);
    #pragma unroll
    for (int b5 = 0; b5 < 2; ++b5){ float p5 = p4*(b5 ? ts[5] : tc[5]);
    #pragma unroll
    for (int b6 = 0; b6 < 2; ++b6){ float p6 = p5*(b6 ? ts[6] : tc[6]);
      float a0 = p6*tc[7]*tc[8];
      float a1 = p6*tc[7]*ts[8];
      float a2 = p6*ts[7]*tc[8];
      float a3 = p6*ts[7]*ts[8];
      ushort h0 = bf16h(a0), h1 = bf16h(a1), h2 = bf16h(a2), h3 = bf16h(a3);
      short4v hv; hv[0]=(short)h0; hv[1]=(short)h1; hv[2]=(short)h2; hv[3]=(short)h3;
      short4v lv; lv[0]=(short)bf16h(a0 - bf16f(h0)); lv[1]=(short)bf16h(a1 - bf16f(h1));
                  lv[2]=(short)bf16h(a2 - bf16f(h2)); lv[3]=(short)bf16h(a3 - bf16f(h3));
      int kk = q*128 + j;
      int kstep = kk >> 4;
      int g = (kk >> 2) & 3;
      int idx4 = (kstep*64 + sm)*4 + (g ^ swz);
      bh4[idx4] = hv; bl4[idx4] = lv;
      j += 4;
    }}}}}
  }
  __syncthreads();
  int wv = tid >> 6, lane = tid & 63, l5 = lane >> 5, l31 = lane & 31;
  f32x16 acc[4][2];
  #pragma unroll
  for (int jj = 0; jj < 4; ++jj)
    #pragma unroll
    for (int nf = 0; nf < 2; ++nf)
      #pragma unroll
      for (int e = 0; e < 16; ++e) acc[jj][nf][e] = 0.f;

  for (int kstep = 0; kstep < 32; ++kstep){
    short8 Bh[2], Bl[2];
    #pragma unroll
    for (int nf = 0; nf < 2; ++nf){
      int sm = nf*32 + l31;
      int base = (kstep*64 + sm)*16;
      int sz = ((sm >> 2) & 3) << 2;
      int e0 = (l5*4) ^ sz;
      int e1 = (l5*4 + 8) ^ sz;
      Bh[nf] = cat8(*(const short4v*)(BhL + base + e0), *(const short4v*)(BhL + base + e1));
      Bl[nf] = cat8(*(const short4v*)(BlL + base + e0), *(const short4v*)(BlL + base + e1));
    }
    #pragma unroll
    for (int jj = 0; jj < 4; ++jj){
      int mf = wv*4 + jj;
      const ushort* ah = Uh + ((kstep*16 + mf)*32 + l31)*16 + l5*4;
      const ushort* al = Ul + ((kstep*16 + mf)*32 + l31)*16 + l5*4;
      short8 Ah = cat8(*(const short4v*)ah, *(const short4v*)(ah + 8));
      short8 Al = cat8(*(const short4v*)al, *(const short4v*)(al + 8));
      acc[jj][0] = __builtin_amdgcn_mfma_f32_32x32x16_bf16(Ah, Bh[0], acc[jj][0], 0, 0, 0);
      acc[jj][1] = __builtin_amdgcn_mfma_f32_32x32x16_bf16(Ah, Bh[1], acc[jj][1], 0, 0, 0);
      acc[jj][0] = __builtin_amdgcn_mfma_f32_32x32x16_bf16(Ah, Bl[0], acc[jj][0], 0, 0, 0);
      acc[jj][1] = __builtin_amdgcn_mfma_f32_32x32x16_bf16(Ah, Bl[1], acc[jj][1], 0, 0, 0);
      acc[jj][0] = __builtin_amdgcn_mfma_f32_32x32x16_bf16(Al, Bh[0], acc[jj][0], 0, 0, 0);
      acc[jj][1] = __builtin_amdgcn_mfma_f32_32x32x16_bf16(Al, Bh[1], acc[jj][1], 0, 0, 0);
    }
  }
  float zz[2][9];
  #pragma unroll
  for (int nf = 0; nf < 2; ++nf)
    #pragma unroll
    for (int i = 0; i < 9; ++i) zz[nf][i] = 0.f;
  #pragma unroll
  for (int jj = 0; jj < 4; ++jj){
    int mf = wv*4 + jj;
    float sg0 = (mf & 8) ? -1.f : 1.f;
    float sg1 = (mf & 4) ? -1.f : 1.f;
    float sg2 = (mf & 2) ? -1.f : 1.f;
    float sg3 = (mf & 1) ? -1.f : 1.f;
    #pragma unroll
    for (int nf = 0; nf < 2; ++nf){
      float psum = 0.f, z4 = 0.f, z5 = 0.f, z7 = 0.f, z8 = 0.f;
      #pragma unroll
      for (int e = 0; e < 16; ++e){
        float qv = acc[jj][nf][e]*acc[jj][nf][e];
        psum += qv;
        z4 += ((e >> 3) & 1) ? -qv : qv;
        z5 += ((e >> 2) & 1) ? -qv : qv;
        z7 += ((e >> 1) & 1) ? -qv : qv;
        z8 += (e & 1) ? -qv : qv;
      }
      zz[nf][0] += sg0*psum; zz[nf][1] += sg1*psum;
      zz[nf][2] += sg2*psum; zz[nf][3] += sg3*psum;
      zz[nf][4] += z4; zz[nf][5] += z5;
      zz[nf][6] += l5 ? -psum : psum;
      zz[nf][7] += z7; zz[nf][8] += z8;
    }
  }
  #pragma unroll
  for (int nf = 0; nf < 2; ++nf)
    #pragma unroll
    for (int i = 0; i < 9; ++i) zz[nf][i] += __shfl_xor(zz[nf][i], 32);
  if (l5 == 0){
    #pragma unroll
    for (int nf = 0; nf < 2; ++nf)
      #pragma unroll
      for (int i = 0; i < 9; ++i) zred[wv][nf*32 + l31][i] = zz[nf][i];
  }
  __syncthreads();
  for (int t = tid; t < 576; t += 256){
    int sm = t / 9, i = t - sm*9;
    float s = zred[0][sm][i] + zred[1][sm][i] + zred[2][sm][i] + zred[3][sm][i];
    qo[(size_t)(nb*64 + sm)*9 + i] = s;
  }
}

// ---------------- fc
__global__ void k_fc(const float* __restrict__ q, const float* __restrict__ fw,
                     const float* __restrict__ fb, float* __restrict__ out){
  int idx = blockIdx.x*256 + threadIdx.x;
  if (idx >= NB*5) return;
  int b = idx / 5, o = idx - b*5;
  const float* qr = q + (size_t)b*288;
  const float* wr = fw + (size_t)o*288;
  float s = 0.f;
  for (int j = 0; j < 288; ++j) s += qr[j]*wr[j];
  out[idx] = s + fb[o];
}

extern "C" void kernel_launch(void* const* d_in, const int* in_sizes, int n_in,
                              void* d_out, int out_size, void* d_ws, size_t ws_size,
                              hipStream_t stream){
  const float* x  = (const float*)d_in[0];
  const float* w1 = (const float*)d_in[1];
  const float* w2 = (const float*)d_in[2];
  const float* w3 = (const float*)d_in[3];
  const float* qw = (const float*)d_in[4];
  const float* fw = (const float*)d_in[5];
  const float* fb = (const float*)d_in[6];
  float* out = (float*)d_out;
  float* W = (float*)d_ws;

  float*  out1   = W + OFF_OUT1;
  ushort* a1h    = (ushort*)(W + OFF_A1H);
  ushort* a1l    = (ushort*)(W + OFF_A1L);
  ushort* w2ph   = (ushort*)(W + OFF_W2PH);
  ushort* w2pl   = (ushort*)(W + OFF_W2PL);
  ushort* w3ph   = (ushort*)(W + OFF_W3PH);
  ushort* w3pl   = (ushort*)(W + OFF_W3PL);
  ushort* uH     = (ushort*)(W + OFF_UH);
  ushort* uL     = (ushort*)(W + OFF_UL);
  float*  pool2raw = W + OFF_POOL2RAW;
  ushort* a2h    = (ushort*)(W + OFF_A2H);
  ushort* a2l    = (ushort*)(W + OFF_A2L);
  float*  featsraw = W + OFF_FEATSRAW;
  float*  qo     = W + OFF_QO;
  float*  part1  = W + OFF_PART1;
  float*  part2  = W + OFF_PART2;
  float*  part3  = W + OFF_PART3;
  float*  stats1 = W + OFF_STATS1;
  float*  stats2 = W + OFF_STATS2;
  float*  stats3 = W + OFF_STATS3;

  k_conv1s<<<NB, 256, 0, stream>>>(x, w1, out1, part1);
  k_stats_finP<<<16, 256, 0, stream>>>(part1, stats1, 16, NB*4, 1.f/((float)NB*H1*W1));
  k_bnelu1<<<NB*4, 256, 0, stream>>>(out1, stats1, a1h, a1l);
  k_cvtw<<<256, 256, 0, stream>>>(w2, w3, w2ph, w2pl, w3ph, w3pl);
  k_buildU<<<128, 256, 0, stream>>>(qw, uH, uL);
  k_conv2f<<<NB*2, 256, 0, stream>>>(a1h, a1l, w2ph, w2pl, pool2raw, part2);
  k_stats_finP<<<32, 256, 0, stream>>>(part2, stats2, 32, NB*2, 1.f/((float)NB*H2*W2));
  k_bn2<<<NB*2, 256, 0, stream>>>(pool2raw, stats2, a2h, a2l);
  k_conv3f<<<NB/2, 256, 0, stream>>>(a2h, a2l, w3ph, w3pl, featsraw, part3);
  k_stats_finP<<<32, 256, 0, stream>>>(part3, stats3, 32, NB/2, 1.f/((float)NB*2*W3));
  k_qgemm<<<NB/2, 256, 0, stream>>>(featsraw, stats3, uH, uL, qo);
  k_fc<<<20, 256, 0, stream>>>(qo, fw, fb, out);
}